// Round 9
// baseline (634.028 us; speedup 1.0000x reference)
//
#include <hip/hip_runtime.h>
#include <hip/hip_bf16.h>
#include <math.h>

typedef unsigned short ushort_t;
typedef __attribute__((ext_vector_type(8))) short short8;
typedef __attribute__((ext_vector_type(4))) float f32x4;

#define B_TOTAL 131072

// ws layout (ushort element offsets). W blobs are K-split chunk-major:
// chunk = [N rows][32 k] where storage (n, slot s, j) holds logical
// k = ck*32 + 8*(s ^ SWZ(n)) + j.  Staged linearly via global_load_lds.
#define SWZ(n) ((((n) & 3)) ^ (((n) >> 2) & 3))
#define OFF_VIB 0        // 2 chunks  [192][32] = 12288
#define OFF_ACO 12288    // 8 chunks             = 49152
#define OFF_TMP 61440    // 4 chunks             = 24576
#define OFF_FUS 86016    // 18 chunks            = 110592
#define OFF_WQ 196608    // 18 chunks (layer-major)
#define OFF_WO 307200    // 18 chunks
#define OFF_GRID 417792  // 6 chunks [64][32]    = 12288
#define OFF_KV 430080    // 3 layers x 10240: Kb[4h][16s][64k] + Vt[4h][48d][32s]
#define F32_BYTE_OFF 921600

// prep kernels: explicit RTNE bit-twiddle (cold code)
__device__ __forceinline__ ushort_t f2bu_prep(float f) {
  union { float f; unsigned u; } c; c.f = f;
  unsigned u = c.u;
  unsigned r = (u + 0x7fffu + ((u >> 16) & 1u)) >> 16;  // RTNE
  return (ushort_t)r;
}
// hot kernel: v_cvt bf16 (RTNE on gfx950)
__device__ __forceinline__ ushort_t f2bu(float f) {
  __hip_bfloat16 h = __float2bfloat16(f);
  return *(ushort_t*)&h;
}
__device__ __forceinline__ float fastrcp(float x) { return __builtin_amdgcn_rcpf(x); }
__device__ __forceinline__ float gelu_fast(float x) {
  float u = 0.7978845608f * x * (1.0f + 0.044715f * x * x);
  float E = exp2f(2.88539008f * u);
  float t = 1.0f - 2.0f * fastrcp(E + 1.0f);
  return 0.5f * x * (1.0f + t);
}
#define MFMA16(a, b, c) __builtin_amdgcn_mfma_f32_16x16x32_bf16(a, b, c, 0, 0, 0)

__device__ __forceinline__ void gload16(const void* g, void* l) {
  __builtin_amdgcn_global_load_lds((const __attribute__((address_space(1))) void*)g,
                                   (__attribute__((address_space(3))) void*)l, 16, 0, 0);
}

// ---------------- prep: weights -> K-split swizzled chunks ----------------
__global__ void prep_weights(const float* __restrict__ ev, const float* __restrict__ ea,
                             const float* __restrict__ et, const float* __restrict__ fw,
                             const float* __restrict__ rwq, const float* __restrict__ rwo,
                             const float* __restrict__ gr, ushort_t* __restrict__ ws) {
  int tid = blockIdx.x * blockDim.x + threadIdx.x;
  int nth = gridDim.x * blockDim.x;
  for (int i = tid; i < 12288; i += nth) {
    int ck = i / 6144, rem = i % 6144, n = rem >> 5, s = (rem >> 3) & 3, j = i & 7;
    int k = ck * 32 + 8 * (s ^ SWZ(n)) + j;
    ws[OFF_VIB + i] = f2bu_prep(ev[k * 192 + n]);
  }
  for (int i = tid; i < 49152; i += nth) {
    int ck = i / 6144, rem = i % 6144, n = rem >> 5, s = (rem >> 3) & 3, j = i & 7;
    int k = ck * 32 + 8 * (s ^ SWZ(n)) + j;
    ws[OFF_ACO + i] = f2bu_prep(ea[k * 192 + n]);
  }
  for (int i = tid; i < 24576; i += nth) {
    int ck = i / 6144, rem = i % 6144, n = rem >> 5, s = (rem >> 3) & 3, j = i & 7;
    int k = ck * 32 + 8 * (s ^ SWZ(n)) + j;
    ws[OFF_TMP + i] = f2bu_prep(et[k * 192 + n]);
  }
  for (int i = tid; i < 110592; i += nth) {
    int ck = i / 6144, rem = i % 6144, n = rem >> 5, s = (rem >> 3) & 3, j = i & 7;
    int k = ck * 32 + 8 * (s ^ SWZ(n)) + j;
    ws[OFF_FUS + i] = f2bu_prep(fw[k * 192 + n]);
  }
  for (int i = tid; i < 110592; i += nth) {
    int ck = i / 6144, rem = i % 6144, n = rem >> 5, s = (rem >> 3) & 3, j = i & 7;
    int l = ck / 6;
    int k = (ck % 6) * 32 + 8 * (s ^ SWZ(n)) + j;
    ws[OFF_WQ + i] = f2bu_prep(rwq[l * 36864 + k * 192 + n]);
    ws[OFF_WO + i] = f2bu_prep(rwo[l * 36864 + k * 192 + n]);
  }
  for (int i = tid; i < 12288; i += nth) {
    int ck = i / 2048, rem = i % 2048, n = rem >> 5, s = (rem >> 3) & 3, j = i & 7;
    int k = ck * 32 + 8 * (s ^ SWZ(n)) + j;
    ws[OFF_GRID + i] = f2bu_prep(gr[n * 192 + k]);
  }
}

// ------- prep: K/V operand banks (plain layout, read from global) ---------
__global__ void prep_kv(const float* __restrict__ rwk, const float* __restrict__ rwv,
                        const float* __restrict__ rbk, const float* __restrict__ rbv,
                        const float* __restrict__ rmem, const float* __restrict__ gr,
                        ushort_t* __restrict__ kvf, float* __restrict__ ggn,
                        unsigned* __restrict__ cnt) {
  int tid = blockIdx.x * blockDim.x + threadIdx.x;
  int nth = gridDim.x * blockDim.x;
  // Kb[i][h][s(16)][k(64; k>=48 zero)]
  for (int idx = tid; idx < 12288; idx += nth) {
    int i = idx >> 12, r = idx & 4095, h = r >> 10, s = (r >> 6) & 15, k = r & 63;
    float val = 0.f;
    if (k < 48) {
      int d = h * 48 + k;
      const float* w = rwk + i * 36864;
      const float* mm = rmem + i * 3072 + s * 192;
      float acc = rbk[i * 192 + d];
      for (int kk = 0; kk < 192; ++kk) acc += mm[kk] * w[kk * 192 + d];
      val = acc;
    }
    kvf[i * 10240 + h * 1024 + s * 64 + k] = f2bu_prep(val);
  }
  // Vt[i][h][d(48)][s(32; s>=16 zero)]
  for (int idx = tid; idx < 18432; idx += nth) {
    int i = idx / 6144, r = idx % 6144, h = r / 1536, q = r % 1536, d = q >> 5, s = q & 31;
    float val = 0.f;
    if (s < 16) {
      int dd = h * 48 + d;
      const float* w = rwv + i * 36864;
      const float* mm = rmem + i * 3072 + s * 192;
      float acc = rbv[i * 192 + dd];
      for (int kk = 0; kk < 192; ++kk) acc += mm[kk] * w[kk * 192 + dd];
      val = acc;
    }
    kvf[i * 10240 + 4096 + h * 1536 + d * 32 + s] = f2bu_prep(val);
  }
  for (int g = tid; g < 64; g += nth) {
    const float* gp = gr + g * 192;
    float s = 0.f;
    for (int k = 0; k < 192; ++k) s += gp[k] * gp[k];
    ggn[g] = s;
    cnt[g] = 0u;
  }
}

// ---------------- main-kernel helpers (8-wave block) ----------------
__device__ __forceinline__ void stage_to(ushort_t* dst, const ushort_t* src, int nseg,
                                         int wave, int lane) {
  for (int s = wave; s < nseg; s += 8)
    gload16(src + (s << 9) + lane * 8, dst + (s << 9));
}

// consumption-order phase table; nseg in 1KB (512-ushort) segments
__device__ __forceinline__ const ushort_t* chunk_ptr(const ushort_t* wsu, int g, int* nseg) {
  if (g < 2)            { *nseg = 12; return wsu + OFF_VIB + g * 6144; }
  g -= 2;  if (g < 6)   { *nseg = 12; return wsu + OFF_FUS + g * 6144; }
  g -= 6;  if (g < 8)   { *nseg = 12; return wsu + OFF_ACO + g * 6144; }
  g -= 8;  if (g < 6)   { *nseg = 12; return wsu + OFF_FUS + 36864 + g * 6144; }
  g -= 6;  if (g < 4)   { *nseg = 12; return wsu + OFF_TMP + g * 6144; }
  g -= 4;  if (g < 6)   { *nseg = 12; return wsu + OFF_FUS + 73728 + g * 6144; }
  g -= 6;  if (g < 36)  { int l = g / 12, r2 = g - l * 12;
    *nseg = 12;
    return (r2 < 6) ? (wsu + OFF_WQ + l * 36864 + r2 * 6144)
                    : (wsu + OFF_WO + l * 36864 + (r2 - 6) * 6144); }
  g -= 36; if (g < 6)   { *nseg = 4; return wsu + OFF_GRID + g * 2048; }
  *nseg = 0; return wsu;
}

__device__ __forceinline__ void phase_begin(const ushort_t* wsu, ushort_t (*Wb)[6144],
                                            int gph, int wave, int lane) {
  __syncthreads();
  int nseg; const ushort_t* ns = chunk_ptr(wsu, gph + 1, &nseg);
  if (nseg) stage_to(&Wb[(gph + 1) & 1][0], ns, nseg, wave, lane);
}

__device__ __forceinline__ short8 cvt8(float4 a, float4 b) {
  short8 v;
  v[0] = (short)f2bu(a.x); v[1] = (short)f2bu(a.y); v[2] = (short)f2bu(a.z); v[3] = (short)f2bu(a.w);
  v[4] = (short)f2bu(b.x); v[5] = (short)f2bu(b.y); v[6] = (short)f2bu(b.z); v[7] = (short)f2bu(b.w);
  return v;
}

// encoder GEMM: A streamed from global (fp32), wave tile 16 rows x 96 cols
template<int NPH>
__device__ __forceinline__ void enc_gemm(const float* __restrict__ x, int row0,
    const ushort_t* wsu, ushort_t (*Wb)[6144], int* gph, f32x4* accE,
    int wc0, int m, int gq, int wave, int lane) {
  const int KF = NPH * 32;
  float4 ca0 = *(const float4*)(x + (size_t)row0 * KF + gq * 8);
  float4 ca1 = *(const float4*)(x + (size_t)row0 * KF + gq * 8 + 4);
#pragma unroll
  for (int ph = 0; ph < NPH; ++ph) {
    phase_begin(wsu, Wb, *gph, wave, lane);
    const ushort_t* Wc = &Wb[*gph & 1][0];
    short8 a0 = cvt8(ca0, ca1);
    if (ph + 1 < NPH) {
      int ko = (ph + 1) * 32 + gq * 8;
      ca0 = *(const float4*)(x + (size_t)row0 * KF + ko);
      ca1 = *(const float4*)(x + (size_t)row0 * KF + ko + 4);
    }
#pragma unroll
    for (int t = 0; t < 6; ++t) {
      int n = wc0 + t * 16 + m;
      short8 b = *(const short8*)(Wc + n * 32 + ((gq ^ SWZ(n)) << 3));
      accE[t] = MFMA16(a0, b, accE[t]);
    }
    ++*gph;
  }
}

// GEMM with A from the swizzled activation panel (6 phases, K=192)
__device__ __forceinline__ void lds_gemm(const ushort_t* Ab, const ushort_t* wsu,
    ushort_t (*Wb)[6144], int* gph, f32x4* acc, int wr0, int wc0, int m, int gq,
    int wave, int lane) {
#pragma unroll
  for (int ph = 0; ph < 6; ++ph) {
    phase_begin(wsu, Wb, *gph, wave, lane);
    const ushort_t* Wc = &Wb[*gph & 1][0];
    int r0 = wr0 + m;
    short8 a0 = *(const short8*)(Ab + r0 * 192 + (((ph * 4 + gq) ^ (r0 & 7)) << 3));
#pragma unroll
    for (int t = 0; t < 6; ++t) {
      int n = wc0 + t * 16 + m;
      short8 b = *(const short8*)(Wc + n * 32 + ((gq ^ SWZ(n)) << 3));
      acc[t] = MFMA16(a0, b, acc[t]);
    }
    ++*gph;
  }
}

// LN(+GELU) epilogue, col-split: cross-wave stats via LDS scratch
__device__ __forceinline__ void ln_gelu_cs(f32x4* acc, const float* __restrict__ bias,
    const float* __restrict__ gam, const float* __restrict__ bet,
    ushort_t* __restrict__ Ab, float2 (*scr)[2], int wr0, int wc0, int colh,
    int m, int gq) {
#pragma unroll
  for (int t = 0; t < 6; ++t) {
    float bv = bias[wc0 + t * 16 + m];
#pragma unroll
    for (int j = 0; j < 4; ++j) acc[t][j] += bv;
  }
#pragma unroll
  for (int j = 0; j < 4; ++j) {
    float s = 0.f, q = 0.f;
#pragma unroll
    for (int t = 0; t < 6; ++t) { float v = acc[t][j]; s += v; q += v * v; }
#pragma unroll
    for (int off = 1; off < 16; off <<= 1) {
      s += __shfl_xor(s, off, 64);
      q += __shfl_xor(q, off, 64);
    }
    if (m == 0) scr[wr0 + gq * 4 + j][colh] = (float2){s, q};
  }
  __syncthreads();
#pragma unroll
  for (int j = 0; j < 4; ++j) {
    int row = wr0 + gq * 4 + j;
    float2 h0 = scr[row][0], h1 = scr[row][1];
    float mean = (h0.x + h1.x) * (1.0f / 192.0f);
    float var = (h0.y + h1.y) * (1.0f / 192.0f) - mean * mean;
    float rstd = rsqrtf(var + 1e-5f);
#pragma unroll
    for (int t = 0; t < 6; ++t) {
      int col = wc0 + t * 16 + m;
      float y = (acc[t][j] - mean) * rstd * gam[col] + bet[col];
      Ab[row * 192 + ((((col >> 3) ^ (row & 7))) << 3) + (col & 7)] = f2bu(gelu_fast(y));
    }
  }
}

__device__ __forceinline__ void bias_store_cs(f32x4* acc, const float* __restrict__ bias,
    ushort_t* __restrict__ Ab, int wr0, int wc0, int m, int gq) {
#pragma unroll
  for (int t = 0; t < 6; ++t) {
    int col = wc0 + t * 16 + m;
    float bv = bias[col];
#pragma unroll
    for (int j = 0; j < 4; ++j) {
      int row = wr0 + gq * 4 + j;
      Ab[row * 192 + ((((col >> 3) ^ (row & 7))) << 3) + (col & 7)] = f2bu(acc[t][j] + bv);
    }
  }
}

// ---------------- main fused kernel ----------------
// R9: 512 threads / 8 waves; wave tile 16 rows x 96 cols. Acc co-live set
// halves to 48 regs -> ~110-120 total/wave -> 4 waves/SIMD; 2 blocks/CU
// = 16 waves/CU (50% occupancy), vs R8's 2-blocks-at-224-regs (23.6%).
__global__ __launch_bounds__(512) __attribute__((amdgpu_waves_per_eu(4))) void arn_main(
    const float* __restrict__ xv, const float* __restrict__ xa, const float* __restrict__ xt,
    const ushort_t* __restrict__ wsu, const ushort_t* __restrict__ kvf,
    const float* __restrict__ ggn, unsigned* __restrict__ counts,
    const float* __restrict__ ebv, const float* __restrict__ egv, const float* __restrict__ ebbv,
    const float* __restrict__ eba, const float* __restrict__ ega, const float* __restrict__ ebba,
    const float* __restrict__ ebt, const float* __restrict__ egt, const float* __restrict__ ebbt,
    const float* __restrict__ fb, const float* __restrict__ fg, const float* __restrict__ fbb,
    const float* __restrict__ rbq, const float* __restrict__ rbo) {
  __shared__ __align__(16) ushort_t Abuf[64 * 192 + 64];  // swizzled activations + zero pad
  __shared__ __align__(16) ushort_t Wbuf[2][6144];        // double-buffered W chunks
  __shared__ float2 lnscr[64][2];
  __shared__ float c_l[64];
  __shared__ unsigned hist[64];

  const int tid = threadIdx.x, lane = tid & 63, wave = tid >> 6;
  const int m = lane & 15, gq = lane >> 4;
  const int wrg = wave & 3;              // row group (16 rows)
  const int wr0 = wrg * 16;
  const int colh = wave >> 2;            // col half
  const int wc0 = colh * 96;
  const int growbase = blockIdx.x * 64;

  if (tid < 64) { hist[tid] = 0u; c_l[tid] = 0.5f * ggn[tid]; Abuf[12288 + tid] = 0; }

  int gph = 0;
  { int nseg; const ushort_t* s0 = chunk_ptr(wsu, 0, &nseg); stage_to(&Wbuf[0][0], s0, nseg, wave, lane); }

  const int row0 = growbase + wr0 + m;
  f32x4 accF[6];
#pragma unroll
  for (int t = 0; t < 6; ++t) accF[t] = (f32x4){0.f, 0.f, 0.f, 0.f};

  // ===== vib encoder + fus part 0 =====
  {
    f32x4 accE[6];
#pragma unroll
    for (int t = 0; t < 6; ++t) accE[t] = (f32x4){0.f, 0.f, 0.f, 0.f};
    enc_gemm<2>(xv, row0, wsu, Wbuf, &gph, accE, wc0, m, gq, wave, lane);
    ln_gelu_cs(accE, ebv, egv, ebbv, Abuf, lnscr, wr0, wc0, colh, m, gq);
  }
  lds_gemm(Abuf, wsu, Wbuf, &gph, accF, wr0, wc0, m, gq, wave, lane);

  // ===== aco encoder + fus part 1 =====
  {
    f32x4 accE[6];
#pragma unroll
    for (int t = 0; t < 6; ++t) accE[t] = (f32x4){0.f, 0.f, 0.f, 0.f};
    enc_gemm<8>(xa, row0, wsu, Wbuf, &gph, accE, wc0, m, gq, wave, lane);
    ln_gelu_cs(accE, eba, ega, ebba, Abuf, lnscr, wr0, wc0, colh, m, gq);
  }
  lds_gemm(Abuf, wsu, Wbuf, &gph, accF, wr0, wc0, m, gq, wave, lane);

  // ===== tmp encoder + fus part 2 + fusion LN =====
  {
    f32x4 accE[6];
#pragma unroll
    for (int t = 0; t < 6; ++t) accE[t] = (f32x4){0.f, 0.f, 0.f, 0.f};
    enc_gemm<4>(xt, row0, wsu, Wbuf, &gph, accE, wc0, m, gq, wave, lane);
    ln_gelu_cs(accE, ebt, egt, ebbt, Abuf, lnscr, wr0, wc0, colh, m, gq);
  }
  lds_gemm(Abuf, wsu, Wbuf, &gph, accF, wr0, wc0, m, gq, wave, lane);
  ln_gelu_cs(accF, fb, fg, fbb, Abuf, lnscr, wr0, wc0, colh, m, gq);

  // ===== 3 resonance layers =====
  for (int i = 0; i < 3; ++i) {
    {
      f32x4 accQ[6];
#pragma unroll
      for (int t = 0; t < 6; ++t) accQ[t] = (f32x4){0.f, 0.f, 0.f, 0.f};
      lds_gemm(Abuf, wsu, Wbuf, &gph, accQ, wr0, wc0, m, gq, wave, lane);
      bias_store_cs(accQ, rbq + i * 192, Abuf, wr0, wc0, m, gq);
    }
    __syncthreads();  // Q fully written; in-flight prefetch targets Wbuf[0]
    {
      const ushort_t* kvl = kvf + i * 10240;
      ushort_t* Pw = &Wbuf[1][0] + wave * 512;  // per-wave P [16 rows][32 slots]
      // zero pad slots 16..31 (8B per lane)
      *(uint2*)(Pw + (lane >> 2) * 32 + 16 + (lane & 3) * 4) = (uint2){0u, 0u};
      const float scale = 0.144337567297406441f;  // 1/sqrt(48)
#pragma unroll
      for (int hh = 0; hh < 2; ++hh) {
        int h = colh * 2 + hh;  // wave handles 2 heads
        f32x4 s4 = (f32x4){0.f, 0.f, 0.f, 0.f};
#pragma unroll
        for (int ks = 0; ks < 2; ++ks) {
          int kg = h * 6 + ks * 4 + gq;
          int r = wr0 + m;
          short8 a = *(const short8*)(Abuf + r * 192 + ((kg ^ (r & 7)) << 3));
          short8 b = *(const short8*)(kvl + h * 1024 + m * 64 + ks * 32 + gq * 8);
          s4 = MFMA16(a, b, s4);
        }
#pragma unroll
        for (int j = 0; j < 4; ++j) {
          float v = s4[j] * scale;
          float mx = v;
          mx = fmaxf(mx, __shfl_xor(mx, 1, 64));
          mx = fmaxf(mx, __shfl_xor(mx, 2, 64));
          mx = fmaxf(mx, __shfl_xor(mx, 4, 64));
          mx = fmaxf(mx, __shfl_xor(mx, 8, 64));
          float e = exp2f((v - mx) * 1.44269504f);
          float sm = e;
          sm += __shfl_xor(sm, 1, 64);
          sm += __shfl_xor(sm, 2, 64);
          sm += __shfl_xor(sm, 4, 64);
          sm += __shfl_xor(sm, 8, 64);
          Pw[(gq * 4 + j) * 32 + m] = f2bu(e * fastrcp(sm));
        }
        short8 pa = *(const short8*)(Pw + m * 32 + gq * 8);
#pragma unroll
        for (int t = 0; t < 3; ++t) {
          short8 vb = *(const short8*)(kvl + 4096 + h * 1536 + (t * 16 + m) * 32 + gq * 8);
          f32x4 o4 = MFMA16(pa, vb, ((f32x4){0.f, 0.f, 0.f, 0.f}));
          int col = h * 48 + t * 16 + m;
#pragma unroll
          for (int j = 0; j < 4; ++j) {
            int row = wr0 + gq * 4 + j;
            Abuf[row * 192 + ((((col >> 3) ^ (row & 7))) << 3) + (col & 7)] = f2bu(o4[j]);
          }
        }
      }
    }
    {
      f32x4 accO[6];
#pragma unroll
      for (int t = 0; t < 6; ++t) accO[t] = (f32x4){0.f, 0.f, 0.f, 0.f};
      lds_gemm(Abuf, wsu, Wbuf, &gph, accO, wr0, wc0, m, gq, wave, lane);
      bias_store_cs(accO, rbo + i * 192, Abuf, wr0, wc0, m, gq);
    }
  }

  // ===== SOFM: argmax_g (f.g - ||g||^2/2) -> histogram =====
  {
    f32x4 accS[4];
#pragma unroll
    for (int t = 0; t < 4; ++t) accS[t] = (f32x4){0.f, 0.f, 0.f, 0.f};
#pragma unroll
    for (int ph = 0; ph < 6; ++ph) {
      phase_begin(wsu, Wbuf, gph, wave, lane);
      const ushort_t* Wc = &Wbuf[gph & 1][0];
      int r0 = wr0 + m;
      short8 a0 = *(const short8*)(Abuf + r0 * 192 + (((ph * 4 + gq) ^ (r0 & 7)) << 3));
#pragma unroll
      for (int nt = 0; nt < 4; ++nt) {
        int n = nt * 16 + m;
        short8 b = *(const short8*)(Wc + n * 32 + ((gq ^ SWZ(n)) << 3));
        accS[nt] = MFMA16(a0, b, accS[nt]);
      }
      ++gph;
    }
#pragma unroll
    for (int j = 0; j < 4; ++j) {
      float bv = -3.0e38f; int bi = 0;
#pragma unroll
      for (int nt = 0; nt < 4; ++nt) {
        int g = nt * 16 + m;
        float v = accS[nt][j] - c_l[g];
        bool take = (v > bv);
        bv = take ? v : bv; bi = take ? g : bi;
      }
#pragma unroll
      for (int off = 1; off < 16; off <<= 1) {
        float ov = __shfl_xor(bv, off, 64);
        int oi = __shfl_xor(bi, off, 64);
        bool take = (ov > bv) || (ov == bv && oi < bi);
        bv = take ? ov : bv; bi = take ? oi : bi;
      }
      // both col-half waves compute the same rows' argmax; only colh==0 counts
      if (m == 0 && colh == 0) atomicAdd(&hist[bi], 1u);
    }
  }
  __syncthreads();
  if (tid < 64 && hist[tid]) atomicAdd(&counts[tid], hist[tid]);
}

// ---------------- finisher ----------------
__global__ void arn_finish(const unsigned* __restrict__ counts, const float* __restrict__ gr,
                           const float* __restrict__ ow, const float* __restrict__ ob,
                           float* __restrict__ out) {
  __shared__ float pooled[192];
  __shared__ float cf[64];
  int t = threadIdx.x;
  if (t < 64) cf[t] = (float)counts[t];
  __syncthreads();
  float s = 0.f;
  for (int g = 0; g < 64; ++g) s += cf[g] * gr[g * 192 + t];
  pooled[t] = s * (1.0f / (float)B_TOTAL);
  __syncthreads();
  if (t < 6) {
    float o = ob[t];
    for (int j = 0; j < 192; ++j) o += pooled[j] * ow[j * 6 + t];
    out[t] = (t == 1) ? fmaxf(o, 0.f) : 1.f / (1.f + expf(-o));
  }
}

// ---------------- launch ----------------
extern "C" void kernel_launch(void* const* d_in, const int* in_sizes, int n_in,
                              void* d_out, int out_size, void* d_ws, size_t ws_size,
                              hipStream_t stream) {
  (void)in_sizes; (void)n_in; (void)out_size; (void)ws_size;
  const float* xv   = (const float*)d_in[0];
  const float* xa   = (const float*)d_in[1];
  const float* xt   = (const float*)d_in[2];
  const float* ewv  = (const float*)d_in[3];
  const float* ebv  = (const float*)d_in[4];
  const float* egv  = (const float*)d_in[5];
  const float* ebbv = (const float*)d_in[6];
  const float* ewa  = (const float*)d_in[7];
  const float* eba  = (const float*)d_in[8];
  const float* ega  = (const float*)d_in[9];
  const float* ebba = (const float*)d_in[10];
  const float* ewt  = (const float*)d_in[11];
  const float* ebt  = (const float*)d_in[12];
  const float* egt  = (const float*)d_in[13];
  const float* ebbt = (const float*)d_in[14];
  const float* fw   = (const float*)d_in[15];
  const float* fb   = (const float*)d_in[16];
  const float* fg   = (const float*)d_in[17];
  const float* fbb  = (const float*)d_in[18];
  const float* rwq  = (const float*)d_in[19];
  const float* rwk  = (const float*)d_in[20];
  const float* rwv  = (const float*)d_in[21];
  const float* rwo  = (const float*)d_in[22];
  const float* rbq  = (const float*)d_in[23];
  const float* rbk  = (const float*)d_in[24];
  const float* rbv  = (const float*)d_in[25];
  const float* rbo  = (const float*)d_in[26];
  const float* rmem = (const float*)d_in[27];
  const float* grid = (const float*)d_in[28];
  const float* ow   = (const float*)d_in[29];
  const float* ob   = (const float*)d_in[30];

  ushort_t* wsu = (ushort_t*)d_ws;
  ushort_t* kvf = wsu + OFF_KV;
  float* wsf = (float*)((char*)d_ws + F32_BYTE_OFF);
  float* ggn = wsf;
  unsigned* cnt = (unsigned*)(wsf + 64);

  prep_weights<<<dim3(256), dim3(256), 0, stream>>>(ewv, ewa, ewt, fw, rwq, rwo, grid, wsu);
  prep_kv<<<dim3(120), dim3(256), 0, stream>>>(rwk, rwv, rbk, rbv, rmem, grid, kvf, ggn, cnt);
  arn_main<<<dim3(2048), dim3(512), 0, stream>>>(xv, xa, xt, wsu, kvf, ggn, cnt,
      ebv, egv, ebbv, eba, ega, ebba, ebt, egt, ebbt, fb, fg, fbb, rbq, rbo);
  arn_finish<<<dim3(1), dim3(192), 0, stream>>>(cnt, grid, ow, ob, (float*)d_out);
}

// Round 10
// 376.488 us; speedup vs baseline: 1.6841x; 1.6841x over previous
//
#include <hip/hip_runtime.h>
#include <hip/hip_bf16.h>
#include <math.h>

typedef unsigned short ushort_t;
typedef __attribute__((ext_vector_type(8))) short short8;
typedef __attribute__((ext_vector_type(4))) float f32x4;

#define B_TOTAL 131072

// ws layout (ushort element offsets). W blobs are K64-split chunk-major:
// chunk = [N rows][64 k]; storage (n, s, j) holds logical k = ck*64 + 8*(s ^ (n&7)) + j.
// Staged linearly via global_load_lds (24 x 1KB segments per chunk; grid chunks 8).
#define OFF_VIB 0        // 1 chunk  [192][64]  = 12288
#define OFF_ACO 12288    // 4 chunks             = 49152
#define OFF_TMP 61440    // 2 chunks             = 24576
#define OFF_FUS 86016    // 9 chunks (3/part)    = 110592
#define OFF_WQ 196608    // 9 chunks (3/layer)
#define OFF_WO 307200    // 9 chunks
#define OFF_GRID 417792  // 3 chunks [64][64]    = 12288
#define OFF_KV 430080    // 3 layers x 10240: Kb[4h][16s][64k] + Vt[4h][48d][32s]
#define F32_BYTE_OFF 921600

// prep kernels: explicit RTNE bit-twiddle (cold code)
__device__ __forceinline__ ushort_t f2bu_prep(float f) {
  union { float f; unsigned u; } c; c.f = f;
  unsigned u = c.u;
  unsigned r = (u + 0x7fffu + ((u >> 16) & 1u)) >> 16;  // RTNE
  return (ushort_t)r;
}
// hot kernel: v_cvt bf16 (RTNE on gfx950)
__device__ __forceinline__ ushort_t f2bu(float f) {
  __hip_bfloat16 h = __float2bfloat16(f);
  return *(ushort_t*)&h;
}
__device__ __forceinline__ float fastrcp(float x) { return __builtin_amdgcn_rcpf(x); }
__device__ __forceinline__ float gelu_fast(float x) {
  float u = 0.7978845608f * x * (1.0f + 0.044715f * x * x);
  float E = exp2f(2.88539008f * u);
  float t = 1.0f - 2.0f * fastrcp(E + 1.0f);
  return 0.5f * x * (1.0f + t);
}
#define MFMA16(a, b, c) __builtin_amdgcn_mfma_f32_16x16x32_bf16(a, b, c, 0, 0, 0)

__device__ __forceinline__ void gload16(const void* g, void* l) {
  __builtin_amdgcn_global_load_lds((const __attribute__((address_space(1))) void*)g,
                                   (__attribute__((address_space(3))) void*)l, 16, 0, 0);
}

// ---------------- prep: weights -> K64-split swizzled chunks ----------------
__global__ void prep_weights(const float* __restrict__ ev, const float* __restrict__ ea,
                             const float* __restrict__ et, const float* __restrict__ fw,
                             const float* __restrict__ rwq, const float* __restrict__ rwo,
                             const float* __restrict__ gr, ushort_t* __restrict__ ws) {
  int tid = blockIdx.x * blockDim.x + threadIdx.x;
  int nth = gridDim.x * blockDim.x;
  // vib: 1 chunk [192][64]; src ev [64][192]
  for (int i = tid; i < 12288; i += nth) {
    int n = i >> 6, kin = i & 63;
    int k = 8 * ((kin >> 3) ^ (n & 7)) + (kin & 7);
    ws[OFF_VIB + i] = f2bu_prep(ev[k * 192 + n]);
  }
  // aco: 4 chunks; src ea [256][192]
  for (int i = tid; i < 49152; i += nth) {
    int ck = i / 12288, rem = i % 12288, n = rem >> 6, kin = rem & 63;
    int k = ck * 64 + 8 * ((kin >> 3) ^ (n & 7)) + (kin & 7);
    ws[OFF_ACO + i] = f2bu_prep(ea[k * 192 + n]);
  }
  // tmp: 2 chunks; src et [128][192]
  for (int i = tid; i < 24576; i += nth) {
    int ck = i / 12288, rem = i % 12288, n = rem >> 6, kin = rem & 63;
    int k = ck * 64 + 8 * ((kin >> 3) ^ (n & 7)) + (kin & 7);
    ws[OFF_TMP + i] = f2bu_prep(et[k * 192 + n]);
  }
  // fus: 9 chunks; src fw [576][192]
  for (int i = tid; i < 110592; i += nth) {
    int ck = i / 12288, rem = i % 12288, n = rem >> 6, kin = rem & 63;
    int k = ck * 64 + 8 * ((kin >> 3) ^ (n & 7)) + (kin & 7);
    ws[OFF_FUS + i] = f2bu_prep(fw[k * 192 + n]);
  }
  // wq/wo: 3 chunks per layer
  for (int i = tid; i < 110592; i += nth) {
    int ck = i / 12288, rem = i % 12288, n = rem >> 6, kin = rem & 63;
    int l = ck / 3;
    int k = (ck % 3) * 64 + 8 * ((kin >> 3) ^ (n & 7)) + (kin & 7);
    ws[OFF_WQ + i] = f2bu_prep(rwq[l * 36864 + k * 192 + n]);
    ws[OFF_WO + i] = f2bu_prep(rwo[l * 36864 + k * 192 + n]);
  }
  // grid: 3 chunks [64][64]; src gr [64][192] (B[n=g][k=d])
  for (int i = tid; i < 12288; i += nth) {
    int ck = i / 4096, rem = i % 4096, n = rem >> 6, kin = rem & 63;
    int k = ck * 64 + 8 * ((kin >> 3) ^ (n & 7)) + (kin & 7);
    ws[OFF_GRID + i] = f2bu_prep(gr[n * 192 + k]);
  }
}

// ------- prep: K/V operand banks (plain layout, read from global) ---------
__global__ void prep_kv(const float* __restrict__ rwk, const float* __restrict__ rwv,
                        const float* __restrict__ rbk, const float* __restrict__ rbv,
                        const float* __restrict__ rmem, const float* __restrict__ gr,
                        ushort_t* __restrict__ kvf, float* __restrict__ ggn,
                        unsigned* __restrict__ cnt) {
  int tid = blockIdx.x * blockDim.x + threadIdx.x;
  int nth = gridDim.x * blockDim.x;
  // Kb[i][h][s(16)][k(64; k>=48 zero)]
  for (int idx = tid; idx < 12288; idx += nth) {
    int i = idx >> 12, r = idx & 4095, h = r >> 10, s = (r >> 6) & 15, k = r & 63;
    float val = 0.f;
    if (k < 48) {
      int d = h * 48 + k;
      const float* w = rwk + i * 36864;
      const float* mm = rmem + i * 3072 + s * 192;
      float acc = rbk[i * 192 + d];
      for (int kk = 0; kk < 192; ++kk) acc += mm[kk] * w[kk * 192 + d];
      val = acc;
    }
    kvf[i * 10240 + h * 1024 + s * 64 + k] = f2bu_prep(val);
  }
  // Vt[i][h][d(48)][s(32; s>=16 zero)]
  for (int idx = tid; idx < 18432; idx += nth) {
    int i = idx / 6144, r = idx % 6144, h = r / 1536, q = r % 1536, d = q >> 5, s = q & 31;
    float val = 0.f;
    if (s < 16) {
      int dd = h * 48 + d;
      const float* w = rwv + i * 36864;
      const float* mm = rmem + i * 3072 + s * 192;
      float acc = rbv[i * 192 + dd];
      for (int kk = 0; kk < 192; ++kk) acc += mm[kk] * w[kk * 192 + dd];
      val = acc;
    }
    kvf[i * 10240 + 4096 + h * 1536 + d * 32 + s] = f2bu_prep(val);
  }
  for (int g = tid; g < 64; g += nth) {
    const float* gp = gr + g * 192;
    float s = 0.f;
    for (int k = 0; k < 192; ++k) s += gp[k] * gp[k];
    ggn[g] = s;
    cnt[g] = 0u;
  }
}

// ---------------- main-kernel helpers (4-wave block, K64 chunks) ----------------
__device__ __forceinline__ void stage_to(ushort_t* dst, const ushort_t* src, int nseg,
                                         int wave, int lane) {
  for (int s = wave; s < nseg; s += 4)
    gload16(src + (s << 9) + lane * 8, dst + (s << 9));
}

// consumption-order phase table (37 phases); nseg in 1KB segments
__device__ __forceinline__ const ushort_t* chunk_ptr(const ushort_t* wsu, int g, int* nseg) {
  *nseg = 24;
  if (g < 1)            return wsu + OFF_VIB;
  g -= 1;  if (g < 3)   return wsu + OFF_FUS + g * 12288;
  g -= 3;  if (g < 4)   return wsu + OFF_ACO + g * 12288;
  g -= 4;  if (g < 3)   return wsu + OFF_FUS + 36864 + g * 12288;
  g -= 3;  if (g < 2)   return wsu + OFF_TMP + g * 12288;
  g -= 2;  if (g < 3)   return wsu + OFF_FUS + 73728 + g * 12288;
  g -= 3;  if (g < 18)  { int l = g / 6, r2 = g - l * 6;
    return (r2 < 3) ? (wsu + OFF_WQ + l * 36864 + r2 * 12288)
                    : (wsu + OFF_WO + l * 36864 + (r2 - 3) * 12288); }
  g -= 18; if (g < 3)   { *nseg = 8; return wsu + OFF_GRID + g * 4096; }
  *nseg = 0; return wsu;
}

__device__ __forceinline__ void phase_begin(const ushort_t* wsu, ushort_t (*Wb)[12288],
                                            int gph, int wave, int lane) {
  __syncthreads();
  int nseg; const ushort_t* ns = chunk_ptr(wsu, gph + 1, &nseg);
  if (nseg) stage_to(&Wb[(gph + 1) & 1][0], ns, nseg, wave, lane);
}

__device__ __forceinline__ short8 cvt8(float4 a, float4 b) {
  short8 v;
  v[0] = (short)f2bu(a.x); v[1] = (short)f2bu(a.y); v[2] = (short)f2bu(a.z); v[3] = (short)f2bu(a.w);
  v[4] = (short)f2bu(b.x); v[5] = (short)f2bu(b.y); v[6] = (short)f2bu(b.z); v[7] = (short)f2bu(b.w);
  return v;
}

// encoder GEMM: A streamed from global (fp32), rolling 32-k register prefetch.
// NPH = K/64 phases; wave tile 32 rows x 96 cols.
template<int NPH>
__device__ __forceinline__ void enc_gemm(const float* __restrict__ x, int row0, int row1,
    const ushort_t* wsu, ushort_t (*Wb)[12288], int* gph, f32x4* accE,
    int wc0, int m, int gq, int wave, int lane) {
  const int KF = NPH * 64;
  const float* p0 = x + (size_t)row0 * KF + gq * 8;
  const float* p1 = x + (size_t)row1 * KF + gq * 8;
  float4 ca0 = *(const float4*)(p0);
  float4 ca1 = *(const float4*)(p0 + 4);
  float4 cb0 = *(const float4*)(p1);
  float4 cb1 = *(const float4*)(p1 + 4);
#pragma unroll
  for (int ph = 0; ph < NPH; ++ph) {
    phase_begin(wsu, Wb, *gph, wave, lane);
    const ushort_t* Wc = &Wb[*gph & 1][0];
#pragma unroll
    for (int ks = 0; ks < 2; ++ks) {
      short8 a0 = cvt8(ca0, ca1);
      short8 a1 = cvt8(cb0, cb1);
      int nk = ph * 64 + ks * 32 + 32;
      if (nk < KF) {
        ca0 = *(const float4*)(p0 + nk);
        ca1 = *(const float4*)(p0 + nk + 4);
        cb0 = *(const float4*)(p1 + nk);
        cb1 = *(const float4*)(p1 + nk + 4);
      }
#pragma unroll
      for (int t = 0; t < 6; ++t) {
        int n = wc0 + t * 16 + m;
        short8 b = *(const short8*)(Wc + n * 64 + ((((ks << 2) + gq) ^ (n & 7)) << 3));
        accE[t]     = MFMA16(a0, b, accE[t]);
        accE[6 + t] = MFMA16(a1, b, accE[6 + t]);
      }
    }
    ++*gph;
  }
}

// GEMM with A from the swizzled activation panel (3 phases, K=192)
__device__ __forceinline__ void lds_gemm(const ushort_t* Ab, const ushort_t* wsu,
    ushort_t (*Wb)[12288], int* gph, f32x4* acc, int wr0, int wc0, int m, int gq,
    int wave, int lane) {
#pragma unroll
  for (int ph = 0; ph < 3; ++ph) {
    phase_begin(wsu, Wb, *gph, wave, lane);
    const ushort_t* Wc = &Wb[*gph & 1][0];
    int r0 = wr0 + m, r1 = wr0 + 16 + m;
#pragma unroll
    for (int ks = 0; ks < 2; ++ks) {
      int sl = (ks << 2) + gq;
      short8 a0 = *(const short8*)(Ab + r0 * 192 + ((ph * 8 + (sl ^ (r0 & 7))) << 3));
      short8 a1 = *(const short8*)(Ab + r1 * 192 + ((ph * 8 + (sl ^ (r1 & 7))) << 3));
#pragma unroll
      for (int t = 0; t < 6; ++t) {
        int n = wc0 + t * 16 + m;
        short8 b = *(const short8*)(Wc + n * 64 + ((sl ^ (n & 7)) << 3));
        acc[t]     = MFMA16(a0, b, acc[t]);
        acc[6 + t] = MFMA16(a1, b, acc[6 + t]);
      }
    }
    ++*gph;
  }
}

// LN(+GELU) epilogue, col-split: cross-wave stats via 1KB scratch
__device__ __forceinline__ void ln_gelu_cs(f32x4* acc, const float* __restrict__ bias,
    const float* __restrict__ gam, const float* __restrict__ bet,
    ushort_t* __restrict__ Ab, float2 (*scr)[2], int wr0, int wc0, int colh,
    int m, int gq) {
#pragma unroll
  for (int t = 0; t < 12; ++t) {
    float bv = bias[wc0 + (t % 6) * 16 + m];
#pragma unroll
    for (int j = 0; j < 4; ++j) acc[t][j] += bv;
  }
#pragma unroll
  for (int mt = 0; mt < 2; ++mt)
#pragma unroll
    for (int j = 0; j < 4; ++j) {
      float s = 0.f, q = 0.f;
#pragma unroll
      for (int t = 0; t < 6; ++t) { float v = acc[mt * 6 + t][j]; s += v; q += v * v; }
#pragma unroll
      for (int off = 1; off < 16; off <<= 1) {
        s += __shfl_xor(s, off, 64);
        q += __shfl_xor(q, off, 64);
      }
      if (m == 0) scr[wr0 + mt * 16 + gq * 4 + j][colh] = (float2){s, q};
    }
  __syncthreads();
#pragma unroll
  for (int mt = 0; mt < 2; ++mt)
#pragma unroll
    for (int j = 0; j < 4; ++j) {
      int row = wr0 + mt * 16 + gq * 4 + j;
      float2 h0 = scr[row][0], h1 = scr[row][1];
      float mean = (h0.x + h1.x) * (1.0f / 192.0f);
      float var = (h0.y + h1.y) * (1.0f / 192.0f) - mean * mean;
      float rstd = rsqrtf(var + 1e-5f);
#pragma unroll
      for (int t = 0; t < 6; ++t) {
        int col = wc0 + t * 16 + m;
        float y = (acc[mt * 6 + t][j] - mean) * rstd * gam[col] + bet[col];
        Ab[row * 192 + ((((col >> 3) ^ (row & 7))) << 3) + (col & 7)] = f2bu(gelu_fast(y));
      }
    }
}

__device__ __forceinline__ void bias_store_cs(f32x4* acc, const float* __restrict__ bias,
    ushort_t* __restrict__ Ab, int wr0, int wc0, int m, int gq) {
#pragma unroll
  for (int mt = 0; mt < 2; ++mt)
#pragma unroll
    for (int t = 0; t < 6; ++t) {
      int col = wc0 + t * 16 + m;
      float bv = bias[col];
#pragma unroll
      for (int j = 0; j < 4; ++j) {
        int row = wr0 + mt * 16 + gq * 4 + j;
        Ab[row * 192 + ((((col >> 3) ^ (row & 7))) << 3) + (col & 7)] =
            f2bu(acc[mt * 6 + t][j] + bv);
      }
    }
}

// ---------------- main fused kernel ----------------
// R10: K64 chunks -> 37 phases (vs 74). Per-phase MFMA doubles (12/wave), so
// the barrier vmcnt-drain latency is exposed half as often. Registers stay in
// the R8 regime (accE12+accF12, waves_per_eu(2) floor -> no spill).
__global__ __launch_bounds__(256) __attribute__((amdgpu_waves_per_eu(2))) void arn_main(
    const float* __restrict__ xv, const float* __restrict__ xa, const float* __restrict__ xt,
    const ushort_t* __restrict__ wsu, const ushort_t* __restrict__ kvf,
    const float* __restrict__ ggn, unsigned* __restrict__ counts,
    const float* __restrict__ ebv, const float* __restrict__ egv, const float* __restrict__ ebbv,
    const float* __restrict__ eba, const float* __restrict__ ega, const float* __restrict__ ebba,
    const float* __restrict__ ebt, const float* __restrict__ egt, const float* __restrict__ ebbt,
    const float* __restrict__ fb, const float* __restrict__ fg, const float* __restrict__ fbb,
    const float* __restrict__ rbq, const float* __restrict__ rbo) {
  __shared__ __align__(16) ushort_t Abuf[64 * 192 + 64];  // swizzled activations + zero pad
  __shared__ __align__(16) ushort_t Wbuf[2][12288];       // double-buffered K64 W chunks
  __shared__ float2 lnscr[64][2];
  __shared__ float c_l[64];
  __shared__ unsigned hist[64];

  const int tid = threadIdx.x, lane = tid & 63, wave = tid >> 6;
  const int m = lane & 15, gq = lane >> 4;
  const int wr0 = (wave & 1) * 32;       // GEMM row half
  const int wc0 = (wave >> 1) * 96;      // GEMM col half
  const int colh = wave >> 1;
  const int aw0 = wave * 16;             // attention row base
  const int growbase = blockIdx.x * 64;

  if (tid < 64) { hist[tid] = 0u; c_l[tid] = 0.5f * ggn[tid]; Abuf[12288 + tid] = 0; }

  int gph = 0;
  { int nseg; const ushort_t* s0 = chunk_ptr(wsu, 0, &nseg); stage_to(&Wbuf[0][0], s0, nseg, wave, lane); }

  const int row0 = growbase + wr0 + m, row1 = row0 + 16;
  f32x4 accF[12];
#pragma unroll
  for (int t = 0; t < 12; ++t) accF[t] = (f32x4){0.f, 0.f, 0.f, 0.f};

  // ===== vib encoder + fus part 0 =====
  {
    f32x4 accE[12];
#pragma unroll
    for (int t = 0; t < 12; ++t) accE[t] = (f32x4){0.f, 0.f, 0.f, 0.f};
    enc_gemm<1>(xv, row0, row1, wsu, Wbuf, &gph, accE, wc0, m, gq, wave, lane);
    ln_gelu_cs(accE, ebv, egv, ebbv, Abuf, lnscr, wr0, wc0, colh, m, gq);
  }
  lds_gemm(Abuf, wsu, Wbuf, &gph, accF, wr0, wc0, m, gq, wave, lane);

  // ===== aco encoder + fus part 1 =====
  {
    f32x4 accE[12];
#pragma unroll
    for (int t = 0; t < 12; ++t) accE[t] = (f32x4){0.f, 0.f, 0.f, 0.f};
    enc_gemm<4>(xa, row0, row1, wsu, Wbuf, &gph, accE, wc0, m, gq, wave, lane);
    ln_gelu_cs(accE, eba, ega, ebba, Abuf, lnscr, wr0, wc0, colh, m, gq);
  }
  lds_gemm(Abuf, wsu, Wbuf, &gph, accF, wr0, wc0, m, gq, wave, lane);

  // ===== tmp encoder + fus part 2 + fusion LN =====
  {
    f32x4 accE[12];
#pragma unroll
    for (int t = 0; t < 12; ++t) accE[t] = (f32x4){0.f, 0.f, 0.f, 0.f};
    enc_gemm<2>(xt, row0, row1, wsu, Wbuf, &gph, accE, wc0, m, gq, wave, lane);
    ln_gelu_cs(accE, ebt, egt, ebbt, Abuf, lnscr, wr0, wc0, colh, m, gq);
  }
  lds_gemm(Abuf, wsu, Wbuf, &gph, accF, wr0, wc0, m, gq, wave, lane);
  ln_gelu_cs(accF, fb, fg, fbb, Abuf, lnscr, wr0, wc0, colh, m, gq);

  // ===== 3 resonance layers =====
  for (int i = 0; i < 3; ++i) {
    {
      f32x4 accQ[12];
#pragma unroll
      for (int t = 0; t < 12; ++t) accQ[t] = (f32x4){0.f, 0.f, 0.f, 0.f};
      lds_gemm(Abuf, wsu, Wbuf, &gph, accQ, wr0, wc0, m, gq, wave, lane);
      bias_store_cs(accQ, rbq + i * 192, Abuf, wr0, wc0, m, gq);
    }
    __syncthreads();  // Q visible to all waves
    {
      // P scratch lives in Wbuf[0]: the last wq phase index is even for every
      // layer, so the in-flight prefetch (first wo chunk) targets Wbuf[1].
      const ushort_t* kvl = kvf + i * 10240;
      ushort_t* Pw = &Wbuf[0][0] + wave * 512;  // [16 rows][32 slots]
      // zero pad slots 16..31 (8B per lane)
      *(uint2*)(Pw + (lane >> 2) * 32 + 16 + (lane & 3) * 4) = (uint2){0u, 0u};
      const float scale = 0.144337567297406441f;  // 1/sqrt(48)
#pragma unroll
      for (int h = 0; h < 4; ++h) {
        f32x4 s4 = (f32x4){0.f, 0.f, 0.f, 0.f};
#pragma unroll
        for (int ks = 0; ks < 2; ++ks) {
          int kg = h * 6 + ks * 4 + gq;
          int r = aw0 + m;
          short8 a = *(const short8*)(Abuf + r * 192 + ((kg ^ (r & 7)) << 3));
          short8 b = *(const short8*)(kvl + h * 1024 + m * 64 + ks * 32 + gq * 8);
          s4 = MFMA16(a, b, s4);
        }
#pragma unroll
        for (int j = 0; j < 4; ++j) {
          float v = s4[j] * scale;
          float mx = v;
          mx = fmaxf(mx, __shfl_xor(mx, 1, 64));
          mx = fmaxf(mx, __shfl_xor(mx, 2, 64));
          mx = fmaxf(mx, __shfl_xor(mx, 4, 64));
          mx = fmaxf(mx, __shfl_xor(mx, 8, 64));
          float e = exp2f((v - mx) * 1.44269504f);
          float sm = e;
          sm += __shfl_xor(sm, 1, 64);
          sm += __shfl_xor(sm, 2, 64);
          sm += __shfl_xor(sm, 4, 64);
          sm += __shfl_xor(sm, 8, 64);
          Pw[(gq * 4 + j) * 32 + m] = f2bu(e * fastrcp(sm));
        }
        short8 pa = *(const short8*)(Pw + m * 32 + gq * 8);
#pragma unroll
        for (int t = 0; t < 3; ++t) {
          short8 vb = *(const short8*)(kvl + 4096 + h * 1536 + (t * 16 + m) * 32 + gq * 8);
          f32x4 o4 = MFMA16(pa, vb, ((f32x4){0.f, 0.f, 0.f, 0.f}));
          int col = h * 48 + t * 16 + m;
#pragma unroll
          for (int j = 0; j < 4; ++j) {
            int row = aw0 + gq * 4 + j;
            Abuf[row * 192 + ((((col >> 3) ^ (row & 7))) << 3) + (col & 7)] = f2bu(o4[j]);
          }
        }
      }
    }
    {
      f32x4 accO[12];
#pragma unroll
      for (int t = 0; t < 12; ++t) accO[t] = (f32x4){0.f, 0.f, 0.f, 0.f};
      lds_gemm(Abuf, wsu, Wbuf, &gph, accO, wr0, wc0, m, gq, wave, lane);
      bias_store_cs(accO, rbo + i * 192, Abuf, wr0, wc0, m, gq);
    }
  }

  // ===== SOFM: argmax_g (f.g - ||g||^2/2) -> histogram =====
  {
    f32x4 accS[8];
#pragma unroll
    for (int t = 0; t < 8; ++t) accS[t] = (f32x4){0.f, 0.f, 0.f, 0.f};
#pragma unroll
    for (int ph = 0; ph < 3; ++ph) {
      phase_begin(wsu, Wbuf, gph, wave, lane);
      const ushort_t* Wc = &Wbuf[gph & 1][0];
      int r0 = wr0 + m, r1 = wr0 + 16 + m;
#pragma unroll
      for (int ks = 0; ks < 2; ++ks) {
        int sl = (ks << 2) + gq;
        short8 a0 = *(const short8*)(Abuf + r0 * 192 + ((ph * 8 + (sl ^ (r0 & 7))) << 3));
        short8 a1 = *(const short8*)(Abuf + r1 * 192 + ((ph * 8 + (sl ^ (r1 & 7))) << 3));
#pragma unroll
        for (int nt = 0; nt < 4; ++nt) {
          int n = nt * 16 + m;
          short8 b = *(const short8*)(Wc + n * 64 + ((sl ^ (n & 7)) << 3));
          accS[nt]     = MFMA16(a0, b, accS[nt]);
          accS[4 + nt] = MFMA16(a1, b, accS[4 + nt]);
        }
      }
      ++gph;
    }
#pragma unroll
    for (int mt = 0; mt < 2; ++mt)
#pragma unroll
      for (int j = 0; j < 4; ++j) {
        float bv = -3.0e38f; int bi = 0;
#pragma unroll
        for (int nt = 0; nt < 4; ++nt) {
          int g = nt * 16 + m;
          float v = accS[mt * 4 + nt][j] - c_l[g];
          bool take = (v > bv);
          bv = take ? v : bv; bi = take ? g : bi;
        }
#pragma unroll
        for (int off = 1; off < 16; off <<= 1) {
          float ov = __shfl_xor(bv, off, 64);
          int oi = __shfl_xor(bi, off, 64);
          bool take = (ov > bv) || (ov == bv && oi < bi);
          bv = take ? ov : bv; bi = take ? oi : bi;
        }
        // both col-half waves compute the same rows' argmax; only colh==0 counts
        if (m == 0 && colh == 0) atomicAdd(&hist[bi], 1u);
      }
  }
  __syncthreads();
  if (tid < 64 && hist[tid]) atomicAdd(&counts[tid], hist[tid]);
}

// ---------------- finisher ----------------
__global__ void arn_finish(const unsigned* __restrict__ counts, const float* __restrict__ gr,
                           const float* __restrict__ ow, const float* __restrict__ ob,
                           float* __restrict__ out) {
  __shared__ float pooled[192];
  __shared__ float cf[64];
  int t = threadIdx.x;
  if (t < 64) cf[t] = (float)counts[t];
  __syncthreads();
  float s = 0.f;
  for (int g = 0; g < 64; ++g) s += cf[g] * gr[g * 192 + t];
  pooled[t] = s * (1.0f / (float)B_TOTAL);
  __syncthreads();
  if (t < 6) {
    float o = ob[t];
    for (int j = 0; j < 192; ++j) o += pooled[j] * ow[j * 6 + t];
    out[t] = (t == 1) ? fmaxf(o, 0.f) : 1.f / (1.f + expf(-o));
  }
}

// ---------------- launch ----------------
extern "C" void kernel_launch(void* const* d_in, const int* in_sizes, int n_in,
                              void* d_out, int out_size, void* d_ws, size_t ws_size,
                              hipStream_t stream) {
  (void)in_sizes; (void)n_in; (void)out_size; (void)ws_size;
  const float* xv   = (const float*)d_in[0];
  const float* xa   = (const float*)d_in[1];
  const float* xt   = (const float*)d_in[2];
  const float* ewv  = (const float*)d_in[3];
  const float* ebv  = (const float*)d_in[4];
  const float* egv  = (const float*)d_in[5];
  const float* ebbv = (const float*)d_in[6];
  const float* ewa  = (const float*)d_in[7];
  const float* eba  = (const float*)d_in[8];
  const float* ega  = (const float*)d_in[9];
  const float* ebba = (const float*)d_in[10];
  const float* ewt  = (const float*)d_in[11];
  const float* ebt  = (const float*)d_in[12];
  const float* egt  = (const float*)d_in[13];
  const float* ebbt = (const float*)d_in[14];
  const float* fw   = (const float*)d_in[15];
  const float* fb   = (const float*)d_in[16];
  const float* fg   = (const float*)d_in[17];
  const float* fbb  = (const float*)d_in[18];
  const float* rwq  = (const float*)d_in[19];
  const float* rwk  = (const float*)d_in[20];
  const float* rwv  = (const float*)d_in[21];
  const float* rwo  = (const float*)d_in[22];
  const float* rbq  = (const float*)d_in[23];
  const float* rbk  = (const float*)d_in[24];
  const float* rbv  = (const float*)d_in[25];
  const float* rbo  = (const float*)d_in[26];
  const float* rmem = (const float*)d_in[27];
  const float* grid = (const float*)d_in[28];
  const float* ow   = (const float*)d_in[29];
  const float* ob   = (const float*)d_in[30];

  ushort_t* wsu = (ushort_t*)d_ws;
  ushort_t* kvf = wsu + OFF_KV;
  float* wsf = (float*)((char*)d_ws + F32_BYTE_OFF);
  float* ggn = wsf;
  unsigned* cnt = (unsigned*)(wsf + 64);

  prep_weights<<<dim3(256), dim3(256), 0, stream>>>(ewv, ewa, ewt, fw, rwq, rwo, grid, wsu);
  prep_kv<<<dim3(120), dim3(256), 0, stream>>>(rwk, rwv, rbk, rbv, rmem, grid, kvf, ggn, cnt);
  arn_main<<<dim3(2048), dim3(256), 0, stream>>>(xv, xa, xt, wsu, kvf, ggn, cnt,
      ebv, egv, ebbv, eba, ega, ebba, ebt, egt, ebbt, fb, fg, fbb, rbq, rbo);
  arn_finish<<<dim3(1), dim3(192), 0, stream>>>(cnt, grid, ow, ob, (float*)d_out);
}

// Round 11
// 316.336 us; speedup vs baseline: 2.0043x; 1.1902x over previous
//
#include <hip/hip_runtime.h>
#include <hip/hip_bf16.h>
#include <math.h>

typedef unsigned short ushort_t;
typedef __attribute__((ext_vector_type(8))) short short8;
typedef __attribute__((ext_vector_type(4))) float f32x4;

#define B_TOTAL 131072

// ws layout (ushort element offsets). W blobs are K64-split chunk-major:
// chunk = [N rows][64 k]; storage (n, s, j) holds logical k = ck*64 + 8*(s ^ (n&7)) + j.
#define OFF_VIB 0        // 1 chunk  [192][64]  = 12288
#define OFF_ACO 12288    // 4 chunks             = 49152
#define OFF_TMP 61440    // 2 chunks             = 24576
#define OFF_FUS 86016    // 9 chunks (3/part)    = 110592
#define OFF_WQ 196608    // 9 chunks (3/layer)
#define OFF_WO 307200    // 9 chunks
#define OFF_GRID 417792  // 3 chunks [64][64]    = 12288
#define OFF_KV 430080    // 3 layers x 10240: Kb[4h][16s][64k] + Vt[4h][48d][32s]
#define F32_BYTE_OFF 921600

// prep kernels: explicit RTNE bit-twiddle (cold code)
__device__ __forceinline__ ushort_t f2bu_prep(float f) {
  union { float f; unsigned u; } c; c.f = f;
  unsigned u = c.u;
  unsigned r = (u + 0x7fffu + ((u >> 16) & 1u)) >> 16;  // RTNE
  return (ushort_t)r;
}
// hot kernel: v_cvt bf16 (RTNE on gfx950); packed-store sites let the
// compiler fuse pairs into v_cvt_pk_bf16_f32.
__device__ __forceinline__ ushort_t f2bu(float f) {
  __hip_bfloat16 h = __float2bfloat16(f);
  return *(ushort_t*)&h;
}
__device__ __forceinline__ float fastrcp(float x) { return __builtin_amdgcn_rcpf(x); }
__device__ __forceinline__ float gelu_fast(float x) {
  float u = 0.7978845608f * x * (1.0f + 0.044715f * x * x);
  float E = exp2f(2.88539008f * u);
  float t = 1.0f - 2.0f * fastrcp(E + 1.0f);
  return 0.5f * x * (1.0f + t);
}
#define MFMA16(a, b, c) __builtin_amdgcn_mfma_f32_16x16x32_bf16(a, b, c, 0, 0, 0)

__device__ __forceinline__ void gload16(const void* g, void* l) {
  __builtin_amdgcn_global_load_lds((const __attribute__((address_space(1))) void*)g,
                                   (__attribute__((address_space(3))) void*)l, 16, 0, 0);
}

// ---------------- prep: weights -> K64-split swizzled chunks ----------------
__global__ void prep_weights(const float* __restrict__ ev, const float* __restrict__ ea,
                             const float* __restrict__ et, const float* __restrict__ fw,
                             const float* __restrict__ rwq, const float* __restrict__ rwo,
                             const float* __restrict__ gr, ushort_t* __restrict__ ws) {
  int tid = blockIdx.x * blockDim.x + threadIdx.x;
  int nth = gridDim.x * blockDim.x;
  for (int i = tid; i < 12288; i += nth) {
    int n = i >> 6, kin = i & 63;
    int k = 8 * ((kin >> 3) ^ (n & 7)) + (kin & 7);
    ws[OFF_VIB + i] = f2bu_prep(ev[k * 192 + n]);
  }
  for (int i = tid; i < 49152; i += nth) {
    int ck = i / 12288, rem = i % 12288, n = rem >> 6, kin = rem & 63;
    int k = ck * 64 + 8 * ((kin >> 3) ^ (n & 7)) + (kin & 7);
    ws[OFF_ACO + i] = f2bu_prep(ea[k * 192 + n]);
  }
  for (int i = tid; i < 24576; i += nth) {
    int ck = i / 12288, rem = i % 12288, n = rem >> 6, kin = rem & 63;
    int k = ck * 64 + 8 * ((kin >> 3) ^ (n & 7)) + (kin & 7);
    ws[OFF_TMP + i] = f2bu_prep(et[k * 192 + n]);
  }
  for (int i = tid; i < 110592; i += nth) {
    int ck = i / 12288, rem = i % 12288, n = rem >> 6, kin = rem & 63;
    int k = ck * 64 + 8 * ((kin >> 3) ^ (n & 7)) + (kin & 7);
    ws[OFF_FUS + i] = f2bu_prep(fw[k * 192 + n]);
  }
  for (int i = tid; i < 110592; i += nth) {
    int ck = i / 12288, rem = i % 12288, n = rem >> 6, kin = rem & 63;
    int l = ck / 3;
    int k = (ck % 3) * 64 + 8 * ((kin >> 3) ^ (n & 7)) + (kin & 7);
    ws[OFF_WQ + i] = f2bu_prep(rwq[l * 36864 + k * 192 + n]);
    ws[OFF_WO + i] = f2bu_prep(rwo[l * 36864 + k * 192 + n]);
  }
  for (int i = tid; i < 12288; i += nth) {
    int ck = i / 4096, rem = i % 4096, n = rem >> 6, kin = rem & 63;
    int k = ck * 64 + 8 * ((kin >> 3) ^ (n & 7)) + (kin & 7);
    ws[OFF_GRID + i] = f2bu_prep(gr[n * 192 + k]);
  }
}

// ------- prep: K/V operand banks (plain layout, read from global) ---------
__global__ void prep_kv(const float* __restrict__ rwk, const float* __restrict__ rwv,
                        const float* __restrict__ rbk, const float* __restrict__ rbv,
                        const float* __restrict__ rmem, const float* __restrict__ gr,
                        ushort_t* __restrict__ kvf, float* __restrict__ ggn,
                        unsigned* __restrict__ cnt) {
  int tid = blockIdx.x * blockDim.x + threadIdx.x;
  int nth = gridDim.x * blockDim.x;
  // Kb[i][h][s(16)][k(64; k>=48 zero)]
  for (int idx = tid; idx < 12288; idx += nth) {
    int i = idx >> 12, r = idx & 4095, h = r >> 10, s = (r >> 6) & 15, k = r & 63;
    float val = 0.f;
    if (k < 48) {
      int d = h * 48 + k;
      const float* w = rwk + i * 36864;
      const float* mm = rmem + i * 3072 + s * 192;
      float acc = rbk[i * 192 + d];
      for (int kk = 0; kk < 192; ++kk) acc += mm[kk] * w[kk * 192 + d];
      val = acc;
    }
    kvf[i * 10240 + h * 1024 + s * 64 + k] = f2bu_prep(val);
  }
  // Vt[i][h][d(48)][s(32; s>=16 zero)]
  for (int idx = tid; idx < 18432; idx += nth) {
    int i = idx / 6144, r = idx % 6144, h = r / 1536, q = r % 1536, d = q >> 5, s = q & 31;
    float val = 0.f;
    if (s < 16) {
      int dd = h * 48 + d;
      const float* w = rwv + i * 36864;
      const float* mm = rmem + i * 3072 + s * 192;
      float acc = rbv[i * 192 + dd];
      for (int kk = 0; kk < 192; ++kk) acc += mm[kk] * w[kk * 192 + dd];
      val = acc;
    }
    kvf[i * 10240 + 4096 + h * 1536 + d * 32 + s] = f2bu_prep(val);
  }
  for (int g = tid; g < 64; g += nth) {
    const float* gp = gr + g * 192;
    float s = 0.f;
    for (int k = 0; k < 192; ++k) s += gp[k] * gp[k];
    ggn[g] = s;
    cnt[g] = 0u;
  }
}

// ---------------- main-kernel helpers (4-wave block, K64 chunks) ----------------
__device__ __forceinline__ void stage_to(ushort_t* dst, const ushort_t* src, int nseg,
                                         int wave, int lane) {
  for (int s = wave; s < nseg; s += 4)
    gload16(src + (s << 9) + lane * 8, dst + (s << 9));
}

// consumption-order phase table (37 phases); nseg in 1KB segments
__device__ __forceinline__ const ushort_t* chunk_ptr(const ushort_t* wsu, int g, int* nseg) {
  *nseg = 24;
  if (g < 1)            return wsu + OFF_VIB;
  g -= 1;  if (g < 3)   return wsu + OFF_FUS + g * 12288;
  g -= 3;  if (g < 4)   return wsu + OFF_ACO + g * 12288;
  g -= 4;  if (g < 3)   return wsu + OFF_FUS + 36864 + g * 12288;
  g -= 3;  if (g < 2)   return wsu + OFF_TMP + g * 12288;
  g -= 2;  if (g < 3)   return wsu + OFF_FUS + 73728 + g * 12288;
  g -= 3;  if (g < 18)  { int l = g / 6, r2 = g - l * 6;
    return (r2 < 3) ? (wsu + OFF_WQ + l * 36864 + r2 * 12288)
                    : (wsu + OFF_WO + l * 36864 + (r2 - 3) * 12288); }
  g -= 18; if (g < 3)   { *nseg = 8; return wsu + OFF_GRID + g * 4096; }
  *nseg = 0; return wsu;
}

__device__ __forceinline__ void phase_begin(const ushort_t* wsu, ushort_t (*Wb)[12288],
                                            int gph, int wave, int lane) {
  __syncthreads();
  int nseg; const ushort_t* ns = chunk_ptr(wsu, gph + 1, &nseg);
  if (nseg) stage_to(&Wb[(gph + 1) & 1][0], ns, nseg, wave, lane);
}

__device__ __forceinline__ short8 cvt8(float4 a, float4 b) {
  short8 v;
  v[0] = (short)f2bu(a.x); v[1] = (short)f2bu(a.y); v[2] = (short)f2bu(a.z); v[3] = (short)f2bu(a.w);
  v[4] = (short)f2bu(b.x); v[5] = (short)f2bu(b.y); v[6] = (short)f2bu(b.z); v[7] = (short)f2bu(b.w);
  return v;
}

// encoder GEMM (swapped operands: weight=A, activation=B).
// acc[t][j] = out[actrow wr0+m][col wc0+t*16+gq*4+j]; acc[6+t]: row +16.
template<int NPH>
__device__ __forceinline__ void enc_gemm(const float* __restrict__ x, int row0, int row1,
    const ushort_t* wsu, ushort_t (*Wb)[12288], int* gph, f32x4* accE,
    int wc0, int m, int gq, int wave, int lane) {
  const int KF = NPH * 64;
  const float* p0 = x + (size_t)row0 * KF + gq * 8;
  const float* p1 = x + (size_t)row1 * KF + gq * 8;
  float4 ca0 = *(const float4*)(p0);
  float4 ca1 = *(const float4*)(p0 + 4);
  float4 cb0 = *(const float4*)(p1);
  float4 cb1 = *(const float4*)(p1 + 4);
#pragma unroll
  for (int ph = 0; ph < NPH; ++ph) {
    phase_begin(wsu, Wb, *gph, wave, lane);
    const ushort_t* Wc = &Wb[*gph & 1][0];
#pragma unroll
    for (int ks = 0; ks < 2; ++ks) {
      short8 a0 = cvt8(ca0, ca1);
      short8 a1 = cvt8(cb0, cb1);
      int nk = ph * 64 + ks * 32 + 32;
      if (nk < KF) {
        ca0 = *(const float4*)(p0 + nk);
        ca1 = *(const float4*)(p0 + nk + 4);
        cb0 = *(const float4*)(p1 + nk);
        cb1 = *(const float4*)(p1 + nk + 4);
      }
#pragma unroll
      for (int t = 0; t < 6; ++t) {
        int n = wc0 + t * 16 + m;
        short8 b = *(const short8*)(Wc + n * 64 + ((((ks << 2) + gq) ^ (n & 7)) << 3));
        accE[t]     = MFMA16(b, a0, accE[t]);
        accE[6 + t] = MFMA16(b, a1, accE[6 + t]);
      }
    }
    ++*gph;
  }
}

// GEMM with A-activation from swizzled panel (3 phases, K=192), swapped operands
__device__ __forceinline__ void lds_gemm(const ushort_t* Ab, const ushort_t* wsu,
    ushort_t (*Wb)[12288], int* gph, f32x4* acc, int wr0, int wc0, int m, int gq,
    int wave, int lane) {
#pragma unroll
  for (int ph = 0; ph < 3; ++ph) {
    phase_begin(wsu, Wb, *gph, wave, lane);
    const ushort_t* Wc = &Wb[*gph & 1][0];
    int r0 = wr0 + m, r1 = wr0 + 16 + m;
#pragma unroll
    for (int ks = 0; ks < 2; ++ks) {
      int sl = (ks << 2) + gq;
      short8 a0 = *(const short8*)(Ab + r0 * 192 + ((ph * 8 + (sl ^ (r0 & 7))) << 3));
      short8 a1 = *(const short8*)(Ab + r1 * 192 + ((ph * 8 + (sl ^ (r1 & 7))) << 3));
#pragma unroll
      for (int t = 0; t < 6; ++t) {
        int n = wc0 + t * 16 + m;
        short8 b = *(const short8*)(Wc + n * 64 + ((sl ^ (n & 7)) << 3));
        acc[t]     = MFMA16(b, a0, acc[t]);
        acc[6 + t] = MFMA16(b, a1, acc[6 + t]);
      }
    }
    ++*gph;
  }
}

// LN(+GELU) epilogue (swapped layout): lane-local row sums + 2 shuffles;
// packed 8B stores of 4 consecutive cols.
__device__ __forceinline__ void ln_gelu_cs(f32x4* acc, const float* __restrict__ bias,
    const float* __restrict__ gam, const float* __restrict__ bet,
    ushort_t* __restrict__ Ab, float2 (*scr)[2], int wr0, int wc0, int colh,
    int m, int gq) {
#pragma unroll
  for (int t = 0; t < 12; ++t) {
    float4 bv = *(const float4*)(bias + wc0 + (t % 6) * 16 + gq * 4);
#pragma unroll
    for (int j = 0; j < 4; ++j) acc[t][j] += ((const float*)&bv)[j];
  }
#pragma unroll
  for (int mt = 0; mt < 2; ++mt) {
    float s = 0.f, q = 0.f;
#pragma unroll
    for (int t = 0; t < 6; ++t)
#pragma unroll
      for (int j = 0; j < 4; ++j) { float v = acc[mt * 6 + t][j]; s += v; q += v * v; }
    s += __shfl_xor(s, 16, 64); q += __shfl_xor(q, 16, 64);
    s += __shfl_xor(s, 32, 64); q += __shfl_xor(q, 32, 64);
    if (gq == 0) scr[wr0 + mt * 16 + m][colh] = (float2){s, q};
  }
  __syncthreads();
#pragma unroll
  for (int mt = 0; mt < 2; ++mt) {
    int row = wr0 + mt * 16 + m;
    float2 h0 = scr[row][0], h1 = scr[row][1];
    float mean = (h0.x + h1.x) * (1.0f / 192.0f);
    float var = (h0.y + h1.y) * (1.0f / 192.0f) - mean * mean;
    float rstd = rsqrtf(var + 1e-5f);
#pragma unroll
    for (int t = 0; t < 6; ++t) {
      int colb = wc0 + t * 16 + gq * 4;
      float4 ga = *(const float4*)(gam + colb);
      float4 be = *(const float4*)(bet + colb);
      ushort_t o[4];
#pragma unroll
      for (int j = 0; j < 4; ++j) {
        float y = (acc[mt * 6 + t][j] - mean) * rstd * ((const float*)&ga)[j] + ((const float*)&be)[j];
        o[j] = f2bu(gelu_fast(y));
      }
      int off = row * 192 + (((colb >> 3) ^ (row & 7)) << 3) + (colb & 7);
      *(uint2*)(Ab + off) = *(uint2*)o;
    }
  }
}

__device__ __forceinline__ void bias_store_cs(f32x4* acc, const float* __restrict__ bias,
    ushort_t* __restrict__ Ab, int wr0, int wc0, int m, int gq) {
#pragma unroll
  for (int mt = 0; mt < 2; ++mt) {
    int row = wr0 + mt * 16 + m;
#pragma unroll
    for (int t = 0; t < 6; ++t) {
      int colb = wc0 + t * 16 + gq * 4;
      float4 bv = *(const float4*)(bias + colb);
      ushort_t o[4];
#pragma unroll
      for (int j = 0; j < 4; ++j)
        o[j] = f2bu(acc[mt * 6 + t][j] + ((const float*)&bv)[j]);
      int off = row * 192 + (((colb >> 3) ^ (row & 7)) << 3) + (colb & 7);
      *(uint2*)(Ab + off) = *(uint2*)o;
    }
  }
}

// ---------------- main fused kernel ----------------
// R11: operand-swapped MFMA everywhere -> packed 8B epilogue stores (4x fewer
// LDS ops), float4 bias/gamma/beta loads, 2-shuffle LN/softmax/argmax
// reductions. Structure otherwise identical to R10 (37 K64 phases).
__global__ __launch_bounds__(256) __attribute__((amdgpu_waves_per_eu(2))) void arn_main(
    const float* __restrict__ xv, const float* __restrict__ xa, const float* __restrict__ xt,
    const ushort_t* __restrict__ wsu, const ushort_t* __restrict__ kvf,
    const float* __restrict__ ggn, unsigned* __restrict__ counts,
    const float* __restrict__ ebv, const float* __restrict__ egv, const float* __restrict__ ebbv,
    const float* __restrict__ eba, const float* __restrict__ ega, const float* __restrict__ ebba,
    const float* __restrict__ ebt, const float* __restrict__ egt, const float* __restrict__ ebbt,
    const float* __restrict__ fb, const float* __restrict__ fg, const float* __restrict__ fbb,
    const float* __restrict__ rbq, const float* __restrict__ rbo) {
  __shared__ __align__(16) ushort_t Abuf[64 * 192 + 64];  // swizzled activations + zero pad
  __shared__ __align__(16) ushort_t Wbuf[2][12288];       // double-buffered K64 W chunks
  __shared__ float2 lnscr[64][2];
  __shared__ __align__(16) float c_l[64];
  __shared__ unsigned hist[64];

  const int tid = threadIdx.x, lane = tid & 63, wave = tid >> 6;
  const int m = lane & 15, gq = lane >> 4;
  const int wr0 = (wave & 1) * 32;       // GEMM row half
  const int wc0 = (wave >> 1) * 96;      // GEMM col half
  const int colh = wave >> 1;
  const int aw0 = wave * 16;             // attention row base
  const int growbase = blockIdx.x * 64;

  if (tid < 64) { hist[tid] = 0u; c_l[tid] = 0.5f * ggn[tid]; Abuf[12288 + tid] = 0; }

  int gph = 0;
  { int nseg; const ushort_t* s0 = chunk_ptr(wsu, 0, &nseg); stage_to(&Wbuf[0][0], s0, nseg, wave, lane); }

  const int row0 = growbase + wr0 + m, row1 = row0 + 16;
  f32x4 accF[12];
#pragma unroll
  for (int t = 0; t < 12; ++t) accF[t] = (f32x4){0.f, 0.f, 0.f, 0.f};

  // ===== vib encoder + fus part 0 =====
  {
    f32x4 accE[12];
#pragma unroll
    for (int t = 0; t < 12; ++t) accE[t] = (f32x4){0.f, 0.f, 0.f, 0.f};
    enc_gemm<1>(xv, row0, row1, wsu, Wbuf, &gph, accE, wc0, m, gq, wave, lane);
    ln_gelu_cs(accE, ebv, egv, ebbv, Abuf, lnscr, wr0, wc0, colh, m, gq);
  }
  lds_gemm(Abuf, wsu, Wbuf, &gph, accF, wr0, wc0, m, gq, wave, lane);

  // ===== aco encoder + fus part 1 =====
  {
    f32x4 accE[12];
#pragma unroll
    for (int t = 0; t < 12; ++t) accE[t] = (f32x4){0.f, 0.f, 0.f, 0.f};
    enc_gemm<4>(xa, row0, row1, wsu, Wbuf, &gph, accE, wc0, m, gq, wave, lane);
    ln_gelu_cs(accE, eba, ega, ebba, Abuf, lnscr, wr0, wc0, colh, m, gq);
  }
  lds_gemm(Abuf, wsu, Wbuf, &gph, accF, wr0, wc0, m, gq, wave, lane);

  // ===== tmp encoder + fus part 2 + fusion LN =====
  {
    f32x4 accE[12];
#pragma unroll
    for (int t = 0; t < 12; ++t) accE[t] = (f32x4){0.f, 0.f, 0.f, 0.f};
    enc_gemm<2>(xt, row0, row1, wsu, Wbuf, &gph, accE, wc0, m, gq, wave, lane);
    ln_gelu_cs(accE, ebt, egt, ebbt, Abuf, lnscr, wr0, wc0, colh, m, gq);
  }
  lds_gemm(Abuf, wsu, Wbuf, &gph, accF, wr0, wc0, m, gq, wave, lane);
  ln_gelu_cs(accF, fb, fg, fbb, Abuf, lnscr, wr0, wc0, colh, m, gq);

  // ===== 3 resonance layers =====
  for (int i = 0; i < 3; ++i) {
    {
      f32x4 accQ[12];
#pragma unroll
      for (int t = 0; t < 12; ++t) accQ[t] = (f32x4){0.f, 0.f, 0.f, 0.f};
      lds_gemm(Abuf, wsu, Wbuf, &gph, accQ, wr0, wc0, m, gq, wave, lane);
      bias_store_cs(accQ, rbq + i * 192, Abuf, wr0, wc0, m, gq);
    }
    __syncthreads();  // Q visible to all waves
    {
      // P scratch in Wbuf[0] (last wq phase is even; in-flight prefetch -> Wbuf[1])
      const ushort_t* kvl = kvf + i * 10240;
      ushort_t* Pw = &Wbuf[0][0] + wave * 512;  // [16 rows][32 slots]
      *(uint2*)(Pw + (lane >> 2) * 32 + 16 + (lane & 3) * 4) = (uint2){0u, 0u};
      const float scale = 0.144337567297406441f;  // 1/sqrt(48)
#pragma unroll
      for (int h = 0; h < 4; ++h) {
        f32x4 s4 = (f32x4){0.f, 0.f, 0.f, 0.f};
#pragma unroll
        for (int ks = 0; ks < 2; ++ks) {
          int kg = h * 6 + ks * 4 + gq;
          int r = aw0 + m;
          short8 a = *(const short8*)(Abuf + r * 192 + ((kg ^ (r & 7)) << 3));
          short8 b = *(const short8*)(kvl + h * 1024 + m * 64 + ks * 32 + gq * 8);
          s4 = MFMA16(b, a, s4);   // swapped: s4[j] = score[slot gq*4+j][qrow aw0+m]
        }
        float e[4];
        float mx = -3.0e38f;
#pragma unroll
        for (int j = 0; j < 4; ++j) { e[j] = s4[j] * scale; mx = fmaxf(mx, e[j]); }
        mx = fmaxf(mx, __shfl_xor(mx, 16, 64));
        mx = fmaxf(mx, __shfl_xor(mx, 32, 64));
        float sm = 0.f;
#pragma unroll
        for (int j = 0; j < 4; ++j) { e[j] = exp2f((e[j] - mx) * 1.44269504f); sm += e[j]; }
        sm += __shfl_xor(sm, 16, 64);
        sm += __shfl_xor(sm, 32, 64);
        float inv = fastrcp(sm);
        ushort_t p4[4];
#pragma unroll
        for (int j = 0; j < 4; ++j) p4[j] = f2bu(e[j] * inv);
        *(uint2*)(Pw + m * 32 + gq * 4) = *(uint2*)p4;
        short8 pa = *(const short8*)(Pw + m * 32 + gq * 8);
#pragma unroll
        for (int t = 0; t < 3; ++t) {
          short8 vb = *(const short8*)(kvl + 4096 + h * 1536 + (t * 16 + m) * 32 + gq * 8);
          f32x4 o4 = MFMA16(vb, pa, ((f32x4){0.f, 0.f, 0.f, 0.f}));  // swapped
          int row = aw0 + m;
          int colb = h * 48 + t * 16 + gq * 4;
          ushort_t o[4];
#pragma unroll
          for (int j = 0; j < 4; ++j) o[j] = f2bu(o4[j]);
          int off = row * 192 + (((colb >> 3) ^ (row & 7)) << 3) + (colb & 7);
          *(uint2*)(Abuf + off) = *(uint2*)o;
        }
      }
    }
    {
      f32x4 accO[12];
#pragma unroll
      for (int t = 0; t < 12; ++t) accO[t] = (f32x4){0.f, 0.f, 0.f, 0.f};
      lds_gemm(Abuf, wsu, Wbuf, &gph, accO, wr0, wc0, m, gq, wave, lane);
      bias_store_cs(accO, rbo + i * 192, Abuf, wr0, wc0, m, gq);
    }
  }

  // ===== SOFM: argmax_g (f.g - ||g||^2/2) -> histogram =====
  {
    f32x4 accS[8];
#pragma unroll
    for (int t = 0; t < 8; ++t) accS[t] = (f32x4){0.f, 0.f, 0.f, 0.f};
#pragma unroll
    for (int ph = 0; ph < 3; ++ph) {
      phase_begin(wsu, Wbuf, gph, wave, lane);
      const ushort_t* Wc = &Wbuf[gph & 1][0];
      int r0 = wr0 + m, r1 = wr0 + 16 + m;
#pragma unroll
      for (int ks = 0; ks < 2; ++ks) {
        int sl = (ks << 2) + gq;
        short8 a0 = *(const short8*)(Abuf + r0 * 192 + ((ph * 8 + (sl ^ (r0 & 7))) << 3));
        short8 a1 = *(const short8*)(Abuf + r1 * 192 + ((ph * 8 + (sl ^ (r1 & 7))) << 3));
#pragma unroll
        for (int nt = 0; nt < 4; ++nt) {
          int n = nt * 16 + m;
          short8 b = *(const short8*)(Wc + n * 64 + ((sl ^ (n & 7)) << 3));
          accS[nt]     = MFMA16(b, a0, accS[nt]);  // swapped
          accS[4 + nt] = MFMA16(b, a1, accS[4 + nt]);
        }
      }
      ++gph;
    }
    // accS[mt*4+nt][j] = score[row wr0+mt*16+m][g = nt*16+gq*4+j]
#pragma unroll
    for (int mt = 0; mt < 2; ++mt) {
      float bv = -3.0e38f; int bi = 64;
#pragma unroll
      for (int nt = 0; nt < 4; ++nt) {
        int gb = nt * 16 + gq * 4;
        float4 cl = *(const float4*)(c_l + gb);
#pragma unroll
        for (int j = 0; j < 4; ++j) {
          float v = accS[mt * 4 + nt][j] - ((const float*)&cl)[j];
          int g = gb + j;
          bool take = (v > bv);            // ascending g within lane: strict > keeps lowest
          bv = take ? v : bv; bi = take ? g : bi;
        }
      }
#pragma unroll
      for (int off = 16; off < 64; off <<= 1) {
        float ov = __shfl_xor(bv, off, 64);
        int oi = __shfl_xor(bi, off, 64);
        bool take = (ov > bv) || (ov == bv && oi < bi);
        bv = take ? ov : bv; bi = take ? oi : bi;
      }
      // each m-lane holds argmax of row wr0+mt*16+m; count once (colh 0, gq 0)
      if (gq == 0 && colh == 0) atomicAdd(&hist[bi], 1u);
    }
  }
  __syncthreads();
  if (tid < 64 && hist[tid]) atomicAdd(&counts[tid], hist[tid]);
}

// ---------------- finisher ----------------
__global__ void arn_finish(const unsigned* __restrict__ counts, const float* __restrict__ gr,
                           const float* __restrict__ ow, const float* __restrict__ ob,
                           float* __restrict__ out) {
  __shared__ float pooled[192];
  __shared__ float cf[64];
  int t = threadIdx.x;
  if (t < 64) cf[t] = (float)counts[t];
  __syncthreads();
  float s = 0.f;
  for (int g = 0; g < 64; ++g) s += cf[g] * gr[g * 192 + t];
  pooled[t] = s * (1.0f / (float)B_TOTAL);
  __syncthreads();
  if (t < 6) {
    float o = ob[t];
    for (int j = 0; j < 192; ++j) o += pooled[j] * ow[j * 6 + t];
    out[t] = (t == 1) ? fmaxf(o, 0.f) : 1.f / (1.f + expf(-o));
  }
}

// ---------------- launch ----------------
extern "C" void kernel_launch(void* const* d_in, const int* in_sizes, int n_in,
                              void* d_out, int out_size, void* d_ws, size_t ws_size,
                              hipStream_t stream) {
  (void)in_sizes; (void)n_in; (void)out_size; (void)ws_size;
  const float* xv   = (const float*)d_in[0];
  const float* xa   = (const float*)d_in[1];
  const float* xt   = (const float*)d_in[2];
  const float* ewv  = (const float*)d_in[3];
  const float* ebv  = (const float*)d_in[4];
  const float* egv  = (const float*)d_in[5];
  const float* ebbv = (const float*)d_in[6];
  const float* ewa  = (const float*)d_in[7];
  const float* eba  = (const float*)d_in[8];
  const float* ega  = (const float*)d_in[9];
  const float* ebba = (const float*)d_in[10];
  const float* ewt  = (const float*)d_in[11];
  const float* ebt  = (const float*)d_in[12];
  const float* egt  = (const float*)d_in[13];
  const float* ebbt = (const float*)d_in[14];
  const float* fw   = (const float*)d_in[15];
  const float* fb   = (const float*)d_in[16];
  const float* fg   = (const float*)d_in[17];
  const float* fbb  = (const float*)d_in[18];
  const float* rwq  = (const float*)d_in[19];
  const float* rwk  = (const float*)d_in[20];
  const float* rwv  = (const float*)d_in[21];
  const float* rwo  = (const float*)d_in[22];
  const float* rbq  = (const float*)d_in[23];
  const float* rbk  = (const float*)d_in[24];
  const float* rbv  = (const float*)d_in[25];
  const float* rbo  = (const float*)d_in[26];
  const float* rmem = (const float*)d_in[27];
  const float* grid = (const float*)d_in[28];
  const float* ow   = (const float*)d_in[29];
  const float* ob   = (const float*)d_in[30];

  ushort_t* wsu = (ushort_t*)d_ws;
  ushort_t* kvf = wsu + OFF_KV;
  float* wsf = (float*)((char*)d_ws + F32_BYTE_OFF);
  float* ggn = wsf;
  unsigned* cnt = (unsigned*)(wsf + 64);

  prep_weights<<<dim3(256), dim3(256), 0, stream>>>(ewv, ewa, ewt, fw, rwq, rwo, grid, wsu);
  prep_kv<<<dim3(120), dim3(256), 0, stream>>>(rwk, rwv, rbk, rbv, rmem, grid, kvf, ggn, cnt);
  arn_main<<<dim3(2048), dim3(256), 0, stream>>>(xv, xa, xt, wsu, kvf, ggn, cnt,
      ebv, egv, ebbv, eba, ega, ebba, ebt, egt, ebbt, fb, fg, fbb, rbq, rbo);
  arn_finish<<<dim3(1), dim3(192), 0, stream>>>(cnt, grid, ow, ob, (float*)d_out);
}

// Round 12
// 288.685 us; speedup vs baseline: 2.1963x; 1.0958x over previous
//
#include <hip/hip_runtime.h>
#include <hip/hip_bf16.h>
#include <math.h>

typedef unsigned short ushort_t;
typedef __attribute__((ext_vector_type(8))) short short8;
typedef __attribute__((ext_vector_type(4))) float f32x4;

#define B_TOTAL 131072

// ws layout (ushort element offsets). W blobs are K64-split chunk-major:
// chunk = [N rows][64 k]; storage (n, s, j) holds logical k = ck*64 + 8*(s ^ (n&7)) + j.
#define OFF_VIB 0        // 1 chunk  [192][64]  = 12288
#define OFF_ACO 12288    // 4 chunks             = 49152
#define OFF_TMP 61440    // 2 chunks             = 24576
#define OFF_FUS 86016    // 9 chunks (3/part)    = 110592
#define OFF_WQ 196608    // 9 chunks (3/layer)
#define OFF_WO 307200    // 9 chunks
#define OFF_GRID 417792  // 3 chunks [64][64]    = 12288
#define OFF_KV 430080    // 3 layers x 10240: Kb[4h][16s][64k] + Vt[4h][48d][32s]
#define F32_BYTE_OFF 921600

// prep kernels: explicit RTNE bit-twiddle (cold code)
__device__ __forceinline__ ushort_t f2bu_prep(float f) {
  union { float f; unsigned u; } c; c.f = f;
  unsigned u = c.u;
  unsigned r = (u + 0x7fffu + ((u >> 16) & 1u)) >> 16;  // RTNE
  return (ushort_t)r;
}
// hot kernel: v_cvt bf16 (RTNE on gfx950)
__device__ __forceinline__ ushort_t f2bu(float f) {
  __hip_bfloat16 h = __float2bfloat16(f);
  return *(ushort_t*)&h;
}
__device__ __forceinline__ float fastrcp(float x) { return __builtin_amdgcn_rcpf(x); }
__device__ __forceinline__ float gelu_fast(float x) {
  float u = 0.7978845608f * x * (1.0f + 0.044715f * x * x);
  float E = exp2f(2.88539008f * u);
  float t = 1.0f - 2.0f * fastrcp(E + 1.0f);
  return 0.5f * x * (1.0f + t);
}
#define MFMA16(a, b, c) __builtin_amdgcn_mfma_f32_16x16x32_bf16(a, b, c, 0, 0, 0)

__device__ __forceinline__ void gload16(const void* g, void* l) {
  __builtin_amdgcn_global_load_lds((const __attribute__((address_space(1))) void*)g,
                                   (__attribute__((address_space(3))) void*)l, 16, 0, 0);
}

// ---------------- prep: weights -> K64-split swizzled chunks ----------------
__global__ void prep_weights(const float* __restrict__ ev, const float* __restrict__ ea,
                             const float* __restrict__ et, const float* __restrict__ fw,
                             const float* __restrict__ rwq, const float* __restrict__ rwo,
                             const float* __restrict__ gr, ushort_t* __restrict__ ws) {
  int tid = blockIdx.x * blockDim.x + threadIdx.x;
  int nth = gridDim.x * blockDim.x;
  for (int i = tid; i < 12288; i += nth) {
    int n = i >> 6, kin = i & 63;
    int k = 8 * ((kin >> 3) ^ (n & 7)) + (kin & 7);
    ws[OFF_VIB + i] = f2bu_prep(ev[k * 192 + n]);
  }
  for (int i = tid; i < 49152; i += nth) {
    int ck = i / 12288, rem = i % 12288, n = rem >> 6, kin = rem & 63;
    int k = ck * 64 + 8 * ((kin >> 3) ^ (n & 7)) + (kin & 7);
    ws[OFF_ACO + i] = f2bu_prep(ea[k * 192 + n]);
  }
  for (int i = tid; i < 24576; i += nth) {
    int ck = i / 12288, rem = i % 12288, n = rem >> 6, kin = rem & 63;
    int k = ck * 64 + 8 * ((kin >> 3) ^ (n & 7)) + (kin & 7);
    ws[OFF_TMP + i] = f2bu_prep(et[k * 192 + n]);
  }
  for (int i = tid; i < 110592; i += nth) {
    int ck = i / 12288, rem = i % 12288, n = rem >> 6, kin = rem & 63;
    int k = ck * 64 + 8 * ((kin >> 3) ^ (n & 7)) + (kin & 7);
    ws[OFF_FUS + i] = f2bu_prep(fw[k * 192 + n]);
  }
  for (int i = tid; i < 110592; i += nth) {
    int ck = i / 12288, rem = i % 12288, n = rem >> 6, kin = rem & 63;
    int l = ck / 3;
    int k = (ck % 3) * 64 + 8 * ((kin >> 3) ^ (n & 7)) + (kin & 7);
    ws[OFF_WQ + i] = f2bu_prep(rwq[l * 36864 + k * 192 + n]);
    ws[OFF_WO + i] = f2bu_prep(rwo[l * 36864 + k * 192 + n]);
  }
  for (int i = tid; i < 12288; i += nth) {
    int ck = i / 4096, rem = i % 4096, n = rem >> 6, kin = rem & 63;
    int k = ck * 64 + 8 * ((kin >> 3) ^ (n & 7)) + (kin & 7);
    ws[OFF_GRID + i] = f2bu_prep(gr[n * 192 + k]);
  }
}

// ------- prep: K/V operand banks (plain layout, read from global) ---------
__global__ void prep_kv(const float* __restrict__ rwk, const float* __restrict__ rwv,
                        const float* __restrict__ rbk, const float* __restrict__ rbv,
                        const float* __restrict__ rmem, const float* __restrict__ gr,
                        ushort_t* __restrict__ kvf, float* __restrict__ ggn,
                        unsigned* __restrict__ cnt) {
  int tid = blockIdx.x * blockDim.x + threadIdx.x;
  int nth = gridDim.x * blockDim.x;
  // Kb[i][h][s(16)][k(64; k>=48 zero)]
  for (int idx = tid; idx < 12288; idx += nth) {
    int i = idx >> 12, r = idx & 4095, h = r >> 10, s = (r >> 6) & 15, k = r & 63;
    float val = 0.f;
    if (k < 48) {
      int d = h * 48 + k;
      const float* w = rwk + i * 36864;
      const float* mm = rmem + i * 3072 + s * 192;
      float acc = rbk[i * 192 + d];
      for (int kk = 0; kk < 192; ++kk) acc += mm[kk] * w[kk * 192 + d];
      val = acc;
    }
    kvf[i * 10240 + h * 1024 + s * 64 + k] = f2bu_prep(val);
  }
  // Vt[i][h][d(48)][s(32; s>=16 zero)]
  for (int idx = tid; idx < 18432; idx += nth) {
    int i = idx / 6144, r = idx % 6144, h = r / 1536, q = r % 1536, d = q >> 5, s = q & 31;
    float val = 0.f;
    if (s < 16) {
      int dd = h * 48 + d;
      const float* w = rwv + i * 36864;
      const float* mm = rmem + i * 3072 + s * 192;
      float acc = rbv[i * 192 + dd];
      for (int kk = 0; kk < 192; ++kk) acc += mm[kk] * w[kk * 192 + dd];
      val = acc;
    }
    kvf[i * 10240 + 4096 + h * 1536 + d * 32 + s] = f2bu_prep(val);
  }
  for (int g = tid; g < 64; g += nth) {
    const float* gp = gr + g * 192;
    float s = 0.f;
    for (int k = 0; k < 192; ++k) s += gp[k] * gp[k];
    ggn[g] = s;
    cnt[g] = 0u;
  }
}

// ---------------- main-kernel helpers (4-wave block, K64 chunks) ----------------
__device__ __forceinline__ void stage_to(ushort_t* dst, const ushort_t* src, int nseg,
                                         int wave, int lane) {
  for (int s = wave; s < nseg; s += 4)
    gload16(src + (s << 9) + lane * 8, dst + (s << 9));
}

// consumption-order phase table (37 phases); nseg in 1KB segments
__device__ __forceinline__ const ushort_t* chunk_ptr(const ushort_t* wsu, int g, int* nseg) {
  *nseg = 24;
  if (g < 1)            return wsu + OFF_VIB;
  g -= 1;  if (g < 3)   return wsu + OFF_FUS + g * 12288;
  g -= 3;  if (g < 4)   return wsu + OFF_ACO + g * 12288;
  g -= 4;  if (g < 3)   return wsu + OFF_FUS + 36864 + g * 12288;
  g -= 3;  if (g < 2)   return wsu + OFF_TMP + g * 12288;
  g -= 2;  if (g < 3)   return wsu + OFF_FUS + 73728 + g * 12288;
  g -= 3;  if (g < 18)  { int l = g / 6, r2 = g - l * 6;
    return (r2 < 3) ? (wsu + OFF_WQ + l * 36864 + r2 * 12288)
                    : (wsu + OFF_WO + l * 36864 + (r2 - 3) * 12288); }
  g -= 18; if (g < 3)   { *nseg = 8; return wsu + OFF_GRID + g * 4096; }
  *nseg = 0; return wsu;
}

__device__ __forceinline__ void phase_begin(const ushort_t* wsu, ushort_t (*Wb)[12288],
                                            int gph, int wave, int lane) {
  __syncthreads();
  int nseg; const ushort_t* ns = chunk_ptr(wsu, gph + 1, &nseg);
  if (nseg) stage_to(&Wb[(gph + 1) & 1][0], ns, nseg, wave, lane);
}

__device__ __forceinline__ short8 cvt8(float4 a, float4 b) {
  short8 v;
  v[0] = (short)f2bu(a.x); v[1] = (short)f2bu(a.y); v[2] = (short)f2bu(a.z); v[3] = (short)f2bu(a.w);
  v[4] = (short)f2bu(b.x); v[5] = (short)f2bu(b.y); v[6] = (short)f2bu(b.z); v[7] = (short)f2bu(b.w);
  return v;
}

// encoder GEMM, ROW-SPLIT: wave owns 16 rows x all 192 out-cols.
// acc[t][j] = out[row0][t*16 + gq*4 + j]; A (activation) streamed from global.
template<int NPH>
__device__ __forceinline__ void enc_gemm(const float* __restrict__ x, int row0,
    const ushort_t* wsu, ushort_t (*Wb)[12288], int* gph, f32x4* accE,
    int m, int gq, int wave, int lane) {
  const int KF = NPH * 64;
  const float* p0 = x + (size_t)row0 * KF + gq * 8;
  float4 ca0 = *(const float4*)(p0);
  float4 ca1 = *(const float4*)(p0 + 4);
#pragma unroll
  for (int ph = 0; ph < NPH; ++ph) {
    phase_begin(wsu, Wb, *gph, wave, lane);
    const ushort_t* Wc = &Wb[*gph & 1][0];
#pragma unroll
    for (int ks = 0; ks < 2; ++ks) {
      int sl = ks * 4 + gq;
      short8 a = cvt8(ca0, ca1);
      int nk = ph * 64 + ks * 32 + 32;
      if (nk < KF) {
        ca0 = *(const float4*)(p0 + nk);
        ca1 = *(const float4*)(p0 + nk + 4);
      }
#pragma unroll
      for (int t = 0; t < 12; ++t) {
        int n = t * 16 + m;
        short8 b = *(const short8*)(Wc + n * 64 + ((sl ^ (n & 7)) << 3));
        accE[t] = MFMA16(b, a, accE[t]);
      }
    }
    ++*gph;
  }
}

// GEMM from activation panel, COL-SPLIT: wave owns all 64 rows x 48 cols.
// acc[mt*3+t][j] = out[mt*16+m][wc0 + t*16 + gq*4 + j]
__device__ __forceinline__ void lds_gemm(const ushort_t* Ab, const ushort_t* wsu,
    ushort_t (*Wb)[12288], int* gph, f32x4* acc, int wc0, int m, int gq,
    int wave, int lane) {
#pragma unroll
  for (int ph = 0; ph < 3; ++ph) {
    phase_begin(wsu, Wb, *gph, wave, lane);
    const ushort_t* Wc = &Wb[*gph & 1][0];
#pragma unroll
    for (int ks = 0; ks < 2; ++ks) {
      int sl = ks * 4 + gq;
      short8 b0, b1, b2;
      {
        int n0 = wc0 + m, n1 = wc0 + 16 + m, n2 = wc0 + 32 + m;
        b0 = *(const short8*)(Wc + n0 * 64 + ((sl ^ (n0 & 7)) << 3));
        b1 = *(const short8*)(Wc + n1 * 64 + ((sl ^ (n1 & 7)) << 3));
        b2 = *(const short8*)(Wc + n2 * 64 + ((sl ^ (n2 & 7)) << 3));
      }
#pragma unroll
      for (int mt = 0; mt < 4; ++mt) {
        int r = mt * 16 + m;
        short8 a = *(const short8*)(Ab + r * 192 + ((ph * 8 + (sl ^ (r & 7))) << 3));
        acc[mt * 3 + 0] = MFMA16(b0, a, acc[mt * 3 + 0]);
        acc[mt * 3 + 1] = MFMA16(b1, a, acc[mt * 3 + 1]);
        acc[mt * 3 + 2] = MFMA16(b2, a, acc[mt * 3 + 2]);
      }
    }
    ++*gph;
  }
}

// encoder LN+GELU: fully wave-local (row-split). rloc = wave*16 + m.
__device__ __forceinline__ void ln_gelu_enc(f32x4* acc, const float* __restrict__ bias,
    const float* __restrict__ gam, const float* __restrict__ bet,
    ushort_t* __restrict__ Ab, int rloc, int gq) {
  float s = 0.f, q = 0.f;
#pragma unroll
  for (int t = 0; t < 12; ++t) {
    float4 bv = *(const float4*)(bias + t * 16 + gq * 4);
#pragma unroll
    for (int j = 0; j < 4; ++j) {
      float v = acc[t][j] + ((const float*)&bv)[j];
      acc[t][j] = v; s += v; q += v * v;
    }
  }
  s += __shfl_xor(s, 16, 64); q += __shfl_xor(q, 16, 64);
  s += __shfl_xor(s, 32, 64); q += __shfl_xor(q, 32, 64);
  float mean = s * (1.0f / 192.0f);
  float var = q * (1.0f / 192.0f) - mean * mean;
  float rstd = rsqrtf(var + 1e-5f);
#pragma unroll
  for (int t = 0; t < 12; ++t) {
    int colb = t * 16 + gq * 4;
    float4 ga = *(const float4*)(gam + colb);
    float4 be = *(const float4*)(bet + colb);
    ushort_t o[4];
#pragma unroll
    for (int j = 0; j < 4; ++j) {
      float y = (acc[t][j] - mean) * rstd * ((const float*)&ga)[j] + ((const float*)&be)[j];
      o[j] = f2bu(gelu_fast(y));
    }
    int off = rloc * 192 + (((colb >> 3) ^ (rloc & 7)) << 3) + (colb & 7);
    *(uint2*)(Ab + off) = *(uint2*)o;
  }
}

// fusion LN+GELU: col-split (4-way) with cross-wave stats scratch
__device__ __forceinline__ void ln_gelu_fus(f32x4* acc, const float* __restrict__ bias,
    const float* __restrict__ gam, const float* __restrict__ bet,
    ushort_t* __restrict__ Ab, float2 (*scr)[4], int wave, int wc0, int m, int gq) {
  float4 bv[3];
#pragma unroll
  for (int t = 0; t < 3; ++t) bv[t] = *(const float4*)(bias + wc0 + t * 16 + gq * 4);
#pragma unroll
  for (int mt = 0; mt < 4; ++mt) {
    float s = 0.f, q = 0.f;
#pragma unroll
    for (int t = 0; t < 3; ++t)
#pragma unroll
      for (int j = 0; j < 4; ++j) {
        float v = acc[mt * 3 + t][j] + ((const float*)&bv[t])[j];
        acc[mt * 3 + t][j] = v; s += v; q += v * v;
      }
    s += __shfl_xor(s, 16, 64); q += __shfl_xor(q, 16, 64);
    s += __shfl_xor(s, 32, 64); q += __shfl_xor(q, 32, 64);
    if (gq == 0) scr[mt * 16 + m][wave] = (float2){s, q};
  }
  __syncthreads();
#pragma unroll
  for (int mt = 0; mt < 4; ++mt) {
    int row = mt * 16 + m;
    float s = 0.f, q = 0.f;
#pragma unroll
    for (int w = 0; w < 4; ++w) { float2 p = scr[row][w]; s += p.x; q += p.y; }
    float mean = s * (1.0f / 192.0f);
    float var = q * (1.0f / 192.0f) - mean * mean;
    float rstd = rsqrtf(var + 1e-5f);
#pragma unroll
    for (int t = 0; t < 3; ++t) {
      int colb = wc0 + t * 16 + gq * 4;
      float4 ga = *(const float4*)(gam + colb);
      float4 be = *(const float4*)(bet + colb);
      ushort_t o[4];
#pragma unroll
      for (int j = 0; j < 4; ++j) {
        float y = (acc[mt * 3 + t][j] - mean) * rstd * ((const float*)&ga)[j] + ((const float*)&be)[j];
        o[j] = f2bu(gelu_fast(y));
      }
      int off = row * 192 + (((colb >> 3) ^ (row & 7)) << 3) + (colb & 7);
      *(uint2*)(Ab + off) = *(uint2*)o;
    }
  }
}

__device__ __forceinline__ void bias_store_cs(f32x4* acc, const float* __restrict__ bias,
    ushort_t* __restrict__ Ab, int wc0, int m, int gq) {
  float4 bv[3];
#pragma unroll
  for (int t = 0; t < 3; ++t) bv[t] = *(const float4*)(bias + wc0 + t * 16 + gq * 4);
#pragma unroll
  for (int mt = 0; mt < 4; ++mt) {
    int row = mt * 16 + m;
#pragma unroll
    for (int t = 0; t < 3; ++t) {
      int colb = wc0 + t * 16 + gq * 4;
      ushort_t o[4];
#pragma unroll
      for (int j = 0; j < 4; ++j)
        o[j] = f2bu(acc[mt * 3 + t][j] + ((const float*)&bv[t])[j]);
      int off = row * 192 + (((colb >> 3) ^ (row & 7)) << 3) + (colb & 7);
      *(uint2*)(Ab + off) = *(uint2*)o;
    }
  }
}

// ---------------- main fused kernel ----------------
// R12: section-shaped wave tiles. lds_gemm col-split 64x48 (14KB LDS/phase vs
// 18KB), encoders row-split 16x192 (local LN, 1x global x reads), SOFM
// row-split (no dedup), P-scratch stride 40 (bank-spread). Same 37-phase
// K64 chunk stream, same reg regime (acc 96 co-live, waves_per_eu(2)).
__global__ __launch_bounds__(256) __attribute__((amdgpu_waves_per_eu(2))) void arn_main(
    const float* __restrict__ xv, const float* __restrict__ xa, const float* __restrict__ xt,
    const ushort_t* __restrict__ wsu, const ushort_t* __restrict__ kvf,
    const float* __restrict__ ggn, unsigned* __restrict__ counts,
    const float* __restrict__ ebv, const float* __restrict__ egv, const float* __restrict__ ebbv,
    const float* __restrict__ eba, const float* __restrict__ ega, const float* __restrict__ ebba,
    const float* __restrict__ ebt, const float* __restrict__ egt, const float* __restrict__ ebbt,
    const float* __restrict__ fb, const float* __restrict__ fg, const float* __restrict__ fbb,
    const float* __restrict__ rbq, const float* __restrict__ rbo) {
  __shared__ __align__(16) ushort_t Abuf[64 * 192 + 64];  // swizzled activations + zero pad
  __shared__ __align__(16) ushort_t Wbuf[2][12288];       // double-buffered K64 W chunks
  __shared__ float2 lnscr[64][4];
  __shared__ __align__(16) float c_l[64];
  __shared__ unsigned hist[64];

  const int tid = threadIdx.x, lane = tid & 63, wave = tid >> 6;
  const int m = lane & 15, gq = lane >> 4;
  const int wc0 = wave * 48;             // col-split GEMM col base
  const int aw0 = wave * 16;             // row-split row base (enc/attn/SOFM)
  const int growbase = blockIdx.x * 64;

  if (tid < 64) { hist[tid] = 0u; c_l[tid] = 0.5f * ggn[tid]; Abuf[12288 + tid] = 0; }

  int gph = 0;
  { int nseg; const ushort_t* s0 = chunk_ptr(wsu, 0, &nseg); stage_to(&Wbuf[0][0], s0, nseg, wave, lane); }

  const int row0 = growbase + aw0 + m;   // this lane's global row (row-split)
  const int rloc = aw0 + m;              // local row in Abuf
  f32x4 accF[12];
#pragma unroll
  for (int t = 0; t < 12; ++t) accF[t] = (f32x4){0.f, 0.f, 0.f, 0.f};

  // ===== vib encoder + fus part 0 =====
  {
    f32x4 accE[12];
#pragma unroll
    for (int t = 0; t < 12; ++t) accE[t] = (f32x4){0.f, 0.f, 0.f, 0.f};
    enc_gemm<1>(xv, row0, wsu, Wbuf, &gph, accE, m, gq, wave, lane);
    ln_gelu_enc(accE, ebv, egv, ebbv, Abuf, rloc, gq);
  }
  lds_gemm(Abuf, wsu, Wbuf, &gph, accF, wc0, m, gq, wave, lane);

  // ===== aco encoder + fus part 1 =====
  {
    f32x4 accE[12];
#pragma unroll
    for (int t = 0; t < 12; ++t) accE[t] = (f32x4){0.f, 0.f, 0.f, 0.f};
    enc_gemm<4>(xa, row0, wsu, Wbuf, &gph, accE, m, gq, wave, lane);
    ln_gelu_enc(accE, eba, ega, ebba, Abuf, rloc, gq);
  }
  lds_gemm(Abuf, wsu, Wbuf, &gph, accF, wc0, m, gq, wave, lane);

  // ===== tmp encoder + fus part 2 + fusion LN =====
  {
    f32x4 accE[12];
#pragma unroll
    for (int t = 0; t < 12; ++t) accE[t] = (f32x4){0.f, 0.f, 0.f, 0.f};
    enc_gemm<2>(xt, row0, wsu, Wbuf, &gph, accE, m, gq, wave, lane);
    ln_gelu_enc(accE, ebt, egt, ebbt, Abuf, rloc, gq);
  }
  lds_gemm(Abuf, wsu, Wbuf, &gph, accF, wc0, m, gq, wave, lane);
  ln_gelu_fus(accF, fb, fg, fbb, Abuf, lnscr, wave, wc0, m, gq);

  // ===== 3 resonance layers =====
  for (int i = 0; i < 3; ++i) {
    {
      f32x4 accQ[12];
#pragma unroll
      for (int t = 0; t < 12; ++t) accQ[t] = (f32x4){0.f, 0.f, 0.f, 0.f};
      lds_gemm(Abuf, wsu, Wbuf, &gph, accQ, wc0, m, gq, wave, lane);
      bias_store_cs(accQ, rbq + i * 192, Abuf, wc0, m, gq);
    }
    __syncthreads();  // Q visible to all waves
    {
      // P scratch in Wbuf[0] (last wq phase is even; in-flight prefetch -> Wbuf[1]).
      // Stride 40 ushorts: banks spread (20m mod 32), 2-way max.
      const ushort_t* kvl = kvf + i * 10240;
      ushort_t* Pw = &Wbuf[0][0] + wave * 640;  // [16 rows][40 slots; 16..31 zero, 32..39 pad]
      *(uint2*)(Pw + (lane >> 2) * 40 + 16 + (lane & 3) * 4) = (uint2){0u, 0u};
      const float scale = 0.144337567297406441f;  // 1/sqrt(48)
#pragma unroll
      for (int h = 0; h < 4; ++h) {
        f32x4 s4 = (f32x4){0.f, 0.f, 0.f, 0.f};
#pragma unroll
        for (int ks = 0; ks < 2; ++ks) {
          int kg = h * 6 + ks * 4 + gq;
          int r = aw0 + m;
          short8 a = *(const short8*)(Abuf + r * 192 + ((kg ^ (r & 7)) << 3));
          short8 b = *(const short8*)(kvl + h * 1024 + m * 64 + ks * 32 + gq * 8);
          s4 = MFMA16(b, a, s4);   // s4[j] = score[slot gq*4+j][qrow aw0+m]
        }
        float e[4];
        float mx = -3.0e38f;
#pragma unroll
        for (int j = 0; j < 4; ++j) { e[j] = s4[j] * scale; mx = fmaxf(mx, e[j]); }
        mx = fmaxf(mx, __shfl_xor(mx, 16, 64));
        mx = fmaxf(mx, __shfl_xor(mx, 32, 64));
        float sm = 0.f;
#pragma unroll
        for (int j = 0; j < 4; ++j) { e[j] = exp2f((e[j] - mx) * 1.44269504f); sm += e[j]; }
        sm += __shfl_xor(sm, 16, 64);
        sm += __shfl_xor(sm, 32, 64);
        float inv = fastrcp(sm);
        ushort_t p4[4];
#pragma unroll
        for (int j = 0; j < 4; ++j) p4[j] = f2bu(e[j] * inv);
        *(uint2*)(Pw + m * 40 + gq * 4) = *(uint2*)p4;
        short8 pa = *(const short8*)(Pw + m * 40 + gq * 8);
#pragma unroll
        for (int t = 0; t < 3; ++t) {
          short8 vb = *(const short8*)(kvl + 4096 + h * 1536 + (t * 16 + m) * 32 + gq * 8);
          f32x4 o4 = MFMA16(vb, pa, ((f32x4){0.f, 0.f, 0.f, 0.f}));
          int row = aw0 + m;
          int colb = h * 48 + t * 16 + gq * 4;
          ushort_t o[4];
#pragma unroll
          for (int j = 0; j < 4; ++j) o[j] = f2bu(o4[j]);
          int off = row * 192 + (((colb >> 3) ^ (row & 7)) << 3) + (colb & 7);
          *(uint2*)(Abuf + off) = *(uint2*)o;
        }
      }
    }
    {
      f32x4 accO[12];
#pragma unroll
      for (int t = 0; t < 12; ++t) accO[t] = (f32x4){0.f, 0.f, 0.f, 0.f};
      lds_gemm(Abuf, wsu, Wbuf, &gph, accO, wc0, m, gq, wave, lane);
      bias_store_cs(accO, rbo + i * 192, Abuf, wc0, m, gq);
    }
  }

  // ===== SOFM (row-split): argmax_g (f.g - ||g||^2/2) -> histogram =====
  {
    f32x4 accS[4];
#pragma unroll
    for (int t = 0; t < 4; ++t) accS[t] = (f32x4){0.f, 0.f, 0.f, 0.f};
#pragma unroll
    for (int ph = 0; ph < 3; ++ph) {
      phase_begin(wsu, Wbuf, gph, wave, lane);
      const ushort_t* Wc = &Wbuf[gph & 1][0];
      int r = aw0 + m;
#pragma unroll
      for (int ks = 0; ks < 2; ++ks) {
        int sl = ks * 4 + gq;
        short8 a = *(const short8*)(Abuf + r * 192 + ((ph * 8 + (sl ^ (r & 7))) << 3));
#pragma unroll
        for (int nt = 0; nt < 4; ++nt) {
          int n = nt * 16 + m;
          short8 b = *(const short8*)(Wc + n * 64 + ((sl ^ (n & 7)) << 3));
          accS[nt] = MFMA16(b, a, accS[nt]);  // accS[nt][j] = score[row][g=nt*16+gq*4+j]
        }
      }
      ++gph;
    }
    float bv = -3.0e38f; int bi = 64;
#pragma unroll
    for (int nt = 0; nt < 4; ++nt) {
      int gb = nt * 16 + gq * 4;
      float4 cl = *(const float4*)(c_l + gb);
#pragma unroll
      for (int j = 0; j < 4; ++j) {
        float v = accS[nt][j] - ((const float*)&cl)[j];
        int g = gb + j;
        bool take = (v > bv);  // ascending g within lane: strict > keeps lowest
        bv = take ? v : bv; bi = take ? g : bi;
      }
    }
#pragma unroll
    for (int off = 16; off < 64; off <<= 1) {
      float ov = __shfl_xor(bv, off, 64);
      int oi = __shfl_xor(bi, off, 64);
      bool take = (ov > bv) || (ov == bv && oi < bi);
      bv = take ? ov : bv; bi = take ? oi : bi;
    }
    if (gq == 0) atomicAdd(&hist[bi], 1u);  // one count per row (owner m-lane)
  }
  __syncthreads();
  if (tid < 64 && hist[tid]) atomicAdd(&counts[tid], hist[tid]);
}

// ---------------- finisher ----------------
__global__ void arn_finish(const unsigned* __restrict__ counts, const float* __restrict__ gr,
                           const float* __restrict__ ow, const float* __restrict__ ob,
                           float* __restrict__ out) {
  __shared__ float pooled[192];
  __shared__ float cf[64];
  int t = threadIdx.x;
  if (t < 64) cf[t] = (float)counts[t];
  __syncthreads();
  float s = 0.f;
  for (int g = 0; g < 64; ++g) s += cf[g] * gr[g * 192 + t];
  pooled[t] = s * (1.0f / (float)B_TOTAL);
  __syncthreads();
  if (t < 6) {
    float o = ob[t];
    for (int j = 0; j < 192; ++j) o += pooled[j] * ow[j * 6 + t];
    out[t] = (t == 1) ? fmaxf(o, 0.f) : 1.f / (1.f + expf(-o));
  }
}

// ---------------- launch ----------------
extern "C" void kernel_launch(void* const* d_in, const int* in_sizes, int n_in,
                              void* d_out, int out_size, void* d_ws, size_t ws_size,
                              hipStream_t stream) {
  (void)in_sizes; (void)n_in; (void)out_size; (void)ws_size;
  const float* xv   = (const float*)d_in[0];
  const float* xa   = (const float*)d_in[1];
  const float* xt   = (const float*)d_in[2];
  const float* ewv  = (const float*)d_in[3];
  const float* ebv  = (const float*)d_in[4];
  const float* egv  = (const float*)d_in[5];
  const float* ebbv = (const float*)d_in[6];
  const float* ewa  = (const float*)d_in[7];
  const float* eba  = (const float*)d_in[8];
  const float* ega  = (const float*)d_in[9];
  const float* ebba = (const float*)d_in[10];
  const float* ewt  = (const float*)d_in[11];
  const float* ebt  = (const float*)d_in[12];
  const float* egt  = (const float*)d_in[13];
  const float* ebbt = (const float*)d_in[14];
  const float* fw   = (const float*)d_in[15];
  const float* fb   = (const float*)d_in[16];
  const float* fg   = (const float*)d_in[17];
  const float* fbb  = (const float*)d_in[18];
  const float* rwq  = (const float*)d_in[19];
  const float* rwk  = (const float*)d_in[20];
  const float* rwv  = (const float*)d_in[21];
  const float* rwo  = (const float*)d_in[22];
  const float* rbq  = (const float*)d_in[23];
  const float* rbk  = (const float*)d_in[24];
  const float* rbv  = (const float*)d_in[25];
  const float* rbo  = (const float*)d_in[26];
  const float* rmem = (const float*)d_in[27];
  const float* grid = (const float*)d_in[28];
  const float* ow   = (const float*)d_in[29];
  const float* ob   = (const float*)d_in[30];

  ushort_t* wsu = (ushort_t*)d_ws;
  ushort_t* kvf = wsu + OFF_KV;
  float* wsf = (float*)((char*)d_ws + F32_BYTE_OFF);
  float* ggn = wsf;
  unsigned* cnt = (unsigned*)(wsf + 64);

  prep_weights<<<dim3(256), dim3(256), 0, stream>>>(ewv, ewa, ewt, fw, rwq, rwo, grid, wsu);
  prep_kv<<<dim3(120), dim3(256), 0, stream>>>(rwk, rwv, rbk, rbv, rmem, grid, kvf, ggn, cnt);
  arn_main<<<dim3(2048), dim3(256), 0, stream>>>(xv, xa, xt, wsu, kvf, ggn, cnt,
      ebv, egv, ebbv, eba, ega, ebba, ebt, egt, ebbt, fb, fg, fbb, rbq, rbo);
  arn_finish<<<dim3(1), dim3(192), 0, stream>>>(cnt, grid, ow, ob, (float*)d_out);
}

// Round 13
// 227.680 us; speedup vs baseline: 2.7847x; 1.2679x over previous
//
#include <hip/hip_runtime.h>
#include <hip/hip_bf16.h>
#include <math.h>

typedef unsigned short ushort_t;
typedef __attribute__((ext_vector_type(8))) short short8;
typedef __attribute__((ext_vector_type(4))) float f32x4;

#define B_TOTAL 131072

// ws layout (ushort element offsets). W blobs are K64-split chunk-major:
// chunk = [N rows][64 k]; storage (n, s, j) holds logical k = ck*64 + 8*(s ^ (n&7)) + j.
#define OFF_VIB 0        // 1 chunk  [192][64]  = 12288
#define OFF_ACO 12288    // 4 chunks             = 49152
#define OFF_TMP 61440    // 2 chunks             = 24576
#define OFF_FUS 86016    // 9 chunks (3/part)    = 110592
#define OFF_WK 196608    // 3 layers x 3 chunks [64][64] = 36864   (scale*(wq@K^T))
#define OFF_VPP 233472   // 3 layers x 1 chunk  [192][64] = 36864  (V@wo stacked)
#define OFF_GRID 270336  // 3 chunks [64][64]    = 12288
// f32 region (byte offset): Kv[9216], Vv[9216], bS[192], ggn[64], cnt[64]
#define F32_BYTE_OFF 565248
#define F_KV 0
#define F_VV 9216
#define F_BS 18432
#define F_GGN 18624
#define F_CNT 18688

// prep kernels: explicit RTNE bit-twiddle (cold code)
__device__ __forceinline__ ushort_t f2bu_prep(float f) {
  union { float f; unsigned u; } c; c.f = f;
  unsigned u = c.u;
  unsigned r = (u + 0x7fffu + ((u >> 16) & 1u)) >> 16;  // RTNE
  return (ushort_t)r;
}
// hot kernel: v_cvt bf16 (RTNE on gfx950)
__device__ __forceinline__ ushort_t f2bu(float f) {
  __hip_bfloat16 h = __float2bfloat16(f);
  return *(ushort_t*)&h;
}
__device__ __forceinline__ float fastrcp(float x) { return __builtin_amdgcn_rcpf(x); }
__device__ __forceinline__ float gelu_fast(float x) {
  float u = 0.7978845608f * x * (1.0f + 0.044715f * x * x);
  float E = exp2f(2.88539008f * u);
  float t = 1.0f - 2.0f * fastrcp(E + 1.0f);
  return 0.5f * x * (1.0f + t);
}
#define MFMA16(a, b, c) __builtin_amdgcn_mfma_f32_16x16x32_bf16(a, b, c, 0, 0, 0)

__device__ __forceinline__ void gload16(const void* g, void* l) {
  __builtin_amdgcn_global_load_lds((const __attribute__((address_space(1))) void*)g,
                                   (__attribute__((address_space(3))) void*)l, 16, 0, 0);
}

// ---------------- prep: weights -> K64-split swizzled chunks ----------------
__global__ void prep_weights(const float* __restrict__ ev, const float* __restrict__ ea,
                             const float* __restrict__ et, const float* __restrict__ fw,
                             const float* __restrict__ gr, ushort_t* __restrict__ ws) {
  int tid = blockIdx.x * blockDim.x + threadIdx.x;
  int nth = gridDim.x * blockDim.x;
  for (int i = tid; i < 12288; i += nth) {
    int n = i >> 6, kin = i & 63;
    int k = 8 * ((kin >> 3) ^ (n & 7)) + (kin & 7);
    ws[OFF_VIB + i] = f2bu_prep(ev[k * 192 + n]);
  }
  for (int i = tid; i < 49152; i += nth) {
    int ck = i / 12288, rem = i % 12288, n = rem >> 6, kin = rem & 63;
    int k = ck * 64 + 8 * ((kin >> 3) ^ (n & 7)) + (kin & 7);
    ws[OFF_ACO + i] = f2bu_prep(ea[k * 192 + n]);
  }
  for (int i = tid; i < 24576; i += nth) {
    int ck = i / 12288, rem = i % 12288, n = rem >> 6, kin = rem & 63;
    int k = ck * 64 + 8 * ((kin >> 3) ^ (n & 7)) + (kin & 7);
    ws[OFF_TMP + i] = f2bu_prep(et[k * 192 + n]);
  }
  for (int i = tid; i < 110592; i += nth) {
    int ck = i / 12288, rem = i % 12288, n = rem >> 6, kin = rem & 63;
    int k = ck * 64 + 8 * ((kin >> 3) ^ (n & 7)) + (kin & 7);
    ws[OFF_FUS + i] = f2bu_prep(fw[k * 192 + n]);
  }
  for (int i = tid; i < 12288; i += nth) {
    int ck = i / 4096, rem = i % 4096, n = rem >> 6, kin = rem & 63;
    int k = ck * 64 + 8 * ((kin >> 3) ^ (n & 7)) + (kin & 7);
    ws[OFF_GRID + i] = f2bu_prep(gr[n * 192 + k]);
  }
}

// ------- prep 1: K/V vectors (fp32): Kv[i][s][192], Vv[i][s][192] ---------
__global__ void prep_kv1(const float* __restrict__ rwk, const float* __restrict__ rwv,
                         const float* __restrict__ rbk, const float* __restrict__ rbv,
                         const float* __restrict__ rmem, const float* __restrict__ gr,
                         float* __restrict__ wsf, unsigned* __restrict__ cnt) {
  int tid = blockIdx.x * blockDim.x + threadIdx.x;
  int nth = gridDim.x * blockDim.x;
  for (int idx = tid; idx < 18432; idx += nth) {
    int bank = idx / 9216, r = idx % 9216;
    int i = r / 3072, q = r % 3072, s = q / 192, d = q % 192;
    const float* w  = (bank ? rwv : rwk) + i * 36864;
    const float* bs = (bank ? rbv : rbk) + i * 192;
    const float* mm = rmem + i * 3072 + s * 192;
    float acc = bs[d];
    for (int kk = 0; kk < 192; ++kk) acc += mm[kk] * w[kk * 192 + d];
    wsf[bank * 9216 + (i * 16 + s) * 192 + d] = acc;
  }
  for (int g = tid; g < 64; g += nth) {
    const float* gp = gr + g * 192;
    float s = 0.f;
    for (int k = 0; k < 192; ++k) s += gp[k] * gp[k];
    wsf[F_GGN + g] = s;
    cnt[g] = 0u;
  }
}

// ------- prep 2: folded attention operands WK, b_S, V'' -------------------
__global__ void prep_kv2(const float* __restrict__ rwq, const float* __restrict__ rbq,
                         const float* __restrict__ rwo, const float* __restrict__ wsf,
                         ushort_t* __restrict__ ws, float* __restrict__ bS) {
  int tid = blockIdx.x * blockDim.x + threadIdx.x;
  int nth = gridDim.x * blockDim.x;
  const float scale = 0.144337567297406441f;  // 1/sqrt(48)
  const float* Kv = wsf + F_KV;
  const float* Vv = wsf + F_VV;
  // WK chunks: [64 n=slot][64 k], n: h=n>>4, s=n&15
  for (int idx = tid; idx < 36864; idx += nth) {
    int i = idx / 12288, rem = idx % 12288;
    int ck = rem >> 12, r2 = rem & 4095, n = r2 >> 6, kin = r2 & 63;
    int k = ck * 64 + 8 * ((kin >> 3) ^ (n & 7)) + (kin & 7);
    int h = n >> 4, s = n & 15;
    const float* kvp = Kv + (i * 16 + s) * 192 + h * 48;
    const float* wqp = rwq + i * 36864 + k * 192 + h * 48;
    float acc = 0.f;
    for (int d = 0; d < 48; ++d) acc += wqp[d] * kvp[d];
    ws[OFF_WK + idx] = f2bu_prep(scale * acc);
  }
  // b_S[i][n] = scale * bq_h . K_h[s]
  for (int idx = tid; idx < 192; idx += nth) {
    int i = idx >> 6, n = idx & 63, h = n >> 4, s = n & 15;
    const float* kvp = Kv + (i * 16 + s) * 192 + h * 48;
    const float* bqp = rbq + i * 192 + h * 48;
    float acc = 0.f;
    for (int d = 0; d < 48; ++d) acc += bqp[d] * kvp[d];
    bS[idx] = scale * acc;
  }
  // V'' chunk: [192 n=col][64 k=slot], k: h=k>>4, s=k&15
  for (int idx = tid; idx < 36864; idx += nth) {
    int i = idx / 12288, rem = idx % 12288;
    int n = rem >> 6, kin = rem & 63;
    int k = 8 * ((kin >> 3) ^ (n & 7)) + (kin & 7);
    int h = k >> 4, s = k & 15;
    const float* vvp = Vv + (i * 16 + s) * 192 + h * 48;
    const float* wop = rwo + i * 36864 + (h * 48) * 192 + n;
    float acc = 0.f;
    for (int d = 0; d < 48; ++d) acc += vvp[d] * wop[d * 192];
    ws[OFF_VPP + idx] = f2bu_prep(acc);
  }
}

// ---------------- main-kernel helpers (4-wave block, K64 chunks) ----------------
__device__ __forceinline__ void stage_to(ushort_t* dst, const ushort_t* src, int nseg,
                                         int wave, int lane) {
  for (int s = wave; s < nseg; s += 4)
    gload16(src + (s << 9) + lane * 8, dst + (s << 9));
}

// consumption-order phase table (31 phases); nseg in 1KB segments
__device__ __forceinline__ const ushort_t* chunk_ptr(const ushort_t* wsu, int g, int* nseg) {
  *nseg = 24;
  if (g < 1)            return wsu + OFF_VIB;
  g -= 1;  if (g < 3)   return wsu + OFF_FUS + g * 12288;
  g -= 3;  if (g < 4)   return wsu + OFF_ACO + g * 12288;
  g -= 4;  if (g < 3)   return wsu + OFF_FUS + 36864 + g * 12288;
  g -= 3;  if (g < 2)   return wsu + OFF_TMP + g * 12288;
  g -= 2;  if (g < 3)   return wsu + OFF_FUS + 73728 + g * 12288;
  g -= 3;  if (g < 12)  { int l = g >> 2, r2 = g & 3;
    if (r2 < 3) { *nseg = 8; return wsu + OFF_WK + l * 12288 + r2 * 4096; }
    return wsu + OFF_VPP + l * 12288; }   // 24 segs
  g -= 12; if (g < 3)   { *nseg = 8; return wsu + OFF_GRID + g * 4096; }
  *nseg = 0; return wsu;
}

__device__ __forceinline__ void phase_begin(const ushort_t* wsu, ushort_t (*Wb)[12288],
                                            int gph, int wave, int lane) {
  __syncthreads();
  int nseg; const ushort_t* ns = chunk_ptr(wsu, gph + 1, &nseg);
  if (nseg) stage_to(&Wb[(gph + 1) & 1][0], ns, nseg, wave, lane);
}

__device__ __forceinline__ short8 cvt8(float4 a, float4 b) {
  short8 v;
  v[0] = (short)f2bu(a.x); v[1] = (short)f2bu(a.y); v[2] = (short)f2bu(a.z); v[3] = (short)f2bu(a.w);
  v[4] = (short)f2bu(b.x); v[5] = (short)f2bu(b.y); v[6] = (short)f2bu(b.z); v[7] = (short)f2bu(b.w);
  return v;
}

// encoder GEMM, ROW-SPLIT: wave owns 16 rows x all 192 out-cols.
template<int NPH>
__device__ __forceinline__ void enc_gemm(const float* __restrict__ x, int row0,
    const ushort_t* wsu, ushort_t (*Wb)[12288], int* gph, f32x4* accE,
    int m, int gq, int wave, int lane) {
  const int KF = NPH * 64;
  const float* p0 = x + (size_t)row0 * KF + gq * 8;
  float4 ca0 = *(const float4*)(p0);
  float4 ca1 = *(const float4*)(p0 + 4);
#pragma unroll
  for (int ph = 0; ph < NPH; ++ph) {
    phase_begin(wsu, Wb, *gph, wave, lane);
    const ushort_t* Wc = &Wb[*gph & 1][0];
#pragma unroll
    for (int ks = 0; ks < 2; ++ks) {
      int sl = ks * 4 + gq;
      short8 a = cvt8(ca0, ca1);
      int nk = ph * 64 + ks * 32 + 32;
      if (nk < KF) {
        ca0 = *(const float4*)(p0 + nk);
        ca1 = *(const float4*)(p0 + nk + 4);
      }
#pragma unroll
      for (int t = 0; t < 12; ++t) {
        int n = t * 16 + m;
        short8 b = *(const short8*)(Wc + n * 64 + ((sl ^ (n & 7)) << 3));
        accE[t] = MFMA16(b, a, accE[t]);
      }
    }
    ++*gph;
  }
}

// GEMM from activation panel, COL-SPLIT: wave owns all 64 rows x 48 cols.
__device__ __forceinline__ void lds_gemm(const ushort_t* Ab, const ushort_t* wsu,
    ushort_t (*Wb)[12288], int* gph, f32x4* acc, int wc0, int m, int gq,
    int wave, int lane) {
#pragma unroll
  for (int ph = 0; ph < 3; ++ph) {
    phase_begin(wsu, Wb, *gph, wave, lane);
    const ushort_t* Wc = &Wb[*gph & 1][0];
#pragma unroll
    for (int ks = 0; ks < 2; ++ks) {
      int sl = ks * 4 + gq;
      short8 b0, b1, b2;
      {
        int n0 = wc0 + m, n1 = wc0 + 16 + m, n2 = wc0 + 32 + m;
        b0 = *(const short8*)(Wc + n0 * 64 + ((sl ^ (n0 & 7)) << 3));
        b1 = *(const short8*)(Wc + n1 * 64 + ((sl ^ (n1 & 7)) << 3));
        b2 = *(const short8*)(Wc + n2 * 64 + ((sl ^ (n2 & 7)) << 3));
      }
#pragma unroll
      for (int mt = 0; mt < 4; ++mt) {
        int r = mt * 16 + m;
        short8 a = *(const short8*)(Ab + r * 192 + ((ph * 8 + (sl ^ (r & 7))) << 3));
        acc[mt * 3 + 0] = MFMA16(b0, a, acc[mt * 3 + 0]);
        acc[mt * 3 + 1] = MFMA16(b1, a, acc[mt * 3 + 1]);
        acc[mt * 3 + 2] = MFMA16(b2, a, acc[mt * 3 + 2]);
      }
    }
    ++*gph;
  }
}

// encoder LN+GELU: fully wave-local (row-split).
__device__ __forceinline__ void ln_gelu_enc(f32x4* acc, const float* __restrict__ bias,
    const float* __restrict__ gam, const float* __restrict__ bet,
    ushort_t* __restrict__ Ab, int rloc, int gq) {
  float s = 0.f, q = 0.f;
#pragma unroll
  for (int t = 0; t < 12; ++t) {
    float4 bv = *(const float4*)(bias + t * 16 + gq * 4);
#pragma unroll
    for (int j = 0; j < 4; ++j) {
      float v = acc[t][j] + ((const float*)&bv)[j];
      acc[t][j] = v; s += v; q += v * v;
    }
  }
  s += __shfl_xor(s, 16, 64); q += __shfl_xor(q, 16, 64);
  s += __shfl_xor(s, 32, 64); q += __shfl_xor(q, 32, 64);
  float mean = s * (1.0f / 192.0f);
  float var = q * (1.0f / 192.0f) - mean * mean;
  float rstd = rsqrtf(var + 1e-5f);
#pragma unroll
  for (int t = 0; t < 12; ++t) {
    int colb = t * 16 + gq * 4;
    float4 ga = *(const float4*)(gam + colb);
    float4 be = *(const float4*)(bet + colb);
    ushort_t o[4];
#pragma unroll
    for (int j = 0; j < 4; ++j) {
      float y = (acc[t][j] - mean) * rstd * ((const float*)&ga)[j] + ((const float*)&be)[j];
      o[j] = f2bu(gelu_fast(y));
    }
    int off = rloc * 192 + (((colb >> 3) ^ (rloc & 7)) << 3) + (colb & 7);
    *(uint2*)(Ab + off) = *(uint2*)o;
  }
}

// fusion LN+GELU: col-split (4-way) with cross-wave stats scratch
__device__ __forceinline__ void ln_gelu_fus(f32x4* acc, const float* __restrict__ bias,
    const float* __restrict__ gam, const float* __restrict__ bet,
    ushort_t* __restrict__ Ab, float2 (*scr)[4], int wave, int wc0, int m, int gq) {
  float4 bv[3];
#pragma unroll
  for (int t = 0; t < 3; ++t) bv[t] = *(const float4*)(bias + wc0 + t * 16 + gq * 4);
#pragma unroll
  for (int mt = 0; mt < 4; ++mt) {
    float s = 0.f, q = 0.f;
#pragma unroll
    for (int t = 0; t < 3; ++t)
#pragma unroll
      for (int j = 0; j < 4; ++j) {
        float v = acc[mt * 3 + t][j] + ((const float*)&bv[t])[j];
        acc[mt * 3 + t][j] = v; s += v; q += v * v;
      }
    s += __shfl_xor(s, 16, 64); q += __shfl_xor(q, 16, 64);
    s += __shfl_xor(s, 32, 64); q += __shfl_xor(q, 32, 64);
    if (gq == 0) scr[mt * 16 + m][wave] = (float2){s, q};
  }
  __syncthreads();
#pragma unroll
  for (int mt = 0; mt < 4; ++mt) {
    int row = mt * 16 + m;
    float s = 0.f, q = 0.f;
#pragma unroll
    for (int w = 0; w < 4; ++w) { float2 p = scr[row][w]; s += p.x; q += p.y; }
    float mean = s * (1.0f / 192.0f);
    float var = q * (1.0f / 192.0f) - mean * mean;
    float rstd = rsqrtf(var + 1e-5f);
#pragma unroll
    for (int t = 0; t < 3; ++t) {
      int colb = wc0 + t * 16 + gq * 4;
      float4 ga = *(const float4*)(gam + colb);
      float4 be = *(const float4*)(bet + colb);
      ushort_t o[4];
#pragma unroll
      for (int j = 0; j < 4; ++j) {
        float y = (acc[mt * 3 + t][j] - mean) * rstd * ((const float*)&ga)[j] + ((const float*)&be)[j];
        o[j] = f2bu(gelu_fast(y));
      }
      int off = row * 192 + (((colb >> 3) ^ (row & 7)) << 3) + (colb & 7);
      *(uint2*)(Ab + off) = *(uint2*)o;
    }
  }
}

__device__ __forceinline__ void bias_store_cs(f32x4* acc, const float* __restrict__ bias,
    ushort_t* __restrict__ Ab, int wc0, int m, int gq) {
  float4 bv[3];
#pragma unroll
  for (int t = 0; t < 3; ++t) bv[t] = *(const float4*)(bias + wc0 + t * 16 + gq * 4);
#pragma unroll
  for (int mt = 0; mt < 4; ++mt) {
    int row = mt * 16 + m;
#pragma unroll
    for (int t = 0; t < 3; ++t) {
      int colb = wc0 + t * 16 + gq * 4;
      ushort_t o[4];
#pragma unroll
      for (int j = 0; j < 4; ++j)
        o[j] = f2bu(acc[mt * 3 + t][j] + ((const float*)&bv[t])[j]);
      int off = row * 192 + (((colb >> 3) ^ (row & 7)) << 3) + (colb & 7);
      *(uint2*)(Ab + off) = *(uint2*)o;
    }
  }
}

// ---------------- main fused kernel ----------------
// R13: folded attention. Per resonance layer: GEMM1 S=fused@WK+bS (3 phases,
// wave=head col-split), in-register softmax -> P (8KB LDS panel, Wbuf[0]
// segs 16-23; all GEMM2 phases odd -> no conflict), GEMM2 o=P@V''+bo
// (1 phase). Replaces wq-GEMM + attention + wo-GEMM (6 phases + 20 MFMA).
// 31 phases total.
__global__ __launch_bounds__(256) __attribute__((amdgpu_waves_per_eu(2))) void arn_main(
    const float* __restrict__ xv, const float* __restrict__ xa, const float* __restrict__ xt,
    const ushort_t* __restrict__ wsu, const float* __restrict__ bS,
    const float* __restrict__ ggn, unsigned* __restrict__ counts,
    const float* __restrict__ ebv, const float* __restrict__ egv, const float* __restrict__ ebbv,
    const float* __restrict__ eba, const float* __restrict__ ega, const float* __restrict__ ebba,
    const float* __restrict__ ebt, const float* __restrict__ egt, const float* __restrict__ ebbt,
    const float* __restrict__ fb, const float* __restrict__ fg, const float* __restrict__ fbb,
    const float* __restrict__ rbo) {
  __shared__ __align__(16) ushort_t Abuf[64 * 192 + 64];  // swizzled activations + zero pad
  __shared__ __align__(16) ushort_t Wbuf[2][12288];       // double-buffered K64 W chunks
  __shared__ float2 lnscr[64][4];
  __shared__ __align__(16) float c_l[64];
  __shared__ unsigned hist[64];

  const int tid = threadIdx.x, lane = tid & 63, wave = tid >> 6;
  const int m = lane & 15, gq = lane >> 4;
  const int wc0 = wave * 48;             // col-split GEMM col base
  const int w16 = wave * 16;             // head base / row-split base
  const int growbase = blockIdx.x * 64;

  if (tid < 64) { hist[tid] = 0u; c_l[tid] = 0.5f * ggn[tid]; Abuf[12288 + tid] = 0; }

  int gph = 0;
  { int nseg; const ushort_t* s0 = chunk_ptr(wsu, 0, &nseg); stage_to(&Wbuf[0][0], s0, nseg, wave, lane); }

  const int row0 = growbase + w16 + m;   // this lane's global row (row-split)
  const int rloc = w16 + m;              // local row in Abuf
  f32x4 accF[12];
#pragma unroll
  for (int t = 0; t < 12; ++t) accF[t] = (f32x4){0.f, 0.f, 0.f, 0.f};

  // ===== vib encoder + fus part 0 =====
  {
    f32x4 accE[12];
#pragma unroll
    for (int t = 0; t < 12; ++t) accE[t] = (f32x4){0.f, 0.f, 0.f, 0.f};
    enc_gemm<1>(xv, row0, wsu, Wbuf, &gph, accE, m, gq, wave, lane);
    ln_gelu_enc(accE, ebv, egv, ebbv, Abuf, rloc, gq);
  }
  lds_gemm(Abuf, wsu, Wbuf, &gph, accF, wc0, m, gq, wave, lane);

  // ===== aco encoder + fus part 1 =====
  {
    f32x4 accE[12];
#pragma unroll
    for (int t = 0; t < 12; ++t) accE[t] = (f32x4){0.f, 0.f, 0.f, 0.f};
    enc_gemm<4>(xa, row0, wsu, Wbuf, &gph, accE, m, gq, wave, lane);
    ln_gelu_enc(accE, eba, ega, ebba, Abuf, rloc, gq);
  }
  lds_gemm(Abuf, wsu, Wbuf, &gph, accF, wc0, m, gq, wave, lane);

  // ===== tmp encoder + fus part 2 + fusion LN =====
  {
    f32x4 accE[12];
#pragma unroll
    for (int t = 0; t < 12; ++t) accE[t] = (f32x4){0.f, 0.f, 0.f, 0.f};
    enc_gemm<2>(xt, row0, wsu, Wbuf, &gph, accE, m, gq, wave, lane);
    ln_gelu_enc(accE, ebt, egt, ebbt, Abuf, rloc, gq);
  }
  lds_gemm(Abuf, wsu, Wbuf, &gph, accF, wc0, m, gq, wave, lane);
  ln_gelu_fus(accF, fb, fg, fbb, Abuf, lnscr, wave, wc0, m, gq);

  // ===== 3 folded resonance layers =====
  for (int i = 0; i < 3; ++i) {
    // --- GEMM1: S = fused @ WK + bS (3 phases; wave = head, slots w16..w16+15)
    f32x4 accS[4];
#pragma unroll
    for (int t = 0; t < 4; ++t) accS[t] = (f32x4){0.f, 0.f, 0.f, 0.f};
#pragma unroll
    for (int ph = 0; ph < 3; ++ph) {
      phase_begin(wsu, Wbuf, gph, wave, lane);
      const ushort_t* Wc = &Wbuf[gph & 1][0];
      int n = w16 + m;
#pragma unroll
      for (int ks = 0; ks < 2; ++ks) {
        int sl = ks * 4 + gq;
        short8 b = *(const short8*)(Wc + n * 64 + ((sl ^ (n & 7)) << 3));
#pragma unroll
        for (int mt = 0; mt < 4; ++mt) {
          int r = mt * 16 + m;
          short8 a = *(const short8*)(Abuf + r * 192 + ((ph * 8 + (sl ^ (r & 7))) << 3));
          accS[mt] = MFMA16(b, a, accS[mt]);
        }
      }
      ++gph;
    }
    // --- softmax (per row, this wave's head) -> P panel (Wbuf[0] segs 16-23)
    {
      ushort_t* Pb = &Wbuf[0][0] + 8192;
      float4 bS4 = *(const float4*)(bS + i * 64 + w16 + gq * 4);
      const int gnum = (w16 + gq * 4) >> 3;  // k-granule of this lane's slots
#pragma unroll
      for (int mt = 0; mt < 4; ++mt) {
        float e[4]; float mx = -3.0e38f;
#pragma unroll
        for (int j = 0; j < 4; ++j) { e[j] = accS[mt][j] + ((const float*)&bS4)[j]; mx = fmaxf(mx, e[j]); }
        mx = fmaxf(mx, __shfl_xor(mx, 16, 64));
        mx = fmaxf(mx, __shfl_xor(mx, 32, 64));
        float sm = 0.f;
#pragma unroll
        for (int j = 0; j < 4; ++j) { e[j] = exp2f((e[j] - mx) * 1.44269504f); sm += e[j]; }
        sm += __shfl_xor(sm, 16, 64);
        sm += __shfl_xor(sm, 32, 64);
        float inv = fastrcp(sm);
        ushort_t p4[4];
#pragma unroll
        for (int j = 0; j < 4; ++j) p4[j] = f2bu(e[j] * inv);
        int r = mt * 16 + m;
        *(uint2*)(Pb + r * 64 + ((gnum ^ (r & 7)) << 3) + (gq & 1) * 4) = *(uint2*)p4;
      }
    }
    // --- GEMM2: o = P @ V'' + bo (1 phase; V'' in buf[odd], P in buf[0] hi)
    {
      f32x4 accO[12];
#pragma unroll
      for (int t = 0; t < 12; ++t) accO[t] = (f32x4){0.f, 0.f, 0.f, 0.f};
      phase_begin(wsu, Wbuf, gph, wave, lane);  // barrier makes P visible
      const ushort_t* Wc = &Wbuf[gph & 1][0];
      const ushort_t* Pb = &Wbuf[0][0] + 8192;
#pragma unroll
      for (int ks = 0; ks < 2; ++ks) {
        int sl = ks * 4 + gq;
        short8 b0, b1, b2;
        {
          int n0 = wc0 + m, n1 = wc0 + 16 + m, n2 = wc0 + 32 + m;
          b0 = *(const short8*)(Wc + n0 * 64 + ((sl ^ (n0 & 7)) << 3));
          b1 = *(const short8*)(Wc + n1 * 64 + ((sl ^ (n1 & 7)) << 3));
          b2 = *(const short8*)(Wc + n2 * 64 + ((sl ^ (n2 & 7)) << 3));
        }
#pragma unroll
        for (int mt = 0; mt < 4; ++mt) {
          int r = mt * 16 + m;
          short8 a = *(const short8*)(Pb + r * 64 + ((sl ^ (r & 7)) << 3));
          accO[mt * 3 + 0] = MFMA16(b0, a, accO[mt * 3 + 0]);
          accO[mt * 3 + 1] = MFMA16(b1, a, accO[mt * 3 + 1]);
          accO[mt * 3 + 2] = MFMA16(b2, a, accO[mt * 3 + 2]);
        }
      }
      ++gph;
      bias_store_cs(accO, rbo + i * 192, Abuf, wc0, m, gq);
    }
  }

  // ===== SOFM (row-split): argmax_g (f.g - ||g||^2/2) -> histogram =====
  {
    f32x4 accS[4];
#pragma unroll
    for (int t = 0; t < 4; ++t) accS[t] = (f32x4){0.f, 0.f, 0.f, 0.f};
#pragma unroll
    for (int ph = 0; ph < 3; ++ph) {
      phase_begin(wsu, Wbuf, gph, wave, lane);
      const ushort_t* Wc = &Wbuf[gph & 1][0];
      int r = w16 + m;
#pragma unroll
      for (int ks = 0; ks < 2; ++ks) {
        int sl = ks * 4 + gq;
        short8 a = *(const short8*)(Abuf + r * 192 + ((ph * 8 + (sl ^ (r & 7))) << 3));
#pragma unroll
        for (int nt = 0; nt < 4; ++nt) {
          int n = nt * 16 + m;
          short8 b = *(const short8*)(Wc + n * 64 + ((sl ^ (n & 7)) << 3));
          accS[nt] = MFMA16(b, a, accS[nt]);  // accS[nt][j] = score[row][g=nt*16+gq*4+j]
        }
      }
      ++gph;
    }
    float bv = -3.0e38f; int bi = 64;
#pragma unroll
    for (int nt = 0; nt < 4; ++nt) {
      int gb = nt * 16 + gq * 4;
      float4 cl = *(const float4*)(c_l + gb);
#pragma unroll
      for (int j = 0; j < 4; ++j) {
        float v = accS[nt][j] - ((const float*)&cl)[j];
        int g = gb + j;
        bool take = (v > bv);  // ascending g within lane: strict > keeps lowest
        bv = take ? v : bv; bi = take ? g : bi;
      }
    }
#pragma unroll
    for (int off = 16; off < 64; off <<= 1) {
      float ov = __shfl_xor(bv, off, 64);
      int oi = __shfl_xor(bi, off, 64);
      bool take = (ov > bv) || (ov == bv && oi < bi);
      bv = take ? ov : bv; bi = take ? oi : bi;
    }
    if (gq == 0) atomicAdd(&hist[bi], 1u);  // one count per row (owner m-lane)
  }
  __syncthreads();
  if (tid < 64 && hist[tid]) atomicAdd(&counts[tid], hist[tid]);
}

// ---------------- finisher ----------------
__global__ void arn_finish(const unsigned* __restrict__ counts, const float* __restrict__ gr,
                           const float* __restrict__ ow, const float* __restrict__ ob,
                           float* __restrict__ out) {
  __shared__ float pooled[192];
  __shared__ float cf[64];
  int t = threadIdx.x;
  if (t < 64) cf[t] = (float)counts[t];
  __syncthreads();
  float s = 0.f;
  for (int g = 0; g < 64; ++g) s += cf[g] * gr[g * 192 + t];
  pooled[t] = s * (1.0f / (float)B_TOTAL);
  __syncthreads();
  if (t < 6) {
    float o = ob[t];
    for (int j = 0; j < 192; ++j) o += pooled[j] * ow[j * 6 + t];
    out[t] = (t == 1) ? fmaxf(o, 0.f) : 1.f / (1.f + expf(-o));
  }
}

// ---------------- launch ----------------
extern "C" void kernel_launch(void* const* d_in, const int* in_sizes, int n_in,
                              void* d_out, int out_size, void* d_ws, size_t ws_size,
                              hipStream_t stream) {
  (void)in_sizes; (void)n_in; (void)out_size; (void)ws_size;
  const float* xv   = (const float*)d_in[0];
  const float* xa   = (const float*)d_in[1];
  const float* xt   = (const float*)d_in[2];
  const float* ewv  = (const float*)d_in[3];
  const float* ebv  = (const float*)d_in[4];
  const float* egv  = (const float*)d_in[5];
  const float* ebbv = (const float*)d_in[6];
  const float* ewa  = (const float*)d_in[7];
  const float* eba  = (const float*)d_in[8];
  const float* ega  = (const float*)d_in[9];
  const float* ebba = (const float*)d_in[10];
  const float* ewt  = (const float*)d_in[11];
  const float* ebt  = (const float*)d_in[12];
  const float* egt  = (const float*)d_in[13];
  const float* ebbt = (const float*)d_in[14];
  const float* fw   = (const float*)d_in[15];
  const float* fb   = (const float*)d_in[16];
  const float* fg   = (const float*)d_in[17];
  const float* fbb  = (const float*)d_in[18];
  const float* rwq  = (const float*)d_in[19];
  const float* rwk  = (const float*)d_in[20];
  const float* rwv  = (const float*)d_in[21];
  const float* rwo  = (const float*)d_in[22];
  const float* rbq  = (const float*)d_in[23];
  const float* rbk  = (const float*)d_in[24];
  const float* rbv  = (const float*)d_in[25];
  const float* rbo  = (const float*)d_in[26];
  const float* rmem = (const float*)d_in[27];
  const float* grid = (const float*)d_in[28];
  const float* ow   = (const float*)d_in[29];
  const float* ob   = (const float*)d_in[30];

  ushort_t* wsu = (ushort_t*)d_ws;
  float* wsf = (float*)((char*)d_ws + F32_BYTE_OFF);
  float* bS  = wsf + F_BS;
  float* ggn = wsf + F_GGN;
  unsigned* cnt = (unsigned*)(wsf + F_CNT);

  prep_weights<<<dim3(256), dim3(256), 0, stream>>>(ewv, ewa, ewt, fw, grid, wsu);
  prep_kv1<<<dim3(80), dim3(256), 0, stream>>>(rwk, rwv, rbk, rbv, rmem, grid, wsf, cnt);
  prep_kv2<<<dim3(80), dim3(256), 0, stream>>>(rwq, rbq, rwo, wsf, wsu, bS);
  arn_main<<<dim3(2048), dim3(256), 0, stream>>>(xv, xa, xt, wsu, bS, ggn, cnt,
      ebv, egv, ebbv, eba, ega, ebba, ebt, egt, ebbt, fb, fg, fbb, rbo);
  arn_finish<<<dim3(1), dim3(192), 0, stream>>>(cnt, grid, ow, ob, (float*)d_out);
}

// Round 14
// 218.795 us; speedup vs baseline: 2.8978x; 1.0406x over previous
//
#include <hip/hip_runtime.h>
#include <hip/hip_bf16.h>
#include <math.h>

typedef unsigned short ushort_t;
typedef __attribute__((ext_vector_type(8))) short short8;
typedef __attribute__((ext_vector_type(4))) float f32x4;

#define B_TOTAL 131072

// ws layout (ushort element offsets). W blobs are K64-split chunk-major:
// chunk = [N rows][64 k]; storage (n, s, j) holds logical k = ck*64 + 8*(s ^ (n&7)) + j.
#define OFF_VIB 0        // 1 chunk  [192][64]  = 12288
#define OFF_ACO 12288    // 4 chunks             = 49152
#define OFF_TMP 61440    // 2 chunks             = 24576
#define OFF_FUS 86016    // 9 chunks (3/part)    = 110592
#define OFF_WK 196608    // layer0 only: 3 chunks [64][64] = 12288  (scale*(wq@K^T))
#define OFF_M 208896     // M2, M3, MG chunks [64][64] = 12288 (slot-space folded)
// f32 region at byte 442368: Kv, Vv, Vpp, WKf, bSf, battn, bG, cnt
#define F32_BYTE_OFF 442368
#define F_KV 0
#define F_VV 9216
#define F_VPP 18432
#define F_WKF 55296
#define F_BSF 92160
#define F_BATTN 92352
#define F_BG 92544
#define F_CNT 92608

// prep kernels: explicit RTNE bit-twiddle (cold code)
__device__ __forceinline__ ushort_t f2bu_prep(float f) {
  union { float f; unsigned u; } c; c.f = f;
  unsigned u = c.u;
  unsigned r = (u + 0x7fffu + ((u >> 16) & 1u)) >> 16;  // RTNE
  return (ushort_t)r;
}
// hot kernel: v_cvt bf16 (RTNE on gfx950)
__device__ __forceinline__ ushort_t f2bu(float f) {
  __hip_bfloat16 h = __float2bfloat16(f);
  return *(ushort_t*)&h;
}
__device__ __forceinline__ float fastrcp(float x) { return __builtin_amdgcn_rcpf(x); }
__device__ __forceinline__ float gelu_fast(float x) {
  float u = 0.7978845608f * x * (1.0f + 0.044715f * x * x);
  float E = exp2f(2.88539008f * u);
  float t = 1.0f - 2.0f * fastrcp(E + 1.0f);
  return 0.5f * x * (1.0f + t);
}
#define MFMA16(a, b, c) __builtin_amdgcn_mfma_f32_16x16x32_bf16(a, b, c, 0, 0, 0)

__device__ __forceinline__ void gload16(const void* g, void* l) {
  __builtin_amdgcn_global_load_lds((const __attribute__((address_space(1))) void*)g,
                                   (__attribute__((address_space(3))) void*)l, 16, 0, 0);
}

// ---------------- prep: weights -> K64-split swizzled chunks ----------------
__global__ void prep_weights(const float* __restrict__ ev, const float* __restrict__ ea,
                             const float* __restrict__ et, const float* __restrict__ fw,
                             ushort_t* __restrict__ ws) {
  int tid = blockIdx.x * blockDim.x + threadIdx.x;
  int nth = gridDim.x * blockDim.x;
  for (int i = tid; i < 12288; i += nth) {
    int n = i >> 6, kin = i & 63;
    int k = 8 * ((kin >> 3) ^ (n & 7)) + (kin & 7);
    ws[OFF_VIB + i] = f2bu_prep(ev[k * 192 + n]);
  }
  for (int i = tid; i < 49152; i += nth) {
    int ck = i / 12288, rem = i % 12288, n = rem >> 6, kin = rem & 63;
    int k = ck * 64 + 8 * ((kin >> 3) ^ (n & 7)) + (kin & 7);
    ws[OFF_ACO + i] = f2bu_prep(ea[k * 192 + n]);
  }
  for (int i = tid; i < 24576; i += nth) {
    int ck = i / 12288, rem = i % 12288, n = rem >> 6, kin = rem & 63;
    int k = ck * 64 + 8 * ((kin >> 3) ^ (n & 7)) + (kin & 7);
    ws[OFF_TMP + i] = f2bu_prep(et[k * 192 + n]);
  }
  for (int i = tid; i < 110592; i += nth) {
    int ck = i / 12288, rem = i % 12288, n = rem >> 6, kin = rem & 63;
    int k = ck * 64 + 8 * ((kin >> 3) ^ (n & 7)) + (kin & 7);
    ws[OFF_FUS + i] = f2bu_prep(fw[k * 192 + n]);
  }
}

// ------- prep 1: K/V vectors (fp32): Kv[i][s][192], Vv[i][s][192] ---------
__global__ void prep_kv1(const float* __restrict__ rwk, const float* __restrict__ rwv,
                         const float* __restrict__ rbk, const float* __restrict__ rbv,
                         const float* __restrict__ rmem, float* __restrict__ wsf,
                         unsigned* __restrict__ cnt) {
  int tid = blockIdx.x * blockDim.x + threadIdx.x;
  int nth = gridDim.x * blockDim.x;
  for (int idx = tid; idx < 18432; idx += nth) {
    int bank = idx / 9216, r = idx % 9216;
    int i = r / 3072, q = r % 3072, s = q / 192, d = q % 192;
    const float* w  = (bank ? rwv : rwk) + i * 36864;
    const float* bs = (bank ? rbv : rbk) + i * 192;
    const float* mm = rmem + i * 3072 + s * 192;
    float acc = bs[d];
    for (int kk = 0; kk < 192; ++kk) acc += mm[kk] * w[kk * 192 + d];
    wsf[bank * 9216 + (i * 16 + s) * 192 + d] = acc;
  }
  for (int g = tid; g < 64; g += nth) cnt[g] = 0u;
}

// ------- prep 2: fp32 WKf[i][n=h*16+s][192], Vpp[i][s1][192], bSf; WK1 bf16 --
__global__ void prep_kv2(const float* __restrict__ rwq, const float* __restrict__ rbq,
                         const float* __restrict__ rwo, float* __restrict__ wsf,
                         ushort_t* __restrict__ ws) {
  int tid = blockIdx.x * blockDim.x + threadIdx.x;
  int nth = gridDim.x * blockDim.x;
  const float scale = 0.144337567297406441f;  // 1/sqrt(48)
  const float* Kv = wsf + F_KV;
  const float* Vv = wsf + F_VV;
  float* WKf = wsf + F_WKF;
  float* Vpp = wsf + F_VPP;
  float* bSf = wsf + F_BSF;
  // WKf fp32
  for (int idx = tid; idx < 36864; idx += nth) {
    int i = idx / 12288, rem = idx % 12288, n = rem / 192, k = rem % 192;
    int h = n >> 4, s = n & 15;
    const float* kvp = Kv + (i * 16 + s) * 192 + h * 48;
    const float* wqp = rwq + i * 36864 + k * 192 + h * 48;
    float acc = 0.f;
    for (int d = 0; d < 48; ++d) acc += wqp[d] * kvp[d];
    WKf[idx] = scale * acc;
  }
  // WK1 bf16 chunks (layer 0), computed directly (no intra-kernel dependency)
  for (int idx = tid; idx < 12288; idx += nth) {
    int ck = idx >> 12, r2 = idx & 4095, n = r2 >> 6, kin = r2 & 63;
    int k = ck * 64 + 8 * ((kin >> 3) ^ (n & 7)) + (kin & 7);
    int h = n >> 4, s = n & 15;
    const float* kvp = Kv + s * 192 + h * 48;
    const float* wqp = rwq + k * 192 + h * 48;
    float acc = 0.f;
    for (int d = 0; d < 48; ++d) acc += wqp[d] * kvp[d];
    ws[OFF_WK + idx] = f2bu_prep(scale * acc);
  }
  // Vpp[i][s1][dcol] = V_i[s1] @ wo_i  (rows h*48.. of wo)
  for (int idx = tid; idx < 36864; idx += nth) {
    int i = idx / 12288, rem = idx % 12288, n = rem / 192, dcol = rem % 192;
    int h = n >> 4, s = n & 15;
    const float* vvp = Vv + (i * 16 + s) * 192 + h * 48;
    const float* wop = rwo + i * 36864 + (h * 48) * 192 + dcol;
    float acc = 0.f;
    for (int d = 0; d < 48; ++d) acc += vvp[d] * wop[d * 192];
    Vpp[idx] = acc;
  }
  // bSf[i][n] = scale * bq_h . K_h[s]
  for (int idx = tid; idx < 192; idx += nth) {
    int i = idx >> 6, n = idx & 63, h = n >> 4, s = n & 15;
    const float* kvp = Kv + (i * 16 + s) * 192 + h * 48;
    const float* bqp = rbq + i * 192 + h * 48;
    float acc = 0.f;
    for (int d = 0; d < 48; ++d) acc += bqp[d] * kvp[d];
    bSf[idx] = scale * acc;
  }
}

// ------- prep 3: slot-space folds M2, M3, MG (bf16 chunks) + battn + bG -----
__global__ void prep_kv3(const float* __restrict__ rbo, const float* __restrict__ gr,
                         float* __restrict__ wsf, ushort_t* __restrict__ ws) {
  int tid = blockIdx.x * blockDim.x + threadIdx.x;
  int nth = gridDim.x * blockDim.x;
  const float* Vpp = wsf + F_VPP;
  const float* WKf = wsf + F_WKF;
  const float* bSf = wsf + F_BSF;
  // M_{l+1}[s1][s2] = Vpp[l][s1] . WKf[l+1][s2]; chunk [n=s2][k=s1] swizzled
  for (int idx = tid; idx < 8192; idx += nth) {
    int l = idx >> 12, rem = idx & 4095, n = rem >> 6, kin = rem & 63;
    int k = 8 * ((kin >> 3) ^ (n & 7)) + (kin & 7);
    const float* vp = Vpp + l * 12288 + k * 192;
    const float* wp = WKf + (l + 1) * 12288 + n * 192;
    float acc = 0.f;
    for (int t = 0; t < 192; ++t) acc += vp[t] * wp[t];
    ws[OFF_M + l * 4096 + n * 64 + kin] = f2bu_prep(acc);
  }
  // MG[s1][g] = Vpp[2][s1] . grid[g]; chunk [n=g][k=s1]
  for (int idx = tid; idx < 4096; idx += nth) {
    int n = idx >> 6, kin = idx & 63;
    int k = 8 * ((kin >> 3) ^ (n & 7)) + (kin & 7);
    const float* vp = Vpp + 2 * 12288 + k * 192;
    const float* gp = gr + n * 192;
    float acc = 0.f;
    for (int t = 0; t < 192; ++t) acc += vp[t] * gp[t];
    ws[OFF_M + 8192 + n * 64 + kin] = f2bu_prep(acc);
  }
  // battn[0]=bSf0; battn[l]=bSf[l]+bo_{l-1}@WKf[l]
  for (int idx = tid; idx < 192; idx += nth) {
    int l = idx >> 6, n = idx & 63;
    float acc = bSf[l * 64 + n];
    if (l > 0) {
      const float* wp = WKf + l * 12288 + n * 192;
      const float* bo = rbo + (l - 1) * 192;
      for (int t = 0; t < 192; ++t) acc += bo[t] * wp[t];
    }
    wsf[F_BATTN + idx] = acc;
  }
  // bG[g] = bo2 . grid[g] - 0.5*||grid[g]||^2
  for (int g = tid; g < 64; g += nth) {
    const float* gp = gr + g * 192;
    const float* bo = rbo + 2 * 192;
    float a = 0.f, s = 0.f;
    for (int t = 0; t < 192; ++t) { a += bo[t] * gp[t]; s += gp[t] * gp[t]; }
    wsf[F_BG + g] = a - 0.5f * s;
  }
}

// ---------------- main-kernel helpers (4-wave block, K64 chunks) ----------------
__device__ __forceinline__ void stage_to(ushort_t* dst, const ushort_t* src, int nseg,
                                         int wave, int lane) {
  for (int s = wave; s < nseg; s += 4)
    gload16(src + (s << 9) + lane * 8, dst + (s << 9));
}

// consumption-order phase table (22 phases); nseg in 1KB segments
__device__ __forceinline__ const ushort_t* chunk_ptr(const ushort_t* wsu, int g, int* nseg) {
  *nseg = 24;
  if (g < 1)            return wsu + OFF_VIB;
  g -= 1;  if (g < 3)   return wsu + OFF_FUS + g * 12288;
  g -= 3;  if (g < 4)   return wsu + OFF_ACO + g * 12288;
  g -= 4;  if (g < 3)   return wsu + OFF_FUS + 36864 + g * 12288;
  g -= 3;  if (g < 2)   return wsu + OFF_TMP + g * 12288;
  g -= 2;  if (g < 3)   return wsu + OFF_FUS + 73728 + g * 12288;
  g -= 3;  if (g < 3)   { *nseg = 8; return wsu + OFF_WK + g * 4096; }  // phases 16-18
  g -= 3;  if (g < 3)   { *nseg = 8; return wsu + OFF_M + g * 4096; }   // 19: M2, 20: M3, 21: MG
  *nseg = 0; return wsu;
}

__device__ __forceinline__ void phase_begin(const ushort_t* wsu, ushort_t (*Wb)[12288],
                                            int gph, int wave, int lane) {
  __syncthreads();
  int nseg; const ushort_t* ns = chunk_ptr(wsu, gph + 1, &nseg);
  if (nseg) stage_to(&Wb[(gph + 1) & 1][0], ns, nseg, wave, lane);
}

__device__ __forceinline__ short8 cvt8(float4 a, float4 b) {
  short8 v;
  v[0] = (short)f2bu(a.x); v[1] = (short)f2bu(a.y); v[2] = (short)f2bu(a.z); v[3] = (short)f2bu(a.w);
  v[4] = (short)f2bu(b.x); v[5] = (short)f2bu(b.y); v[6] = (short)f2bu(b.z); v[7] = (short)f2bu(b.w);
  return v;
}

// encoder GEMM, ROW-SPLIT: wave owns 16 rows x all 192 out-cols.
template<int NPH>
__device__ __forceinline__ void enc_gemm(const float* __restrict__ x, int row0,
    const ushort_t* wsu, ushort_t (*Wb)[12288], int* gph, f32x4* accE,
    int m, int gq, int wave, int lane) {
  const int KF = NPH * 64;
  const float* p0 = x + (size_t)row0 * KF + gq * 8;
  float4 ca0 = *(const float4*)(p0);
  float4 ca1 = *(const float4*)(p0 + 4);
#pragma unroll
  for (int ph = 0; ph < NPH; ++ph) {
    phase_begin(wsu, Wb, *gph, wave, lane);
    const ushort_t* Wc = &Wb[*gph & 1][0];
#pragma unroll
    for (int ks = 0; ks < 2; ++ks) {
      int sl = ks * 4 + gq;
      short8 a = cvt8(ca0, ca1);
      int nk = ph * 64 + ks * 32 + 32;
      if (nk < KF) {
        ca0 = *(const float4*)(p0 + nk);
        ca1 = *(const float4*)(p0 + nk + 4);
      }
#pragma unroll
      for (int t = 0; t < 12; ++t) {
        int n = t * 16 + m;
        short8 b = *(const short8*)(Wc + n * 64 + ((sl ^ (n & 7)) << 3));
        accE[t] = MFMA16(b, a, accE[t]);
      }
    }
    ++*gph;
  }
}

// GEMM from activation panel, COL-SPLIT: wave owns all 64 rows x 48 cols.
__device__ __forceinline__ void lds_gemm(const ushort_t* Ab, const ushort_t* wsu,
    ushort_t (*Wb)[12288], int* gph, f32x4* acc, int wc0, int m, int gq,
    int wave, int lane) {
#pragma unroll
  for (int ph = 0; ph < 3; ++ph) {
    phase_begin(wsu, Wb, *gph, wave, lane);
    const ushort_t* Wc = &Wb[*gph & 1][0];
#pragma unroll
    for (int ks = 0; ks < 2; ++ks) {
      int sl = ks * 4 + gq;
      short8 b0, b1, b2;
      {
        int n0 = wc0 + m, n1 = wc0 + 16 + m, n2 = wc0 + 32 + m;
        b0 = *(const short8*)(Wc + n0 * 64 + ((sl ^ (n0 & 7)) << 3));
        b1 = *(const short8*)(Wc + n1 * 64 + ((sl ^ (n1 & 7)) << 3));
        b2 = *(const short8*)(Wc + n2 * 64 + ((sl ^ (n2 & 7)) << 3));
      }
#pragma unroll
      for (int mt = 0; mt < 4; ++mt) {
        int r = mt * 16 + m;
        short8 a = *(const short8*)(Ab + r * 192 + ((ph * 8 + (sl ^ (r & 7))) << 3));
        acc[mt * 3 + 0] = MFMA16(b0, a, acc[mt * 3 + 0]);
        acc[mt * 3 + 1] = MFMA16(b1, a, acc[mt * 3 + 1]);
        acc[mt * 3 + 2] = MFMA16(b2, a, acc[mt * 3 + 2]);
      }
    }
    ++*gph;
  }
}

// encoder LN+GELU: fully wave-local (row-split).
__device__ __forceinline__ void ln_gelu_enc(f32x4* acc, const float* __restrict__ bias,
    const float* __restrict__ gam, const float* __restrict__ bet,
    ushort_t* __restrict__ Ab, int rloc, int gq) {
  float s = 0.f, q = 0.f;
#pragma unroll
  for (int t = 0; t < 12; ++t) {
    float4 bv = *(const float4*)(bias + t * 16 + gq * 4);
#pragma unroll
    for (int j = 0; j < 4; ++j) {
      float v = acc[t][j] + ((const float*)&bv)[j];
      acc[t][j] = v; s += v; q += v * v;
    }
  }
  s += __shfl_xor(s, 16, 64); q += __shfl_xor(q, 16, 64);
  s += __shfl_xor(s, 32, 64); q += __shfl_xor(q, 32, 64);
  float mean = s * (1.0f / 192.0f);
  float var = q * (1.0f / 192.0f) - mean * mean;
  float rstd = rsqrtf(var + 1e-5f);
#pragma unroll
  for (int t = 0; t < 12; ++t) {
    int colb = t * 16 + gq * 4;
    float4 ga = *(const float4*)(gam + colb);
    float4 be = *(const float4*)(bet + colb);
    ushort_t o[4];
#pragma unroll
    for (int j = 0; j < 4; ++j) {
      float y = (acc[t][j] - mean) * rstd * ((const float*)&ga)[j] + ((const float*)&be)[j];
      o[j] = f2bu(gelu_fast(y));
    }
    int off = rloc * 192 + (((colb >> 3) ^ (rloc & 7)) << 3) + (colb & 7);
    *(uint2*)(Ab + off) = *(uint2*)o;
  }
}

// fusion LN+GELU: col-split (4-way) with cross-wave stats scratch
__device__ __forceinline__ void ln_gelu_fus(f32x4* acc, const float* __restrict__ bias,
    const float* __restrict__ gam, const float* __restrict__ bet,
    ushort_t* __restrict__ Ab, float2 (*scr)[4], int wave, int wc0, int m, int gq) {
  float4 bv[3];
#pragma unroll
  for (int t = 0; t < 3; ++t) bv[t] = *(const float4*)(bias + wc0 + t * 16 + gq * 4);
#pragma unroll
  for (int mt = 0; mt < 4; ++mt) {
    float s = 0.f, q = 0.f;
#pragma unroll
    for (int t = 0; t < 3; ++t)
#pragma unroll
      for (int j = 0; j < 4; ++j) {
        float v = acc[mt * 3 + t][j] + ((const float*)&bv[t])[j];
        acc[mt * 3 + t][j] = v; s += v; q += v * v;
      }
    s += __shfl_xor(s, 16, 64); q += __shfl_xor(q, 16, 64);
    s += __shfl_xor(s, 32, 64); q += __shfl_xor(q, 32, 64);
    if (gq == 0) scr[mt * 16 + m][wave] = (float2){s, q};
  }
  __syncthreads();
#pragma unroll
  for (int mt = 0; mt < 4; ++mt) {
    int row = mt * 16 + m;
    float s = 0.f, q = 0.f;
#pragma unroll
    for (int w = 0; w < 4; ++w) { float2 p = scr[row][w]; s += p.x; q += p.y; }
    float mean = s * (1.0f / 192.0f);
    float var = q * (1.0f / 192.0f) - mean * mean;
    float rstd = rsqrtf(var + 1e-5f);
#pragma unroll
    for (int t = 0; t < 3; ++t) {
      int colb = wc0 + t * 16 + gq * 4;
      float4 ga = *(const float4*)(gam + colb);
      float4 be = *(const float4*)(bet + colb);
      ushort_t o[4];
#pragma unroll
      for (int j = 0; j < 4; ++j) {
        float y = (acc[mt * 3 + t][j] - mean) * rstd * ((const float*)&ga)[j] + ((const float*)&be)[j];
        o[j] = f2bu(gelu_fast(y));
      }
      int off = row * 192 + (((colb >> 3) ^ (row & 7)) << 3) + (colb & 7);
      *(uint2*)(Ab + off) = *(uint2*)o;
    }
  }
}

// softmax over this wave's 16 slots (head = wave) -> write P panel (swizzled)
__device__ __forceinline__ void softmax_to_P(f32x4* accS, const float* __restrict__ bptr,
    ushort_t* __restrict__ Pb, int w16, int m, int gq) {
  float4 b4 = *(const float4*)(bptr + w16 + gq * 4);
  const int gnum = (w16 + gq * 4) >> 3;
#pragma unroll
  for (int mt = 0; mt < 4; ++mt) {
    float e[4]; float mx = -3.0e38f;
#pragma unroll
    for (int j = 0; j < 4; ++j) { e[j] = accS[mt][j] + ((const float*)&b4)[j]; mx = fmaxf(mx, e[j]); }
    mx = fmaxf(mx, __shfl_xor(mx, 16, 64));
    mx = fmaxf(mx, __shfl_xor(mx, 32, 64));
    float sm = 0.f;
#pragma unroll
    for (int j = 0; j < 4; ++j) { e[j] = exp2f((e[j] - mx) * 1.44269504f); sm += e[j]; }
    sm += __shfl_xor(sm, 16, 64);
    sm += __shfl_xor(sm, 32, 64);
    float inv = fastrcp(sm);
    ushort_t p4[4];
#pragma unroll
    for (int j = 0; j < 4; ++j) p4[j] = f2bu(e[j] * inv);
    int r = mt * 16 + m;
    *(uint2*)(Pb + r * 64 + ((gnum ^ (r & 7)) << 3) + (gq & 1) * 4) = *(uint2*)p4;
  }
}

// ---------------- main fused kernel ----------------
// R14: fully folded resonance chain. GEMM1 (fused@WK1, 3 phases) -> P1;
// then S_{i+1} = P_i @ M_{i+1} + b (1 phase each, M = V''@WK folded 64x64),
// and SOFM scores = P3 @ MG + bG (1 phase, MG = V''3@G^T, bG absorbs
// bo3@G^T - 0.5||g||^2). P panels ping-pong in Wbuf[phase&1] segs 16-23
// (disjoint from 8KB chunk prefetch segs 0-7; parity-verified). 22 phases.
__global__ __launch_bounds__(256) __attribute__((amdgpu_waves_per_eu(2))) void arn_main(
    const float* __restrict__ xv, const float* __restrict__ xa, const float* __restrict__ xt,
    const ushort_t* __restrict__ wsu, const float* __restrict__ battn,
    const float* __restrict__ bG, unsigned* __restrict__ counts,
    const float* __restrict__ ebv, const float* __restrict__ egv, const float* __restrict__ ebbv,
    const float* __restrict__ eba, const float* __restrict__ ega, const float* __restrict__ ebba,
    const float* __restrict__ ebt, const float* __restrict__ egt, const float* __restrict__ ebbt,
    const float* __restrict__ fb, const float* __restrict__ fg, const float* __restrict__ fbb) {
  __shared__ __align__(16) ushort_t Abuf[64 * 192 + 64];  // swizzled activations + zero pad
  __shared__ __align__(16) ushort_t Wbuf[2][12288];       // double-buffered K64 W chunks
  __shared__ float2 lnscr[64][4];
  __shared__ unsigned hist[64];

  const int tid = threadIdx.x, lane = tid & 63, wave = tid >> 6;
  const int m = lane & 15, gq = lane >> 4;
  const int wc0 = wave * 48;             // col-split GEMM col base
  const int w16 = wave * 16;             // head base / row-split base
  const int growbase = blockIdx.x * 64;

  if (tid < 64) { hist[tid] = 0u; Abuf[12288 + tid] = 0; }

  int gph = 0;
  { int nseg; const ushort_t* s0 = chunk_ptr(wsu, 0, &nseg); stage_to(&Wbuf[0][0], s0, nseg, wave, lane); }

  const int row0 = growbase + w16 + m;   // this lane's global row (row-split)
  const int rloc = w16 + m;              // local row in Abuf
  f32x4 accF[12];
#pragma unroll
  for (int t = 0; t < 12; ++t) accF[t] = (f32x4){0.f, 0.f, 0.f, 0.f};

  // ===== vib encoder + fus part 0 =====
  {
    f32x4 accE[12];
#pragma unroll
    for (int t = 0; t < 12; ++t) accE[t] = (f32x4){0.f, 0.f, 0.f, 0.f};
    enc_gemm<1>(xv, row0, wsu, Wbuf, &gph, accE, m, gq, wave, lane);
    ln_gelu_enc(accE, ebv, egv, ebbv, Abuf, rloc, gq);
  }
  lds_gemm(Abuf, wsu, Wbuf, &gph, accF, wc0, m, gq, wave, lane);

  // ===== aco encoder + fus part 1 =====
  {
    f32x4 accE[12];
#pragma unroll
    for (int t = 0; t < 12; ++t) accE[t] = (f32x4){0.f, 0.f, 0.f, 0.f};
    enc_gemm<4>(xa, row0, wsu, Wbuf, &gph, accE, m, gq, wave, lane);
    ln_gelu_enc(accE, eba, ega, ebba, Abuf, rloc, gq);
  }
  lds_gemm(Abuf, wsu, Wbuf, &gph, accF, wc0, m, gq, wave, lane);

  // ===== tmp encoder + fus part 2 + fusion LN =====
  {
    f32x4 accE[12];
#pragma unroll
    for (int t = 0; t < 12; ++t) accE[t] = (f32x4){0.f, 0.f, 0.f, 0.f};
    enc_gemm<2>(xt, row0, wsu, Wbuf, &gph, accE, m, gq, wave, lane);
    ln_gelu_enc(accE, ebt, egt, ebbt, Abuf, rloc, gq);
  }
  lds_gemm(Abuf, wsu, Wbuf, &gph, accF, wc0, m, gq, wave, lane);
  ln_gelu_fus(accF, fb, fg, fbb, Abuf, lnscr, wave, wc0, m, gq);

  // ===== folded resonance chain =====
  {
    f32x4 accS[4];
    // --- GEMM1: S1 = fused @ WK1 (3 phases; wave = head, slots w16..w16+15)
#pragma unroll
    for (int t = 0; t < 4; ++t) accS[t] = (f32x4){0.f, 0.f, 0.f, 0.f};
#pragma unroll
    for (int ph = 0; ph < 3; ++ph) {
      phase_begin(wsu, Wbuf, gph, wave, lane);
      const ushort_t* Wc = &Wbuf[gph & 1][0];
      int n = w16 + m;
#pragma unroll
      for (int ks = 0; ks < 2; ++ks) {
        int sl = ks * 4 + gq;
        short8 b = *(const short8*)(Wc + n * 64 + ((sl ^ (n & 7)) << 3));
#pragma unroll
        for (int mt = 0; mt < 4; ++mt) {
          int r = mt * 16 + m;
          short8 a = *(const short8*)(Abuf + r * 192 + ((ph * 8 + (sl ^ (r & 7))) << 3));
          accS[mt] = MFMA16(b, a, accS[mt]);
        }
      }
      ++gph;
    }
    softmax_to_P(accS, battn, &Wbuf[(gph - 1) & 1][8192], w16, m, gq);

    // --- layers 2,3: S = P_prev @ M + b (1 phase each, K=64)
#pragma unroll
    for (int l = 1; l <= 2; ++l) {
      const ushort_t* Pprev = &Wbuf[(gph & 1) ^ 1][8192];
#pragma unroll
      for (int t = 0; t < 4; ++t) accS[t] = (f32x4){0.f, 0.f, 0.f, 0.f};
      phase_begin(wsu, Wbuf, gph, wave, lane);
      const ushort_t* Wc = &Wbuf[gph & 1][0];
      int n = w16 + m;
#pragma unroll
      for (int ks = 0; ks < 2; ++ks) {
        int sl = ks * 4 + gq;
        short8 b = *(const short8*)(Wc + n * 64 + ((sl ^ (n & 7)) << 3));
#pragma unroll
        for (int mt = 0; mt < 4; ++mt) {
          int r = mt * 16 + m;
          short8 a = *(const short8*)(Pprev + r * 64 + ((sl ^ (r & 7)) << 3));
          accS[mt] = MFMA16(b, a, accS[mt]);
        }
      }
      ++gph;
      softmax_to_P(accS, battn + l * 64, &Wbuf[(gph - 1) & 1][8192], w16, m, gq);
    }

    // --- SOFM: scores = P3 @ MG + bG (1 phase, row-split) -> argmax histogram
    {
      const ushort_t* P3 = &Wbuf[(gph & 1) ^ 1][8192];
      f32x4 accG[4];
#pragma unroll
      for (int t = 0; t < 4; ++t) accG[t] = (f32x4){0.f, 0.f, 0.f, 0.f};
      phase_begin(wsu, Wbuf, gph, wave, lane);
      const ushort_t* Wc = &Wbuf[gph & 1][0];
      int r = w16 + m;
#pragma unroll
      for (int ks = 0; ks < 2; ++ks) {
        int sl = ks * 4 + gq;
        short8 a = *(const short8*)(P3 + r * 64 + ((sl ^ (r & 7)) << 3));
#pragma unroll
        for (int nt = 0; nt < 4; ++nt) {
          int n = nt * 16 + m;
          short8 b = *(const short8*)(Wc + n * 64 + ((sl ^ (n & 7)) << 3));
          accG[nt] = MFMA16(b, a, accG[nt]);  // accG[nt][j] = score[row][g=nt*16+gq*4+j]
        }
      }
      ++gph;
      float bv = -3.0e38f; int bi = 64;
#pragma unroll
      for (int nt = 0; nt < 4; ++nt) {
        int gb = nt * 16 + gq * 4;
        float4 g4 = *(const float4*)(bG + gb);
#pragma unroll
        for (int j = 0; j < 4; ++j) {
          float v = accG[nt][j] + ((const float*)&g4)[j];
          int g = gb + j;
          bool take = (v > bv);  // ascending g within lane: strict > keeps lowest
          bv = take ? v : bv; bi = take ? g : bi;
        }
      }
#pragma unroll
      for (int off = 16; off < 64; off <<= 1) {
        float ov = __shfl_xor(bv, off, 64);
        int oi = __shfl_xor(bi, off, 64);
        bool take = (ov > bv) || (ov == bv && oi < bi);
        bv = take ? ov : bv; bi = take ? oi : bi;
      }
      if (gq == 0) atomicAdd(&hist[bi], 1u);  // one count per row (owner m-lane)
    }
  }
  __syncthreads();
  if (tid < 64 && hist[tid]) atomicAdd(&counts[tid], hist[tid]);
}

// ---------------- finisher ----------------
__global__ void arn_finish(const unsigned* __restrict__ counts, const float* __restrict__ gr,
                           const float* __restrict__ ow, const float* __restrict__ ob,
                           float* __restrict__ out) {
  __shared__ float pooled[192];
  __shared__ float cf[64];
  int t = threadIdx.x;
  if (t < 64) cf[t] = (float)counts[t];
  __syncthreads();
  float s = 0.f;
  for (int g = 0; g < 64; ++g) s += cf[g] * gr[g * 192 + t];
  pooled[t] = s * (1.0f / (float)B_TOTAL);
  __syncthreads();
  if (t < 6) {
    float o = ob[t];
    for (int j = 0; j < 192; ++j) o += pooled[j] * ow[j * 6 + t];
    out[t] = (t == 1) ? fmaxf(o, 0.f) : 1.f / (1.f + expf(-o));
  }
}

// ---------------- launch ----------------
extern "C" void kernel_launch(void* const* d_in, const int* in_sizes, int n_in,
                              void* d_out, int out_size, void* d_ws, size_t ws_size,
                              hipStream_t stream) {
  (void)in_sizes; (void)n_in; (void)out_size; (void)ws_size;
  const float* xv   = (const float*)d_in[0];
  const float* xa   = (const float*)d_in[1];
  const float* xt   = (const float*)d_in[2];
  const float* ewv  = (const float*)d_in[3];
  const float* ebv  = (const float*)d_in[4];
  const float* egv  = (const float*)d_in[5];
  const float* ebbv = (const float*)d_in[6];
  const float* ewa  = (const float*)d_in[7];
  const float* eba  = (const float*)d_in[8];
  const float* ega  = (const float*)d_in[9];
  const float* ebba = (const float*)d_in[10];
  const float* ewt  = (const float*)d_in[11];
  const float* ebt  = (const float*)d_in[12];
  const float* egt  = (const float*)d_in[13];
  const float* ebbt = (const float*)d_in[14];
  const float* fw   = (const float*)d_in[15];
  const float* fb   = (const float*)d_in[16];
  const float* fg   = (const float*)d_in[17];
  const float* fbb  = (const float*)d_in[18];
  const float* rwq  = (const float*)d_in[19];
  const float* rwk  = (const float*)d_in[20];
  const float* rwv  = (const float*)d_in[21];
  const float* rwo  = (const float*)d_in[22];
  const float* rbq  = (const float*)d_in[23];
  const float* rbk  = (const float*)d_in[24];
  const float* rbv  = (const float*)d_in[25];
  const float* rbo  = (const float*)d_in[26];
  const float* rmem = (const float*)d_in[27];
  const float* grid = (const float*)d_in[28];
  const float* ow   = (const float*)d_in[29];
  const float* ob   = (const float*)d_in[30];

  ushort_t* wsu = (ushort_t*)d_ws;
  float* wsf = (float*)((char*)d_ws + F32_BYTE_OFF);
  float* battn = wsf + F_BATTN;
  float* bG    = wsf + F_BG;
  unsigned* cnt = (unsigned*)(wsf + F_CNT);

  prep_weights<<<dim3(256), dim3(256), 0, stream>>>(ewv, ewa, ewt, fw, wsu);
  prep_kv1<<<dim3(80), dim3(256), 0, stream>>>(rwk, rwv, rbk, rbv, rmem, wsf, cnt);
  prep_kv2<<<dim3(120), dim3(256), 0, stream>>>(rwq, rbq, rwo, wsf, wsu);
  prep_kv3<<<dim3(64), dim3(256), 0, stream>>>(rbo, grid, wsf, wsu);
  arn_main<<<dim3(2048), dim3(256), 0, stream>>>(xv, xa, xt, wsu, battn, bG, cnt,
      ebv, egv, ebbv, eba, ega, ebba, ebt, egt, ebbt, fb, fg, fbb);
  arn_finish<<<dim3(1), dim3(192), 0, stream>>>(cnt, grid, ow, ob, (float*)d_out);
}

// Round 15
// 204.683 us; speedup vs baseline: 3.0976x; 1.0689x over previous
//
#include <hip/hip_runtime.h>
#include <hip/hip_bf16.h>
#include <math.h>

typedef unsigned short ushort_t;
typedef __attribute__((ext_vector_type(8))) short short8;
typedef __attribute__((ext_vector_type(4))) float f32x4;

#define B_TOTAL 131072

// ws layout (ushort element offsets). W blobs are K64-split chunk-major:
// chunk = [N rows][64 k]; storage (n, s, j) holds logical k = ck*64 + 8*(s ^ (n&7)) + j.
#define OFF_VIB 0        // 1 chunk  [192][64]  = 12288
#define OFF_ACO 12288    // 4 chunks             = 49152
#define OFF_TMP 61440    // 2 chunks             = 24576
#define OFF_FUS 86016    // 9 chunks (3/part)    = 110592
#define OFF_WK 196608    // single [64][192] chunk (3 k-blocks) = 12288
#define OFF_M 208896     // M2|M3|MG blob, 3 x [64][64] = 12288
// f32 region at byte 442368: Kv, Vv, Vpp, WKf, bSf, battn, bG, cnt
#define F32_BYTE_OFF 442368
#define F_KV 0
#define F_VV 9216
#define F_VPP 18432
#define F_WKF 55296
#define F_BSF 92160
#define F_BATTN 92352
#define F_BG 92544
#define F_CNT 92608

// prep kernels: explicit RTNE bit-twiddle (cold code)
__device__ __forceinline__ ushort_t f2bu_prep(float f) {
  union { float f; unsigned u; } c; c.f = f;
  unsigned u = c.u;
  unsigned r = (u + 0x7fffu + ((u >> 16) & 1u)) >> 16;  // RTNE
  return (ushort_t)r;
}
// hot kernel: v_cvt bf16 (RTNE on gfx950)
__device__ __forceinline__ ushort_t f2bu(float f) {
  __hip_bfloat16 h = __float2bfloat16(f);
  return *(ushort_t*)&h;
}
__device__ __forceinline__ float fastrcp(float x) { return __builtin_amdgcn_rcpf(x); }
// sigmoid-form GELU: x * sigma(1.702 x); 5 VALU ops, NaN-free.
__device__ __forceinline__ float gelu_fast(float x) {
  return x * fastrcp(1.0f + exp2f(-2.45546465f * x));
}
#define MFMA16(a, b, c) __builtin_amdgcn_mfma_f32_16x16x32_bf16(a, b, c, 0, 0, 0)

__device__ __forceinline__ void gload16(const void* g, void* l) {
  __builtin_amdgcn_global_load_lds((const __attribute__((address_space(1))) void*)g,
                                   (__attribute__((address_space(3))) void*)l, 16, 0, 0);
}

// ---------------- prep: weights -> K64-split swizzled chunks ----------------
__global__ void prep_weights(const float* __restrict__ ev, const float* __restrict__ ea,
                             const float* __restrict__ et, const float* __restrict__ fw,
                             ushort_t* __restrict__ ws) {
  int tid = blockIdx.x * blockDim.x + threadIdx.x;
  int nth = gridDim.x * blockDim.x;
  for (int i = tid; i < 12288; i += nth) {
    int n = i >> 6, kin = i & 63;
    int k = 8 * ((kin >> 3) ^ (n & 7)) + (kin & 7);
    ws[OFF_VIB + i] = f2bu_prep(ev[k * 192 + n]);
  }
  for (int i = tid; i < 49152; i += nth) {
    int ck = i / 12288, rem = i % 12288, n = rem >> 6, kin = rem & 63;
    int k = ck * 64 + 8 * ((kin >> 3) ^ (n & 7)) + (kin & 7);
    ws[OFF_ACO + i] = f2bu_prep(ea[k * 192 + n]);
  }
  for (int i = tid; i < 24576; i += nth) {
    int ck = i / 12288, rem = i % 12288, n = rem >> 6, kin = rem & 63;
    int k = ck * 64 + 8 * ((kin >> 3) ^ (n & 7)) + (kin & 7);
    ws[OFF_TMP + i] = f2bu_prep(et[k * 192 + n]);
  }
  for (int i = tid; i < 110592; i += nth) {
    int ck = i / 12288, rem = i % 12288, n = rem >> 6, kin = rem & 63;
    int k = ck * 64 + 8 * ((kin >> 3) ^ (n & 7)) + (kin & 7);
    ws[OFF_FUS + i] = f2bu_prep(fw[k * 192 + n]);
  }
}

// ------- prep 1: K/V vectors (fp32): Kv[i][s][192], Vv[i][s][192] ---------
__global__ void prep_kv1(const float* __restrict__ rwk, const float* __restrict__ rwv,
                         const float* __restrict__ rbk, const float* __restrict__ rbv,
                         const float* __restrict__ rmem, float* __restrict__ wsf,
                         unsigned* __restrict__ cnt) {
  int tid = blockIdx.x * blockDim.x + threadIdx.x;
  int nth = gridDim.x * blockDim.x;
  for (int idx = tid; idx < 18432; idx += nth) {
    int bank = idx / 9216, r = idx % 9216;
    int i = r / 3072, q = r % 3072, s = q / 192, d = q % 192;
    const float* w  = (bank ? rwv : rwk) + i * 36864;
    const float* bs = (bank ? rbv : rbk) + i * 192;
    const float* mm = rmem + i * 3072 + s * 192;
    float acc = bs[d];
    for (int kk = 0; kk < 192; ++kk) acc += mm[kk] * w[kk * 192 + d];
    wsf[bank * 9216 + (i * 16 + s) * 192 + d] = acc;
  }
  for (int g = tid; g < 64; g += nth) cnt[g] = 0u;
}

// ------- prep 2: fp32 WKf, Vpp, bSf; WK1 bf16 single [64][192] chunk -------
__global__ void prep_kv2(const float* __restrict__ rwq, const float* __restrict__ rbq,
                         const float* __restrict__ rwo, float* __restrict__ wsf,
                         ushort_t* __restrict__ ws) {
  int tid = blockIdx.x * blockDim.x + threadIdx.x;
  int nth = gridDim.x * blockDim.x;
  const float scale = 0.144337567297406441f;  // 1/sqrt(48)
  const float* Kv = wsf + F_KV;
  const float* Vv = wsf + F_VV;
  float* WKf = wsf + F_WKF;
  float* Vpp = wsf + F_VPP;
  float* bSf = wsf + F_BSF;
  // WKf fp32 (layers 1,2 for folding)
  for (int idx = tid; idx < 36864; idx += nth) {
    int i = idx / 12288, rem = idx % 12288, n = rem / 192, k = rem % 192;
    int h = n >> 4, s = n & 15;
    const float* kvp = Kv + (i * 16 + s) * 192 + h * 48;
    const float* wqp = rwq + i * 36864 + k * 192 + h * 48;
    float acc = 0.f;
    for (int d = 0; d < 48; ++d) acc += wqp[d] * kvp[d];
    WKf[idx] = scale * acc;
  }
  // WK1 bf16 single chunk [64 n][192 k] (per-64k-block 8-granule swizzle)
  for (int idx = tid; idx < 12288; idx += nth) {
    int n = idx / 192, rem = idx % 192, kb = rem >> 6, kin = rem & 63;
    int k = kb * 64 + 8 * ((kin >> 3) ^ (n & 7)) + (kin & 7);
    int h = n >> 4, s = n & 15;
    const float* kvp = Kv + s * 192 + h * 48;
    const float* wqp = rwq + k * 192 + h * 48;
    float acc = 0.f;
    for (int d = 0; d < 48; ++d) acc += wqp[d] * kvp[d];
    ws[OFF_WK + idx] = f2bu_prep(scale * acc);
  }
  // Vpp[i][s1][dcol] = V_i[s1] @ wo_i
  for (int idx = tid; idx < 36864; idx += nth) {
    int i = idx / 12288, rem = idx % 12288, n = rem / 192, dcol = rem % 192;
    int h = n >> 4, s = n & 15;
    const float* vvp = Vv + (i * 16 + s) * 192 + h * 48;
    const float* wop = rwo + i * 36864 + (h * 48) * 192 + dcol;
    float acc = 0.f;
    for (int d = 0; d < 48; ++d) acc += vvp[d] * wop[d * 192];
    Vpp[idx] = acc;
  }
  // bSf[i][n] = scale * bq_h . K_h[s]
  for (int idx = tid; idx < 192; idx += nth) {
    int i = idx >> 6, n = idx & 63, h = n >> 4, s = n & 15;
    const float* kvp = Kv + (i * 16 + s) * 192 + h * 48;
    const float* bqp = rbq + i * 192 + h * 48;
    float acc = 0.f;
    for (int d = 0; d < 48; ++d) acc += bqp[d] * kvp[d];
    bSf[idx] = scale * acc;
  }
}

// ------- prep 3: slot-space folds M2, M3, MG (bf16 blob) + battn + bG -----
__global__ void prep_kv3(const float* __restrict__ rbo, const float* __restrict__ gr,
                         float* __restrict__ wsf, ushort_t* __restrict__ ws) {
  int tid = blockIdx.x * blockDim.x + threadIdx.x;
  int nth = gridDim.x * blockDim.x;
  const float* Vpp = wsf + F_VPP;
  const float* WKf = wsf + F_WKF;
  const float* bSf = wsf + F_BSF;
  // M_{l+1}[s1][s2] = Vpp[l][s1] . WKf[l+1][s2]; chunk [n=s2][k=s1] swizzled
  for (int idx = tid; idx < 8192; idx += nth) {
    int l = idx >> 12, rem = idx & 4095, n = rem >> 6, kin = rem & 63;
    int k = 8 * ((kin >> 3) ^ (n & 7)) + (kin & 7);
    const float* vp = Vpp + l * 12288 + k * 192;
    const float* wp = WKf + (l + 1) * 12288 + n * 192;
    float acc = 0.f;
    for (int t = 0; t < 192; ++t) acc += vp[t] * wp[t];
    ws[OFF_M + l * 4096 + n * 64 + kin] = f2bu_prep(acc);
  }
  // MG[s1][g] = Vpp[2][s1] . grid[g]; chunk [n=g][k=s1]
  for (int idx = tid; idx < 4096; idx += nth) {
    int n = idx >> 6, kin = idx & 63;
    int k = 8 * ((kin >> 3) ^ (n & 7)) + (kin & 7);
    const float* vp = Vpp + 2 * 12288 + k * 192;
    const float* gp = gr + n * 192;
    float acc = 0.f;
    for (int t = 0; t < 192; ++t) acc += vp[t] * gp[t];
    ws[OFF_M + 8192 + n * 64 + kin] = f2bu_prep(acc);
  }
  // battn[0]=bSf0; battn[l]=bSf[l]+bo_{l-1}@WKf[l]
  for (int idx = tid; idx < 192; idx += nth) {
    int l = idx >> 6, n = idx & 63;
    float acc = bSf[l * 64 + n];
    if (l > 0) {
      const float* wp = WKf + l * 12288 + n * 192;
      const float* bo = rbo + (l - 1) * 192;
      for (int t = 0; t < 192; ++t) acc += bo[t] * wp[t];
    }
    wsf[F_BATTN + idx] = acc;
  }
  // bG[g] = bo2 . grid[g] - 0.5*||grid[g]||^2
  for (int g = tid; g < 64; g += nth) {
    const float* gp = gr + g * 192;
    const float* bo = rbo + 2 * 192;
    float a = 0.f, s = 0.f;
    for (int t = 0; t < 192; ++t) { a += bo[t] * gp[t]; s += gp[t] * gp[t]; }
    wsf[F_BG + g] = a - 0.5f * s;
  }
}

// ---------------- main-kernel helpers (4-wave block, 24-seg chunks) -------
__device__ __forceinline__ void stage_to(ushort_t* dst, const ushort_t* src, int wave, int lane) {
#pragma unroll
  for (int j = 0; j < 6; ++j) {
    int s = wave + j * 4;
    gload16(src + (s << 9) + lane * 8, dst + (s << 9));
  }
}

// consumption-order phase table (18 phases); all chunks are 24 segs
__device__ __forceinline__ const ushort_t* chunk_ptr(const ushort_t* wsu, int g, int* nseg) {
  *nseg = 24;
  if (g < 1)            return wsu + OFF_VIB;
  g -= 1;  if (g < 3)   return wsu + OFF_FUS + g * 12288;
  g -= 3;  if (g < 4)   return wsu + OFF_ACO + g * 12288;
  g -= 4;  if (g < 3)   return wsu + OFF_FUS + 36864 + g * 12288;
  g -= 3;  if (g < 2)   return wsu + OFF_TMP + g * 12288;
  g -= 2;  if (g < 3)   return wsu + OFF_FUS + 73728 + g * 12288;
  g -= 3;  if (g < 1)   return wsu + OFF_WK;    // phase 16
  g -= 1;  if (g < 1)   return wsu + OFF_M;     // phase 17 (blob; staged during 16)
  *nseg = 0; return wsu;
}

__device__ __forceinline__ void phase_begin(const ushort_t* wsu, ushort_t (*Wb)[12288],
                                            int gph, int wave, int lane) {
  __syncthreads();
  int nseg; const ushort_t* ns = chunk_ptr(wsu, gph + 1, &nseg);
  if (nseg) stage_to(&Wb[(gph + 1) & 1][0], ns, wave, lane);
}

__device__ __forceinline__ short8 cvt8(float4 a, float4 b) {
  short8 v;
  v[0] = (short)f2bu(a.x); v[1] = (short)f2bu(a.y); v[2] = (short)f2bu(a.z); v[3] = (short)f2bu(a.w);
  v[4] = (short)f2bu(b.x); v[5] = (short)f2bu(b.y); v[6] = (short)f2bu(b.z); v[7] = (short)f2bu(b.w);
  return v;
}

// encoder GEMM, ROW-SPLIT: wave owns 16 rows x all 192 out-cols.
template<int NPH>
__device__ __forceinline__ void enc_gemm(const float* __restrict__ x, int row0,
    const ushort_t* wsu, ushort_t (*Wb)[12288], int* gph, f32x4* accE,
    int m, int gq, int wave, int lane) {
  const int KF = NPH * 64;
  const float* p0 = x + (size_t)row0 * KF + gq * 8;
  float4 ca0 = *(const float4*)(p0);
  float4 ca1 = *(const float4*)(p0 + 4);
#pragma unroll
  for (int ph = 0; ph < NPH; ++ph) {
    phase_begin(wsu, Wb, *gph, wave, lane);
    const ushort_t* Wc = &Wb[*gph & 1][0];
#pragma unroll
    for (int ks = 0; ks < 2; ++ks) {
      int sl = ks * 4 + gq;
      short8 a = cvt8(ca0, ca1);
      int nk = ph * 64 + ks * 32 + 32;
      if (nk < KF) {
        ca0 = *(const float4*)(p0 + nk);
        ca1 = *(const float4*)(p0 + nk + 4);
      }
#pragma unroll
      for (int t = 0; t < 12; ++t) {
        int n = t * 16 + m;
        short8 b = *(const short8*)(Wc + n * 64 + ((sl ^ (n & 7)) << 3));
        accE[t] = MFMA16(b, a, accE[t]);
      }
    }
    ++*gph;
  }
}

// GEMM from activation panel, COL-SPLIT: wave owns all 64 rows x 48 cols.
__device__ __forceinline__ void lds_gemm(const ushort_t* Ab, const ushort_t* wsu,
    ushort_t (*Wb)[12288], int* gph, f32x4* acc, int wc0, int m, int gq,
    int wave, int lane) {
#pragma unroll
  for (int ph = 0; ph < 3; ++ph) {
    phase_begin(wsu, Wb, *gph, wave, lane);
    const ushort_t* Wc = &Wb[*gph & 1][0];
#pragma unroll
    for (int ks = 0; ks < 2; ++ks) {
      int sl = ks * 4 + gq;
      short8 b0, b1, b2;
      {
        int n0 = wc0 + m, n1 = wc0 + 16 + m, n2 = wc0 + 32 + m;
        b0 = *(const short8*)(Wc + n0 * 64 + ((sl ^ (n0 & 7)) << 3));
        b1 = *(const short8*)(Wc + n1 * 64 + ((sl ^ (n1 & 7)) << 3));
        b2 = *(const short8*)(Wc + n2 * 64 + ((sl ^ (n2 & 7)) << 3));
      }
#pragma unroll
      for (int mt = 0; mt < 4; ++mt) {
        int r = mt * 16 + m;
        short8 a = *(const short8*)(Ab + r * 192 + ((ph * 8 + (sl ^ (r & 7))) << 3));
        acc[mt * 3 + 0] = MFMA16(b0, a, acc[mt * 3 + 0]);
        acc[mt * 3 + 1] = MFMA16(b1, a, acc[mt * 3 + 1]);
        acc[mt * 3 + 2] = MFMA16(b2, a, acc[mt * 3 + 2]);
      }
    }
    ++*gph;
  }
}

// encoder LN+GELU: fully wave-local (row-split).
__device__ __forceinline__ void ln_gelu_enc(f32x4* acc, const float* __restrict__ bias,
    const float* __restrict__ gam, const float* __restrict__ bet,
    ushort_t* __restrict__ Ab, int rloc, int gq) {
  float s = 0.f, q = 0.f;
#pragma unroll
  for (int t = 0; t < 12; ++t) {
    float4 bv = *(const float4*)(bias + t * 16 + gq * 4);
#pragma unroll
    for (int j = 0; j < 4; ++j) {
      float v = acc[t][j] + ((const float*)&bv)[j];
      acc[t][j] = v; s += v; q += v * v;
    }
  }
  s += __shfl_xor(s, 16, 64); q += __shfl_xor(q, 16, 64);
  s += __shfl_xor(s, 32, 64); q += __shfl_xor(q, 32, 64);
  float mean = s * (1.0f / 192.0f);
  float var = q * (1.0f / 192.0f) - mean * mean;
  float rstd = rsqrtf(var + 1e-5f);
#pragma unroll
  for (int t = 0; t < 12; ++t) {
    int colb = t * 16 + gq * 4;
    float4 ga = *(const float4*)(gam + colb);
    float4 be = *(const float4*)(bet + colb);
    ushort_t o[4];
#pragma unroll
    for (int j = 0; j < 4; ++j) {
      float y = (acc[t][j] - mean) * rstd * ((const float*)&ga)[j] + ((const float*)&be)[j];
      o[j] = f2bu(gelu_fast(y));
    }
    int off = rloc * 192 + (((colb >> 3) ^ (rloc & 7)) << 3) + (colb & 7);
    *(uint2*)(Ab + off) = *(uint2*)o;
  }
}

// fusion LN+GELU: col-split (4-way) with cross-wave stats scratch
__device__ __forceinline__ void ln_gelu_fus(f32x4* acc, const float* __restrict__ bias,
    const float* __restrict__ gam, const float* __restrict__ bet,
    ushort_t* __restrict__ Ab, float2 (*scr)[4], int wave, int wc0, int m, int gq) {
  float4 bv[3];
#pragma unroll
  for (int t = 0; t < 3; ++t) bv[t] = *(const float4*)(bias + wc0 + t * 16 + gq * 4);
#pragma unroll
  for (int mt = 0; mt < 4; ++mt) {
    float s = 0.f, q = 0.f;
#pragma unroll
    for (int t = 0; t < 3; ++t)
#pragma unroll
      for (int j = 0; j < 4; ++j) {
        float v = acc[mt * 3 + t][j] + ((const float*)&bv[t])[j];
        acc[mt * 3 + t][j] = v; s += v; q += v * v;
      }
    s += __shfl_xor(s, 16, 64); q += __shfl_xor(q, 16, 64);
    s += __shfl_xor(s, 32, 64); q += __shfl_xor(q, 32, 64);
    if (gq == 0) scr[mt * 16 + m][wave] = (float2){s, q};
  }
  __syncthreads();
#pragma unroll
  for (int mt = 0; mt < 4; ++mt) {
    int row = mt * 16 + m;
    float s = 0.f, q = 0.f;
#pragma unroll
    for (int w = 0; w < 4; ++w) { float2 p = scr[row][w]; s += p.x; q += p.y; }
    float mean = s * (1.0f / 192.0f);
    float var = q * (1.0f / 192.0f) - mean * mean;
    float rstd = rsqrtf(var + 1e-5f);
#pragma unroll
    for (int t = 0; t < 3; ++t) {
      int colb = wc0 + t * 16 + gq * 4;
      float4 ga = *(const float4*)(gam + colb);
      float4 be = *(const float4*)(bet + colb);
      ushort_t o[4];
#pragma unroll
      for (int j = 0; j < 4; ++j) {
        float y = (acc[mt * 3 + t][j] - mean) * rstd * ((const float*)&ga)[j] + ((const float*)&be)[j];
        o[j] = f2bu(gelu_fast(y));
      }
      int off = row * 192 + (((colb >> 3) ^ (row & 7)) << 3) + (colb & 7);
      *(uint2*)(Ab + off) = *(uint2*)o;
    }
  }
}

// softmax over this wave's 16 slots (head = wave) -> write P panel (swizzled)
__device__ __forceinline__ void softmax_to_P(f32x4* accS, const float* __restrict__ bptr,
    ushort_t* __restrict__ Pb, int w16, int m, int gq) {
  float4 b4 = *(const float4*)(bptr + w16 + gq * 4);
  const int gnum = (w16 + gq * 4) >> 3;
#pragma unroll
  for (int mt = 0; mt < 4; ++mt) {
    float e[4]; float mx = -3.0e38f;
#pragma unroll
    for (int j = 0; j < 4; ++j) { e[j] = accS[mt][j] + ((const float*)&b4)[j]; mx = fmaxf(mx, e[j]); }
    mx = fmaxf(mx, __shfl_xor(mx, 16, 64));
    mx = fmaxf(mx, __shfl_xor(mx, 32, 64));
    float sm = 0.f;
#pragma unroll
    for (int j = 0; j < 4; ++j) { e[j] = exp2f((e[j] - mx) * 1.44269504f); sm += e[j]; }
    sm += __shfl_xor(sm, 16, 64);
    sm += __shfl_xor(sm, 32, 64);
    float inv = fastrcp(sm);
    ushort_t p4[4];
#pragma unroll
    for (int j = 0; j < 4; ++j) p4[j] = f2bu(e[j] * inv);
    int r = mt * 16 + m;
    *(uint2*)(Pb + r * 64 + ((gnum ^ (r & 7)) << 3) + (gq & 1) * 4) = *(uint2*)p4;
  }
}

// ---------------- main fused kernel ----------------
// R15: GEMM1 merged to ONE [64][192] chunk phase; M2|M3|MG blob staged during
// it; layers 2/3 + SOFM are barrier-only (P panels ping through buf0 @0/4096/
// 8192, overwriting the dead WK1). 18 heavy phases + 4 light barriers.
// GELU = sigmoid form (5 ops).
__global__ __launch_bounds__(256) __attribute__((amdgpu_waves_per_eu(2))) void arn_main(
    const float* __restrict__ xv, const float* __restrict__ xa, const float* __restrict__ xt,
    const ushort_t* __restrict__ wsu, const float* __restrict__ battn,
    const float* __restrict__ bG, unsigned* __restrict__ counts,
    const float* __restrict__ ebv, const float* __restrict__ egv, const float* __restrict__ ebbv,
    const float* __restrict__ eba, const float* __restrict__ ega, const float* __restrict__ ebba,
    const float* __restrict__ ebt, const float* __restrict__ egt, const float* __restrict__ ebbt,
    const float* __restrict__ fb, const float* __restrict__ fg, const float* __restrict__ fbb) {
  __shared__ __align__(16) ushort_t Abuf[64 * 192 + 64];  // swizzled activations + zero pad
  __shared__ __align__(16) ushort_t Wbuf[2][12288];       // double-buffered chunks
  __shared__ float2 lnscr[64][4];
  __shared__ unsigned hist[64];

  const int tid = threadIdx.x, lane = tid & 63, wave = tid >> 6;
  const int m = lane & 15, gq = lane >> 4;
  const int wc0 = wave * 48;             // col-split GEMM col base
  const int w16 = wave * 16;             // head base / row-split base
  const int growbase = blockIdx.x * 64;

  if (tid < 64) { hist[tid] = 0u; Abuf[12288 + tid] = 0; }

  int gph = 0;
  { int nseg; const ushort_t* s0 = chunk_ptr(wsu, 0, &nseg); stage_to(&Wbuf[0][0], s0, wave, lane); }

  const int row0 = growbase + w16 + m;   // this lane's global row (row-split)
  const int rloc = w16 + m;              // local row in Abuf
  f32x4 accF[12];
#pragma unroll
  for (int t = 0; t < 12; ++t) accF[t] = (f32x4){0.f, 0.f, 0.f, 0.f};

  // ===== vib encoder + fus part 0 =====
  {
    f32x4 accE[12];
#pragma unroll
    for (int t = 0; t < 12; ++t) accE[t] = (f32x4){0.f, 0.f, 0.f, 0.f};
    enc_gemm<1>(xv, row0, wsu, Wbuf, &gph, accE, m, gq, wave, lane);
    ln_gelu_enc(accE, ebv, egv, ebbv, Abuf, rloc, gq);
  }
  lds_gemm(Abuf, wsu, Wbuf, &gph, accF, wc0, m, gq, wave, lane);

  // ===== aco encoder + fus part 1 =====
  {
    f32x4 accE[12];
#pragma unroll
    for (int t = 0; t < 12; ++t) accE[t] = (f32x4){0.f, 0.f, 0.f, 0.f};
    enc_gemm<4>(xa, row0, wsu, Wbuf, &gph, accE, m, gq, wave, lane);
    ln_gelu_enc(accE, eba, ega, ebba, Abuf, rloc, gq);
  }
  lds_gemm(Abuf, wsu, Wbuf, &gph, accF, wc0, m, gq, wave, lane);

  // ===== tmp encoder + fus part 2 + fusion LN =====
  {
    f32x4 accE[12];
#pragma unroll
    for (int t = 0; t < 12; ++t) accE[t] = (f32x4){0.f, 0.f, 0.f, 0.f};
    enc_gemm<2>(xt, row0, wsu, Wbuf, &gph, accE, m, gq, wave, lane);
    ln_gelu_enc(accE, ebt, egt, ebbt, Abuf, rloc, gq);
  }
  lds_gemm(Abuf, wsu, Wbuf, &gph, accF, wc0, m, gq, wave, lane);
  ln_gelu_fus(accF, fb, fg, fbb, Abuf, lnscr, wave, wc0, m, gq);

  // ===== folded resonance chain (1 heavy phase + 4 light barriers) =====
  {
    f32x4 accS[4];
#pragma unroll
    for (int t = 0; t < 4; ++t) accS[t] = (f32x4){0.f, 0.f, 0.f, 0.f};
    // --- GEMM1: S1 = fused @ WK1 (phase 16; prefetches M-blob into buf1)
    phase_begin(wsu, Wbuf, gph, wave, lane);   // gph == 16, WK1 in buf0
    {
      const ushort_t* Wc = &Wbuf[0][0];
      int n = w16 + m;
#pragma unroll
      for (int ks = 0; ks < 6; ++ks) {
        int kb = ks >> 1, sl = (ks & 1) * 4 + gq;
        short8 b = *(const short8*)(Wc + n * 192 + ((kb * 8 + (sl ^ (n & 7))) << 3));
#pragma unroll
        for (int mt = 0; mt < 4; ++mt) {
          int r = mt * 16 + m;
          short8 a = *(const short8*)(Abuf + r * 192 + ((kb * 8 + (sl ^ (r & 7))) << 3));
          accS[mt] = MFMA16(b, a, accS[mt]);
        }
      }
      ++gph;
    }
    __syncthreads();  // all WK1 reads done; M-blob loads drained (vmcnt on barrier)
    softmax_to_P(accS, battn, &Wbuf[0][0], w16, m, gq);  // P1 -> buf0 @0
    __syncthreads();

    // --- layers 2,3: S = P_prev @ M + b (barrier-only; M from buf1 blob)
#pragma unroll
    for (int l = 1; l <= 2; ++l) {
      const ushort_t* Mc = &Wbuf[1][(l - 1) * 4096];
      const ushort_t* Pp = &Wbuf[0][(l - 1) * 4096];
#pragma unroll
      for (int t = 0; t < 4; ++t) accS[t] = (f32x4){0.f, 0.f, 0.f, 0.f};
      int n = w16 + m;
#pragma unroll
      for (int ks = 0; ks < 2; ++ks) {
        int sl = ks * 4 + gq;
        short8 b = *(const short8*)(Mc + n * 64 + ((sl ^ (n & 7)) << 3));
#pragma unroll
        for (int mt = 0; mt < 4; ++mt) {
          int r = mt * 16 + m;
          short8 a = *(const short8*)(Pp + r * 64 + ((sl ^ (r & 7)) << 3));
          accS[mt] = MFMA16(b, a, accS[mt]);
        }
      }
      softmax_to_P(accS, battn + l * 64, &Wbuf[0][l * 4096], w16, m, gq);  // disjoint region
      __syncthreads();
    }

    // --- SOFM: scores = P3 @ MG + bG (row-split) -> argmax histogram
    {
      const ushort_t* Mc = &Wbuf[1][8192];
      const ushort_t* P3 = &Wbuf[0][8192];
      f32x4 accG[4];
#pragma unroll
      for (int t = 0; t < 4; ++t) accG[t] = (f32x4){0.f, 0.f, 0.f, 0.f};
      int r = w16 + m;
#pragma unroll
      for (int ks = 0; ks < 2; ++ks) {
        int sl = ks * 4 + gq;
        short8 a = *(const short8*)(P3 + r * 64 + ((sl ^ (r & 7)) << 3));
#pragma unroll
        for (int nt = 0; nt < 4; ++nt) {
          int n = nt * 16 + m;
          short8 b = *(const short8*)(Mc + n * 64 + ((sl ^ (n & 7)) << 3));
          accG[nt] = MFMA16(b, a, accG[nt]);  // accG[nt][j] = score[row][g=nt*16+gq*4+j]
        }
      }
      float bv = -3.0e38f; int bi = 64;
#pragma unroll
      for (int nt = 0; nt < 4; ++nt) {
        int gb = nt * 16 + gq * 4;
        float4 g4 = *(const float4*)(bG + gb);
#pragma unroll
        for (int j = 0; j < 4; ++j) {
          float v = accG[nt][j] + ((const float*)&g4)[j];
          int g = gb + j;
          bool take = (v > bv);  // ascending g within lane: strict > keeps lowest
          bv = take ? v : bv; bi = take ? g : bi;
        }
      }
#pragma unroll
      for (int off = 16; off < 64; off <<= 1) {
        float ov = __shfl_xor(bv, off, 64);
        int oi = __shfl_xor(bi, off, 64);
        bool take = (ov > bv) || (ov == bv && oi < bi);
        bv = take ? ov : bv; bi = take ? oi : bi;
      }
      if (gq == 0) atomicAdd(&hist[bi], 1u);  // one count per row (owner m-lane)
    }
  }
  __syncthreads();
  if (tid < 64 && hist[tid]) atomicAdd(&counts[tid], hist[tid]);
}

// ---------------- finisher ----------------
__global__ void arn_finish(const unsigned* __restrict__ counts, const float* __restrict__ gr,
                           const float* __restrict__ ow, const float* __restrict__ ob,
                           float* __restrict__ out) {
  __shared__ float pooled[192];
  __shared__ float cf[64];
  int t = threadIdx.x;
  if (t < 64) cf[t] = (float)counts[t];
  __syncthreads();
  float s = 0.f;
  for (int g = 0; g < 64; ++g) s += cf[g] * gr[g * 192 + t];
  pooled[t] = s * (1.0f / (float)B_TOTAL);
  __syncthreads();
  if (t < 6) {
    float o = ob[t];
    for (int j = 0; j < 192; ++j) o += pooled[j] * ow[j * 6 + t];
    out[t] = (t == 1) ? fmaxf(o, 0.f) : 1.f / (1.f + expf(-o));
  }
}

// ---------------- launch ----------------
extern "C" void kernel_launch(void* const* d_in, const int* in_sizes, int n_in,
                              void* d_out, int out_size, void* d_ws, size_t ws_size,
                              hipStream_t stream) {
  (void)in_sizes; (void)n_in; (void)out_size; (void)ws_size;
  const float* xv   = (const float*)d_in[0];
  const float* xa   = (const float*)d_in[1];
  const float* xt   = (const float*)d_in[2];
  const float* ewv  = (const float*)d_in[3];
  const float* ebv  = (const float*)d_in[4];
  const float* egv  = (const float*)d_in[5];
  const float* ebbv = (const float*)d_in[6];
  const float* ewa  = (const float*)d_in[7];
  const float* eba  = (const float*)d_in[8];
  const float* ega  = (const float*)d_in[9];
  const float* ebba = (const float*)d_in[10];
  const float* ewt  = (const float*)d_in[11];
  const float* ebt  = (const float*)d_in[12];
  const float* egt  = (const float*)d_in[13];
  const float* ebbt = (const float*)d_in[14];
  const float* fw   = (const float*)d_in[15];
  const float* fb   = (const float*)d_in[16];
  const float* fg   = (const float*)d_in[17];
  const float* fbb  = (const float*)d_in[18];
  const float* rwq  = (const float*)d_in[19];
  const float* rwk  = (const float*)d_in[20];
  const float* rwv  = (const float*)d_in[21];
  const float* rwo  = (const float*)d_in[22];
  const float* rbq  = (const float*)d_in[23];
  const float* rbk  = (const float*)d_in[24];
  const float* rbv  = (const float*)d_in[25];
  const float* rbo  = (const float*)d_in[26];
  const float* rmem = (const float*)d_in[27];
  const float* grid = (const float*)d_in[28];
  const float* ow   = (const float*)d_in[29];
  const float* ob   = (const float*)d_in[30];

  ushort_t* wsu = (ushort_t*)d_ws;
  float* wsf = (float*)((char*)d_ws + F32_BYTE_OFF);
  float* battn = wsf + F_BATTN;
  float* bG    = wsf + F_BG;
  unsigned* cnt = (unsigned*)(wsf + F_CNT);

  prep_weights<<<dim3(256), dim3(256), 0, stream>>>(ewv, ewa, ewt, fw, wsu);
  prep_kv1<<<dim3(80), dim3(256), 0, stream>>>(rwk, rwv, rbk, rbv, rmem, wsf, cnt);
  prep_kv2<<<dim3(120), dim3(256), 0, stream>>>(rwq, rbq, rwo, wsf, wsu);
  prep_kv3<<<dim3(64), dim3(256), 0, stream>>>(rbo, grid, wsf, wsu);
  arn_main<<<dim3(2048), dim3(256), 0, stream>>>(xv, xa, xt, wsu, battn, bG, cnt,
      ebv, egv, ebbv, eba, ega, ebba, ebt, egt, ebbt, fb, fg, fbb);
  arn_finish<<<dim3(1), dim3(192), 0, stream>>>(cnt, grid, ow, ob, (float*)d_out);
}

// Round 16
// 197.693 us; speedup vs baseline: 3.2071x; 1.0354x over previous
//
#include <hip/hip_runtime.h>
#include <hip/hip_bf16.h>
#include <math.h>

typedef unsigned short ushort_t;
typedef __attribute__((ext_vector_type(8))) short short8;
typedef __attribute__((ext_vector_type(4))) float f32x4;

#define B_TOTAL 131072

// ws layout (ushort element offsets). W blobs are K64-split chunk-major:
// chunk = [N rows][64 k]; storage (n, s, j) holds logical k = ck*64 + 8*(s ^ (n&7)) + j.
#define OFF_VIB 0        // 1 chunk  [192][64]  = 12288
#define OFF_ACO 12288    // 4 chunks             = 49152
#define OFF_TMP 61440    // 2 chunks             = 24576
#define OFF_FUS 86016    // 9 chunks (3/part)    = 110592
#define OFF_WK 196608    // single [64][192] chunk (3 k-blocks) = 12288
#define OFF_M 208896     // M2|M3|MG blob, 3 x [64][64] = 12288
// f32 region at byte 442368: Kv, Vv, Vpp, WKf, bSf, battn, bG, cnt
#define F32_BYTE_OFF 442368
#define F_KV 0
#define F_VV 9216
#define F_VPP 18432
#define F_WKF 55296
#define F_BSF 92160
#define F_BATTN 92352
#define F_BG 92544
#define F_CNT 92608

// prep kernels: explicit RTNE bit-twiddle (cold code)
__device__ __forceinline__ ushort_t f2bu_prep(float f) {
  union { float f; unsigned u; } c; c.f = f;
  unsigned u = c.u;
  unsigned r = (u + 0x7fffu + ((u >> 16) & 1u)) >> 16;  // RTNE
  return (ushort_t)r;
}
// hot kernel: v_cvt bf16 (RTNE on gfx950)
__device__ __forceinline__ ushort_t f2bu(float f) {
  __hip_bfloat16 h = __float2bfloat16(f);
  return *(ushort_t*)&h;
}
__device__ __forceinline__ float fastrcp(float x) { return __builtin_amdgcn_rcpf(x); }
// sigmoid-form GELU: x * sigma(1.702 x); 5 VALU ops, NaN-free.
__device__ __forceinline__ float gelu_fast(float x) {
  return x * fastrcp(1.0f + exp2f(-2.45546465f * x));
}
#define MFMA16(a, b, c) __builtin_amdgcn_mfma_f32_16x16x32_bf16(a, b, c, 0, 0, 0)

__device__ __forceinline__ void gload16(const void* g, void* l) {
  __builtin_amdgcn_global_load_lds((const __attribute__((address_space(1))) void*)g,
                                   (__attribute__((address_space(3))) void*)l, 16, 0, 0);
}

// ---------------- prep: weights -> K64-split swizzled chunks ----------------
__global__ void prep_weights(const float* __restrict__ ev, const float* __restrict__ ea,
                             const float* __restrict__ et, const float* __restrict__ fw,
                             ushort_t* __restrict__ ws) {
  int tid = blockIdx.x * blockDim.x + threadIdx.x;
  int nth = gridDim.x * blockDim.x;
  for (int i = tid; i < 12288; i += nth) {
    int n = i >> 6, kin = i & 63;
    int k = 8 * ((kin >> 3) ^ (n & 7)) + (kin & 7);
    ws[OFF_VIB + i] = f2bu_prep(ev[k * 192 + n]);
  }
  for (int i = tid; i < 49152; i += nth) {
    int ck = i / 12288, rem = i % 12288, n = rem >> 6, kin = rem & 63;
    int k = ck * 64 + 8 * ((kin >> 3) ^ (n & 7)) + (kin & 7);
    ws[OFF_ACO + i] = f2bu_prep(ea[k * 192 + n]);
  }
  for (int i = tid; i < 24576; i += nth) {
    int ck = i / 12288, rem = i % 12288, n = rem >> 6, kin = rem & 63;
    int k = ck * 64 + 8 * ((kin >> 3) ^ (n & 7)) + (kin & 7);
    ws[OFF_TMP + i] = f2bu_prep(et[k * 192 + n]);
  }
  for (int i = tid; i < 110592; i += nth) {
    int ck = i / 12288, rem = i % 12288, n = rem >> 6, kin = rem & 63;
    int k = ck * 64 + 8 * ((kin >> 3) ^ (n & 7)) + (kin & 7);
    ws[OFF_FUS + i] = f2bu_prep(fw[k * 192 + n]);
  }
}

// ------- prep 1: K/V vectors (fp32): Kv[i][s][192], Vv[i][s][192] ---------
__global__ void prep_kv1(const float* __restrict__ rwk, const float* __restrict__ rwv,
                         const float* __restrict__ rbk, const float* __restrict__ rbv,
                         const float* __restrict__ rmem, float* __restrict__ wsf,
                         unsigned* __restrict__ cnt) {
  int tid = blockIdx.x * blockDim.x + threadIdx.x;
  int nth = gridDim.x * blockDim.x;
  for (int idx = tid; idx < 18432; idx += nth) {
    int bank = idx / 9216, r = idx % 9216;
    int i = r / 3072, q = r % 3072, s = q / 192, d = q % 192;
    const float* w  = (bank ? rwv : rwk) + i * 36864;
    const float* bs = (bank ? rbv : rbk) + i * 192;
    const float* mm = rmem + i * 3072 + s * 192;
    float acc = bs[d];
    for (int kk = 0; kk < 192; ++kk) acc += mm[kk] * w[kk * 192 + d];
    wsf[bank * 9216 + (i * 16 + s) * 192 + d] = acc;
  }
  for (int g = tid; g < 64; g += nth) cnt[g] = 0u;
}

// ------- prep 2: fp32 WKf, Vpp, bSf; WK1 bf16 single [64][192] chunk -------
__global__ void prep_kv2(const float* __restrict__ rwq, const float* __restrict__ rbq,
                         const float* __restrict__ rwo, float* __restrict__ wsf,
                         ushort_t* __restrict__ ws) {
  int tid = blockIdx.x * blockDim.x + threadIdx.x;
  int nth = gridDim.x * blockDim.x;
  const float scale = 0.144337567297406441f;  // 1/sqrt(48)
  const float* Kv = wsf + F_KV;
  const float* Vv = wsf + F_VV;
  float* WKf = wsf + F_WKF;
  float* Vpp = wsf + F_VPP;
  float* bSf = wsf + F_BSF;
  // WKf fp32 (layers 1,2 for folding)
  for (int idx = tid; idx < 36864; idx += nth) {
    int i = idx / 12288, rem = idx % 12288, n = rem / 192, k = rem % 192;
    int h = n >> 4, s = n & 15;
    const float* kvp = Kv + (i * 16 + s) * 192 + h * 48;
    const float* wqp = rwq + i * 36864 + k * 192 + h * 48;
    float acc = 0.f;
    for (int d = 0; d < 48; ++d) acc += wqp[d] * kvp[d];
    WKf[idx] = scale * acc;
  }
  // WK1 bf16 single chunk [64 n][192 k] (per-64k-block 8-granule swizzle)
  for (int idx = tid; idx < 12288; idx += nth) {
    int n = idx / 192, rem = idx % 192, kb = rem >> 6, kin = rem & 63;
    int k = kb * 64 + 8 * ((kin >> 3) ^ (n & 7)) + (kin & 7);
    int h = n >> 4, s = n & 15;
    const float* kvp = Kv + s * 192 + h * 48;
    const float* wqp = rwq + k * 192 + h * 48;
    float acc = 0.f;
    for (int d = 0; d < 48; ++d) acc += wqp[d] * kvp[d];
    ws[OFF_WK + idx] = f2bu_prep(scale * acc);
  }
  // Vpp[i][s1][dcol] = V_i[s1] @ wo_i
  for (int idx = tid; idx < 36864; idx += nth) {
    int i = idx / 12288, rem = idx % 12288, n = rem / 192, dcol = rem % 192;
    int h = n >> 4, s = n & 15;
    const float* vvp = Vv + (i * 16 + s) * 192 + h * 48;
    const float* wop = rwo + i * 36864 + (h * 48) * 192 + dcol;
    float acc = 0.f;
    for (int d = 0; d < 48; ++d) acc += vvp[d] * wop[d * 192];
    Vpp[idx] = acc;
  }
  // bSf[i][n] = scale * bq_h . K_h[s]
  for (int idx = tid; idx < 192; idx += nth) {
    int i = idx >> 6, n = idx & 63, h = n >> 4, s = n & 15;
    const float* kvp = Kv + (i * 16 + s) * 192 + h * 48;
    const float* bqp = rbq + i * 192 + h * 48;
    float acc = 0.f;
    for (int d = 0; d < 48; ++d) acc += bqp[d] * kvp[d];
    bSf[idx] = scale * acc;
  }
}

// ------- prep 3: slot-space folds M2, M3, MG (bf16 blob) + battn + bG -----
__global__ void prep_kv3(const float* __restrict__ rbo, const float* __restrict__ gr,
                         float* __restrict__ wsf, ushort_t* __restrict__ ws) {
  int tid = blockIdx.x * blockDim.x + threadIdx.x;
  int nth = gridDim.x * blockDim.x;
  const float* Vpp = wsf + F_VPP;
  const float* WKf = wsf + F_WKF;
  const float* bSf = wsf + F_BSF;
  // M_{l+1}[s1][s2] = Vpp[l][s1] . WKf[l+1][s2]; chunk [n=s2][k=s1] swizzled
  for (int idx = tid; idx < 8192; idx += nth) {
    int l = idx >> 12, rem = idx & 4095, n = rem >> 6, kin = rem & 63;
    int k = 8 * ((kin >> 3) ^ (n & 7)) + (kin & 7);
    const float* vp = Vpp + l * 12288 + k * 192;
    const float* wp = WKf + (l + 1) * 12288 + n * 192;
    float acc = 0.f;
    for (int t = 0; t < 192; ++t) acc += vp[t] * wp[t];
    ws[OFF_M + l * 4096 + n * 64 + kin] = f2bu_prep(acc);
  }
  // MG[s1][g] = Vpp[2][s1] . grid[g]; chunk [n=g][k=s1]
  for (int idx = tid; idx < 4096; idx += nth) {
    int n = idx >> 6, kin = idx & 63;
    int k = 8 * ((kin >> 3) ^ (n & 7)) + (kin & 7);
    const float* vp = Vpp + 2 * 12288 + k * 192;
    const float* gp = gr + n * 192;
    float acc = 0.f;
    for (int t = 0; t < 192; ++t) acc += vp[t] * gp[t];
    ws[OFF_M + 8192 + n * 64 + kin] = f2bu_prep(acc);
  }
  // battn[0]=bSf0; battn[l]=bSf[l]+bo_{l-1}@WKf[l]
  for (int idx = tid; idx < 192; idx += nth) {
    int l = idx >> 6, n = idx & 63;
    float acc = bSf[l * 64 + n];
    if (l > 0) {
      const float* wp = WKf + l * 12288 + n * 192;
      const float* bo = rbo + (l - 1) * 192;
      for (int t = 0; t < 192; ++t) acc += bo[t] * wp[t];
    }
    wsf[F_BATTN + idx] = acc;
  }
  // bG[g] = bo2 . grid[g] - 0.5*||grid[g]||^2
  for (int g = tid; g < 64; g += nth) {
    const float* gp = gr + g * 192;
    const float* bo = rbo + 2 * 192;
    float a = 0.f, s = 0.f;
    for (int t = 0; t < 192; ++t) { a += bo[t] * gp[t]; s += gp[t] * gp[t]; }
    wsf[F_BG + g] = a - 0.5f * s;
  }
}

// ---------------- main-kernel helpers (4-wave block, 24-seg chunks) -------
__device__ __forceinline__ void stage_to(ushort_t* dst, const ushort_t* src, int wave, int lane) {
#pragma unroll
  for (int j = 0; j < 6; ++j) {
    int s = wave + j * 4;
    gload16(src + (s << 9) + lane * 8, dst + (s << 9));
  }
}

// consumption-order phase table (18 phases); all chunks are 24 segs
__device__ __forceinline__ const ushort_t* chunk_ptr(const ushort_t* wsu, int g, int* nseg) {
  *nseg = 24;
  if (g < 1)            return wsu + OFF_VIB;
  g -= 1;  if (g < 3)   return wsu + OFF_FUS + g * 12288;
  g -= 3;  if (g < 4)   return wsu + OFF_ACO + g * 12288;
  g -= 4;  if (g < 3)   return wsu + OFF_FUS + 36864 + g * 12288;
  g -= 3;  if (g < 2)   return wsu + OFF_TMP + g * 12288;
  g -= 2;  if (g < 3)   return wsu + OFF_FUS + 73728 + g * 12288;
  g -= 3;  if (g < 1)   return wsu + OFF_WK;    // phase 16
  g -= 1;  if (g < 1)   return wsu + OFF_M;     // phase 17 (blob; staged during 16)
  *nseg = 0; return wsu;
}

__device__ __forceinline__ void phase_begin(const ushort_t* wsu, ushort_t (*Wb)[12288],
                                            int gph, int wave, int lane) {
  __syncthreads();
  int nseg; const ushort_t* ns = chunk_ptr(wsu, gph + 1, &nseg);
  if (nseg) stage_to(&Wb[(gph + 1) & 1][0], ns, wave, lane);
}

__device__ __forceinline__ short8 cvt8(float4 a, float4 b) {
  short8 v;
  v[0] = (short)f2bu(a.x); v[1] = (short)f2bu(a.y); v[2] = (short)f2bu(a.z); v[3] = (short)f2bu(a.w);
  v[4] = (short)f2bu(b.x); v[5] = (short)f2bu(b.y); v[6] = (short)f2bu(b.z); v[7] = (short)f2bu(b.w);
  return v;
}

// encoder GEMM, ROW-SPLIT: wave owns 16 rows x all 192 out-cols.
// R16: 2-step (64k) rolling x prefetch — hides the scattered-row load latency
// behind a full phase of compute instead of one ks-step.
template<int NPH>
__device__ __forceinline__ void enc_gemm(const float* __restrict__ x, int row0,
    const ushort_t* wsu, ushort_t (*Wb)[12288], int* gph, f32x4* accE,
    int m, int gq, int wave, int lane) {
  const int KF = NPH * 64;
  const float* p0 = x + (size_t)row0 * KF + gq * 8;
  float4 ca0 = *(const float4*)(p0);
  float4 ca1 = *(const float4*)(p0 + 4);
  float4 cb0 = ca0, cb1 = ca1;
  if (KF > 32) { cb0 = *(const float4*)(p0 + 32); cb1 = *(const float4*)(p0 + 36); }
#pragma unroll
  for (int ph = 0; ph < NPH; ++ph) {
    phase_begin(wsu, Wb, *gph, wave, lane);
    const ushort_t* Wc = &Wb[*gph & 1][0];
#pragma unroll
    for (int ks = 0; ks < 2; ++ks) {
      int sl = ks * 4 + gq;
      short8 a = cvt8(ca0, ca1);
      int nk = (ph * 2 + ks + 2) * 32;
      float4 n0 = ca0, n1 = ca1;
      if (nk < KF) {
        n0 = *(const float4*)(p0 + nk);
        n1 = *(const float4*)(p0 + nk + 4);
      }
      __builtin_amdgcn_s_setprio(1);
#pragma unroll
      for (int t = 0; t < 12; ++t) {
        int n = t * 16 + m;
        short8 b = *(const short8*)(Wc + n * 64 + ((sl ^ (n & 7)) << 3));
        accE[t] = MFMA16(b, a, accE[t]);
      }
      __builtin_amdgcn_s_setprio(0);
      ca0 = cb0; ca1 = cb1; cb0 = n0; cb1 = n1;
    }
    ++*gph;
  }
}

// GEMM from activation panel, COL-SPLIT: wave owns all 64 rows x 48 cols.
__device__ __forceinline__ void lds_gemm(const ushort_t* Ab, const ushort_t* wsu,
    ushort_t (*Wb)[12288], int* gph, f32x4* acc, int wc0, int m, int gq,
    int wave, int lane) {
#pragma unroll
  for (int ph = 0; ph < 3; ++ph) {
    phase_begin(wsu, Wb, *gph, wave, lane);
    const ushort_t* Wc = &Wb[*gph & 1][0];
    __builtin_amdgcn_s_setprio(1);
#pragma unroll
    for (int ks = 0; ks < 2; ++ks) {
      int sl = ks * 4 + gq;
      short8 b0, b1, b2;
      {
        int n0 = wc0 + m, n1 = wc0 + 16 + m, n2 = wc0 + 32 + m;
        b0 = *(const short8*)(Wc + n0 * 64 + ((sl ^ (n0 & 7)) << 3));
        b1 = *(const short8*)(Wc + n1 * 64 + ((sl ^ (n1 & 7)) << 3));
        b2 = *(const short8*)(Wc + n2 * 64 + ((sl ^ (n2 & 7)) << 3));
      }
#pragma unroll
      for (int mt = 0; mt < 4; ++mt) {
        int r = mt * 16 + m;
        short8 a = *(const short8*)(Ab + r * 192 + ((ph * 8 + (sl ^ (r & 7))) << 3));
        acc[mt * 3 + 0] = MFMA16(b0, a, acc[mt * 3 + 0]);
        acc[mt * 3 + 1] = MFMA16(b1, a, acc[mt * 3 + 1]);
        acc[mt * 3 + 2] = MFMA16(b2, a, acc[mt * 3 + 2]);
      }
    }
    __builtin_amdgcn_s_setprio(0);
    ++*gph;
  }
}

// encoder LN+GELU: fully wave-local (row-split).
__device__ __forceinline__ void ln_gelu_enc(f32x4* acc, const float* __restrict__ bias,
    const float* __restrict__ gam, const float* __restrict__ bet,
    ushort_t* __restrict__ Ab, int rloc, int gq) {
  float s = 0.f, q = 0.f;
#pragma unroll
  for (int t = 0; t < 12; ++t) {
    float4 bv = *(const float4*)(bias + t * 16 + gq * 4);
#pragma unroll
    for (int j = 0; j < 4; ++j) {
      float v = acc[t][j] + ((const float*)&bv)[j];
      acc[t][j] = v; s += v; q += v * v;
    }
  }
  s += __shfl_xor(s, 16, 64); q += __shfl_xor(q, 16, 64);
  s += __shfl_xor(s, 32, 64); q += __shfl_xor(q, 32, 64);
  float mean = s * (1.0f / 192.0f);
  float var = q * (1.0f / 192.0f) - mean * mean;
  float rstd = rsqrtf(var + 1e-5f);
#pragma unroll
  for (int t = 0; t < 12; ++t) {
    int colb = t * 16 + gq * 4;
    float4 ga = *(const float4*)(gam + colb);
    float4 be = *(const float4*)(bet + colb);
    ushort_t o[4];
#pragma unroll
    for (int j = 0; j < 4; ++j) {
      float y = (acc[t][j] - mean) * rstd * ((const float*)&ga)[j] + ((const float*)&be)[j];
      o[j] = f2bu(gelu_fast(y));
    }
    int off = rloc * 192 + (((colb >> 3) ^ (rloc & 7)) << 3) + (colb & 7);
    *(uint2*)(Ab + off) = *(uint2*)o;
  }
}

// fusion LN+GELU: col-split (4-way) with cross-wave stats scratch
__device__ __forceinline__ void ln_gelu_fus(f32x4* acc, const float* __restrict__ bias,
    const float* __restrict__ gam, const float* __restrict__ bet,
    ushort_t* __restrict__ Ab, float2 (*scr)[4], int wave, int wc0, int m, int gq) {
  float4 bv[3];
#pragma unroll
  for (int t = 0; t < 3; ++t) bv[t] = *(const float4*)(bias + wc0 + t * 16 + gq * 4);
#pragma unroll
  for (int mt = 0; mt < 4; ++mt) {
    float s = 0.f, q = 0.f;
#pragma unroll
    for (int t = 0; t < 3; ++t)
#pragma unroll
      for (int j = 0; j < 4; ++j) {
        float v = acc[mt * 3 + t][j] + ((const float*)&bv[t])[j];
        acc[mt * 3 + t][j] = v; s += v; q += v * v;
      }
    s += __shfl_xor(s, 16, 64); q += __shfl_xor(q, 16, 64);
    s += __shfl_xor(s, 32, 64); q += __shfl_xor(q, 32, 64);
    if (gq == 0) scr[mt * 16 + m][wave] = (float2){s, q};
  }
  __syncthreads();
#pragma unroll
  for (int mt = 0; mt < 4; ++mt) {
    int row = mt * 16 + m;
    float s = 0.f, q = 0.f;
#pragma unroll
    for (int w = 0; w < 4; ++w) { float2 p = scr[row][w]; s += p.x; q += p.y; }
    float mean = s * (1.0f / 192.0f);
    float var = q * (1.0f / 192.0f) - mean * mean;
    float rstd = rsqrtf(var + 1e-5f);
#pragma unroll
    for (int t = 0; t < 3; ++t) {
      int colb = wc0 + t * 16 + gq * 4;
      float4 ga = *(const float4*)(gam + colb);
      float4 be = *(const float4*)(bet + colb);
      ushort_t o[4];
#pragma unroll
      for (int j = 0; j < 4; ++j) {
        float y = (acc[mt * 3 + t][j] - mean) * rstd * ((const float*)&ga)[j] + ((const float*)&be)[j];
        o[j] = f2bu(gelu_fast(y));
      }
      int off = row * 192 + (((colb >> 3) ^ (row & 7)) << 3) + (colb & 7);
      *(uint2*)(Ab + off) = *(uint2*)o;
    }
  }
}

// softmax over this wave's 16 slots (head = wave) -> write P panel (swizzled)
__device__ __forceinline__ void softmax_to_P(f32x4* accS, const float* __restrict__ bptr,
    ushort_t* __restrict__ Pb, int w16, int m, int gq) {
  float4 b4 = *(const float4*)(bptr + w16 + gq * 4);
  const int gnum = (w16 + gq * 4) >> 3;
#pragma unroll
  for (int mt = 0; mt < 4; ++mt) {
    float e[4]; float mx = -3.0e38f;
#pragma unroll
    for (int j = 0; j < 4; ++j) { e[j] = accS[mt][j] + ((const float*)&b4)[j]; mx = fmaxf(mx, e[j]); }
    mx = fmaxf(mx, __shfl_xor(mx, 16, 64));
    mx = fmaxf(mx, __shfl_xor(mx, 32, 64));
    float sm = 0.f;
#pragma unroll
    for (int j = 0; j < 4; ++j) { e[j] = exp2f((e[j] - mx) * 1.44269504f); sm += e[j]; }
    sm += __shfl_xor(sm, 16, 64);
    sm += __shfl_xor(sm, 32, 64);
    float inv = fastrcp(sm);
    ushort_t p4[4];
#pragma unroll
    for (int j = 0; j < 4; ++j) p4[j] = f2bu(e[j] * inv);
    int r = mt * 16 + m;
    *(uint2*)(Pb + r * 64 + ((gnum ^ (r & 7)) << 3) + (gq & 1) * 4) = *(uint2*)p4;
  }
}

// ---------------- main fused kernel ----------------
// R16 = R15 + 2-deep encoder x prefetch + s_setprio(1) around MFMA clusters
// (2 co-resident blocks sit at different phases -> scheduler can favor the
// computing wave over the staging wave).
__global__ __launch_bounds__(256) __attribute__((amdgpu_waves_per_eu(2))) void arn_main(
    const float* __restrict__ xv, const float* __restrict__ xa, const float* __restrict__ xt,
    const ushort_t* __restrict__ wsu, const float* __restrict__ battn,
    const float* __restrict__ bG, unsigned* __restrict__ counts,
    const float* __restrict__ ebv, const float* __restrict__ egv, const float* __restrict__ ebbv,
    const float* __restrict__ eba, const float* __restrict__ ega, const float* __restrict__ ebba,
    const float* __restrict__ ebt, const float* __restrict__ egt, const float* __restrict__ ebbt,
    const float* __restrict__ fb, const float* __restrict__ fg, const float* __restrict__ fbb) {
  __shared__ __align__(16) ushort_t Abuf[64 * 192 + 64];  // swizzled activations + zero pad
  __shared__ __align__(16) ushort_t Wbuf[2][12288];       // double-buffered chunks
  __shared__ float2 lnscr[64][4];
  __shared__ unsigned hist[64];

  const int tid = threadIdx.x, lane = tid & 63, wave = tid >> 6;
  const int m = lane & 15, gq = lane >> 4;
  const int wc0 = wave * 48;             // col-split GEMM col base
  const int w16 = wave * 16;             // head base / row-split base
  const int growbase = blockIdx.x * 64;

  if (tid < 64) { hist[tid] = 0u; Abuf[12288 + tid] = 0; }

  int gph = 0;
  { int nseg; const ushort_t* s0 = chunk_ptr(wsu, 0, &nseg); stage_to(&Wbuf[0][0], s0, wave, lane); }

  const int row0 = growbase + w16 + m;   // this lane's global row (row-split)
  const int rloc = w16 + m;              // local row in Abuf
  f32x4 accF[12];
#pragma unroll
  for (int t = 0; t < 12; ++t) accF[t] = (f32x4){0.f, 0.f, 0.f, 0.f};

  // ===== vib encoder + fus part 0 =====
  {
    f32x4 accE[12];
#pragma unroll
    for (int t = 0; t < 12; ++t) accE[t] = (f32x4){0.f, 0.f, 0.f, 0.f};
    enc_gemm<1>(xv, row0, wsu, Wbuf, &gph, accE, m, gq, wave, lane);
    ln_gelu_enc(accE, ebv, egv, ebbv, Abuf, rloc, gq);
  }
  lds_gemm(Abuf, wsu, Wbuf, &gph, accF, wc0, m, gq, wave, lane);

  // ===== aco encoder + fus part 1 =====
  {
    f32x4 accE[12];
#pragma unroll
    for (int t = 0; t < 12; ++t) accE[t] = (f32x4){0.f, 0.f, 0.f, 0.f};
    enc_gemm<4>(xa, row0, wsu, Wbuf, &gph, accE, m, gq, wave, lane);
    ln_gelu_enc(accE, eba, ega, ebba, Abuf, rloc, gq);
  }
  lds_gemm(Abuf, wsu, Wbuf, &gph, accF, wc0, m, gq, wave, lane);

  // ===== tmp encoder + fus part 2 + fusion LN =====
  {
    f32x4 accE[12];
#pragma unroll
    for (int t = 0; t < 12; ++t) accE[t] = (f32x4){0.f, 0.f, 0.f, 0.f};
    enc_gemm<2>(xt, row0, wsu, Wbuf, &gph, accE, m, gq, wave, lane);
    ln_gelu_enc(accE, ebt, egt, ebbt, Abuf, rloc, gq);
  }
  lds_gemm(Abuf, wsu, Wbuf, &gph, accF, wc0, m, gq, wave, lane);
  ln_gelu_fus(accF, fb, fg, fbb, Abuf, lnscr, wave, wc0, m, gq);

  // ===== folded resonance chain (1 heavy phase + 4 light barriers) =====
  {
    f32x4 accS[4];
#pragma unroll
    for (int t = 0; t < 4; ++t) accS[t] = (f32x4){0.f, 0.f, 0.f, 0.f};
    // --- GEMM1: S1 = fused @ WK1 (phase 16; prefetches M-blob into buf1)
    phase_begin(wsu, Wbuf, gph, wave, lane);   // gph == 16, WK1 in buf0
    {
      const ushort_t* Wc = &Wbuf[0][0];
      int n = w16 + m;
      __builtin_amdgcn_s_setprio(1);
#pragma unroll
      for (int ks = 0; ks < 6; ++ks) {
        int kb = ks >> 1, sl = (ks & 1) * 4 + gq;
        short8 b = *(const short8*)(Wc + n * 192 + ((kb * 8 + (sl ^ (n & 7))) << 3));
#pragma unroll
        for (int mt = 0; mt < 4; ++mt) {
          int r = mt * 16 + m;
          short8 a = *(const short8*)(Abuf + r * 192 + ((kb * 8 + (sl ^ (r & 7))) << 3));
          accS[mt] = MFMA16(b, a, accS[mt]);
        }
      }
      __builtin_amdgcn_s_setprio(0);
      ++gph;
    }
    __syncthreads();  // all WK1 reads done; M-blob loads drained (vmcnt on barrier)
    softmax_to_P(accS, battn, &Wbuf[0][0], w16, m, gq);  // P1 -> buf0 @0
    __syncthreads();

    // --- layers 2,3: S = P_prev @ M + b (barrier-only; M from buf1 blob)
#pragma unroll
    for (int l = 1; l <= 2; ++l) {
      const ushort_t* Mc = &Wbuf[1][(l - 1) * 4096];
      const ushort_t* Pp = &Wbuf[0][(l - 1) * 4096];
#pragma unroll
      for (int t = 0; t < 4; ++t) accS[t] = (f32x4){0.f, 0.f, 0.f, 0.f};
      int n = w16 + m;
#pragma unroll
      for (int ks = 0; ks < 2; ++ks) {
        int sl = ks * 4 + gq;
        short8 b = *(const short8*)(Mc + n * 64 + ((sl ^ (n & 7)) << 3));
#pragma unroll
        for (int mt = 0; mt < 4; ++mt) {
          int r = mt * 16 + m;
          short8 a = *(const short8*)(Pp + r * 64 + ((sl ^ (r & 7)) << 3));
          accS[mt] = MFMA16(b, a, accS[mt]);
        }
      }
      softmax_to_P(accS, battn + l * 64, &Wbuf[0][l * 4096], w16, m, gq);  // disjoint region
      __syncthreads();
    }

    // --- SOFM: scores = P3 @ MG + bG (row-split) -> argmax histogram
    {
      const ushort_t* Mc = &Wbuf[1][8192];
      const ushort_t* P3 = &Wbuf[0][8192];
      f32x4 accG[4];
#pragma unroll
      for (int t = 0; t < 4; ++t) accG[t] = (f32x4){0.f, 0.f, 0.f, 0.f};
      int r = w16 + m;
#pragma unroll
      for (int ks = 0; ks < 2; ++ks) {
        int sl = ks * 4 + gq;
        short8 a = *(const short8*)(P3 + r * 64 + ((sl ^ (r & 7)) << 3));
#pragma unroll
        for (int nt = 0; nt < 4; ++nt) {
          int n = nt * 16 + m;
          short8 b = *(const short8*)(Mc + n * 64 + ((sl ^ (n & 7)) << 3));
          accG[nt] = MFMA16(b, a, accG[nt]);  // accG[nt][j] = score[row][g=nt*16+gq*4+j]
        }
      }
      float bv = -3.0e38f; int bi = 64;
#pragma unroll
      for (int nt = 0; nt < 4; ++nt) {
        int gb = nt * 16 + gq * 4;
        float4 g4 = *(const float4*)(bG + gb);
#pragma unroll
        for (int j = 0; j < 4; ++j) {
          float v = accG[nt][j] + ((const float*)&g4)[j];
          int g = gb + j;
          bool take = (v > bv);  // ascending g within lane: strict > keeps lowest
          bv = take ? v : bv; bi = take ? g : bi;
        }
      }
#pragma unroll
      for (int off = 16; off < 64; off <<= 1) {
        float ov = __shfl_xor(bv, off, 64);
        int oi = __shfl_xor(bi, off, 64);
        bool take = (ov > bv) || (ov == bv && oi < bi);
        bv = take ? ov : bv; bi = take ? oi : bi;
      }
      if (gq == 0) atomicAdd(&hist[bi], 1u);  // one count per row (owner m-lane)
    }
  }
  __syncthreads();
  if (tid < 64 && hist[tid]) atomicAdd(&counts[tid], hist[tid]);
}

// ---------------- finisher ----------------
__global__ void arn_finish(const unsigned* __restrict__ counts, const float* __restrict__ gr,
                           const float* __restrict__ ow, const float* __restrict__ ob,
                           float* __restrict__ out) {
  __shared__ float pooled[192];
  __shared__ float cf[64];
  int t = threadIdx.x;
  if (t < 64) cf[t] = (float)counts[t];
  __syncthreads();
  float s = 0.f;
  for (int g = 0; g < 64; ++g) s += cf[g] * gr[g * 192 + t];
  pooled[t] = s * (1.0f / (float)B_TOTAL);
  __syncthreads();
  if (t < 6) {
    float o = ob[t];
    for (int j = 0; j < 192; ++j) o += pooled[j] * ow[j * 6 + t];
    out[t] = (t == 1) ? fmaxf(o, 0.f) : 1.f / (1.f + expf(-o));
  }
}

// ---------------- launch ----------------
extern "C" void kernel_launch(void* const* d_in, const int* in_sizes, int n_in,
                              void* d_out, int out_size, void* d_ws, size_t ws_size,
                              hipStream_t stream) {
  (void)in_sizes; (void)n_in; (void)out_size; (void)ws_size;
  const float* xv   = (const float*)d_in[0];
  const float* xa   = (const float*)d_in[1];
  const float* xt   = (const float*)d_in[2];
  const float* ewv  = (const float*)d_in[3];
  const float* ebv  = (const float*)d_in[4];
  const float* egv  = (const float*)d_in[5];
  const float* ebbv = (const float*)d_in[6];
  const float* ewa  = (const float*)d_in[7];
  const float* eba  = (const float*)d_in[8];
  const float* ega  = (const float*)d_in[9];
  const float* ebba = (const float*)d_in[10];
  const float* ewt  = (const float*)d_in[11];
  const float* ebt  = (const float*)d_in[12];
  const float* egt  = (const float*)d_in[13];
  const float* ebbt = (const float*)d_in[14];
  const float* fw   = (const float*)d_in[15];
  const float* fb   = (const float*)d_in[16];
  const float* fg   = (const float*)d_in[17];
  const float* fbb  = (const float*)d_in[18];
  const float* rwq  = (const float*)d_in[19];
  const float* rwk  = (const float*)d_in[20];
  const float* rwv  = (const float*)d_in[21];
  const float* rwo  = (const float*)d_in[22];
  const float* rbq  = (const float*)d_in[23];
  const float* rbk  = (const float*)d_in[24];
  const float* rbv  = (const float*)d_in[25];
  const float* rbo  = (const float*)d_in[26];
  const float* rmem = (const float*)d_in[27];
  const float* grid = (const float*)d_in[28];
  const float* ow   = (const float*)d_in[29];
  const float* ob   = (const float*)d_in[30];

  ushort_t* wsu = (ushort_t*)d_ws;
  float* wsf = (float*)((char*)d_ws + F32_BYTE_OFF);
  float* battn = wsf + F_BATTN;
  float* bG    = wsf + F_BG;
  unsigned* cnt = (unsigned*)(wsf + F_CNT);

  prep_weights<<<dim3(256), dim3(256), 0, stream>>>(ewv, ewa, ewt, fw, wsu);
  prep_kv1<<<dim3(80), dim3(256), 0, stream>>>(rwk, rwv, rbk, rbv, rmem, wsf, cnt);
  prep_kv2<<<dim3(120), dim3(256), 0, stream>>>(rwq, rbq, rwo, wsf, wsu);
  prep_kv3<<<dim3(64), dim3(256), 0, stream>>>(rbo, grid, wsf, wsu);
  arn_main<<<dim3(2048), dim3(256), 0, stream>>>(xv, xa, xt, wsu, battn, bG, cnt,
      ebv, egv, ebbv, eba, ega, ebba, ebt, egt, ebbt, fb, fg, fbb);
  arn_finish<<<dim3(1), dim3(192), 0, stream>>>(cnt, grid, ow, ob, (float*)d_out);
}

// Round 17
// 196.577 us; speedup vs baseline: 3.2253x; 1.0057x over previous
//
#include <hip/hip_runtime.h>
#include <hip/hip_bf16.h>
#include <math.h>

typedef unsigned short ushort_t;
typedef __attribute__((ext_vector_type(8))) short short8;
typedef __attribute__((ext_vector_type(4))) float f32x4;

#define B_TOTAL 131072

// ws layout (ushort element offsets). W blobs are K64-split chunk-major:
// chunk = [N rows][64 k]; storage (n, s, j) holds logical k = ck*64 + 8*(s ^ (n&7)) + j.
#define OFF_VIB 0        // 1 chunk  [192][64]  = 12288
#define OFF_ACO 12288    // 4 chunks             = 49152
#define OFF_TMP 61440    // 2 chunks             = 24576
#define OFF_FUS 86016    // 9 chunks (3/part)    = 110592
#define OFF_WK 196608    // single [64][192] chunk (3 k-blocks) = 12288
#define OFF_M 208896     // M2|M3|MG blob, 3 x [64][64] = 12288
// f32 region at byte 442368: Kv, Vv, Vpp, WKf, bSf, battn, bG, cnt
#define F32_BYTE_OFF 442368
#define F_KV 0
#define F_VV 9216
#define F_VPP 18432
#define F_WKF 55296
#define F_BSF 92160
#define F_BATTN 92352
#define F_BG 92544
#define F_CNT 92608

// prep kernels: explicit RTNE bit-twiddle (cold code)
__device__ __forceinline__ ushort_t f2bu_prep(float f) {
  union { float f; unsigned u; } c; c.f = f;
  unsigned u = c.u;
  unsigned r = (u + 0x7fffu + ((u >> 16) & 1u)) >> 16;  // RTNE
  return (ushort_t)r;
}
// hot kernel: v_cvt bf16 (RTNE on gfx950)
__device__ __forceinline__ ushort_t f2bu(float f) {
  __hip_bfloat16 h = __float2bfloat16(f);
  return *(ushort_t*)&h;
}
__device__ __forceinline__ float fastrcp(float x) { return __builtin_amdgcn_rcpf(x); }
// sigmoid-form GELU: x * sigma(1.702 x); 5 VALU ops, NaN-free.
__device__ __forceinline__ float gelu_fast(float x) {
  return x * fastrcp(1.0f + exp2f(-2.45546465f * x));
}
#define MFMA16(a, b, c) __builtin_amdgcn_mfma_f32_16x16x32_bf16(a, b, c, 0, 0, 0)

__device__ __forceinline__ void gload16(const void* g, void* l) {
  __builtin_amdgcn_global_load_lds((const __attribute__((address_space(1))) void*)g,
                                   (__attribute__((address_space(3))) void*)l, 16, 0, 0);
}

// ---------------- prep: weights -> K64-split swizzled chunks ----------------
__global__ void prep_weights(const float* __restrict__ ev, const float* __restrict__ ea,
                             const float* __restrict__ et, const float* __restrict__ fw,
                             ushort_t* __restrict__ ws) {
  int tid = blockIdx.x * blockDim.x + threadIdx.x;
  int nth = gridDim.x * blockDim.x;
  for (int i = tid; i < 12288; i += nth) {
    int n = i >> 6, kin = i & 63;
    int k = 8 * ((kin >> 3) ^ (n & 7)) + (kin & 7);
    ws[OFF_VIB + i] = f2bu_prep(ev[k * 192 + n]);
  }
  for (int i = tid; i < 49152; i += nth) {
    int ck = i / 12288, rem = i % 12288, n = rem >> 6, kin = rem & 63;
    int k = ck * 64 + 8 * ((kin >> 3) ^ (n & 7)) + (kin & 7);
    ws[OFF_ACO + i] = f2bu_prep(ea[k * 192 + n]);
  }
  for (int i = tid; i < 24576; i += nth) {
    int ck = i / 12288, rem = i % 12288, n = rem >> 6, kin = rem & 63;
    int k = ck * 64 + 8 * ((kin >> 3) ^ (n & 7)) + (kin & 7);
    ws[OFF_TMP + i] = f2bu_prep(et[k * 192 + n]);
  }
  for (int i = tid; i < 110592; i += nth) {
    int ck = i / 12288, rem = i % 12288, n = rem >> 6, kin = rem & 63;
    int k = ck * 64 + 8 * ((kin >> 3) ^ (n & 7)) + (kin & 7);
    ws[OFF_FUS + i] = f2bu_prep(fw[k * 192 + n]);
  }
}

// ------- prep 1: K/V vectors (fp32): Kv[i][s][192], Vv[i][s][192] ---------
__global__ void prep_kv1(const float* __restrict__ rwk, const float* __restrict__ rwv,
                         const float* __restrict__ rbk, const float* __restrict__ rbv,
                         const float* __restrict__ rmem, float* __restrict__ wsf,
                         unsigned* __restrict__ cnt) {
  int tid = blockIdx.x * blockDim.x + threadIdx.x;
  int nth = gridDim.x * blockDim.x;
  for (int idx = tid; idx < 18432; idx += nth) {
    int bank = idx / 9216, r = idx % 9216;
    int i = r / 3072, q = r % 3072, s = q / 192, d = q % 192;
    const float* w  = (bank ? rwv : rwk) + i * 36864;
    const float* bs = (bank ? rbv : rbk) + i * 192;
    const float* mm = rmem + i * 3072 + s * 192;
    float acc = bs[d];
    for (int kk = 0; kk < 192; ++kk) acc += mm[kk] * w[kk * 192 + d];
    wsf[bank * 9216 + (i * 16 + s) * 192 + d] = acc;
  }
  for (int g = tid; g < 64; g += nth) cnt[g] = 0u;
}

// ------- prep 2: fp32 WKf, Vpp, bSf; WK1 bf16 single [64][192] chunk -------
__global__ void prep_kv2(const float* __restrict__ rwq, const float* __restrict__ rbq,
                         const float* __restrict__ rwo, float* __restrict__ wsf,
                         ushort_t* __restrict__ ws) {
  int tid = blockIdx.x * blockDim.x + threadIdx.x;
  int nth = gridDim.x * blockDim.x;
  const float scale = 0.144337567297406441f;  // 1/sqrt(48)
  const float* Kv = wsf + F_KV;
  const float* Vv = wsf + F_VV;
  float* WKf = wsf + F_WKF;
  float* Vpp = wsf + F_VPP;
  float* bSf = wsf + F_BSF;
  // WKf fp32 (layers 1,2 for folding)
  for (int idx = tid; idx < 36864; idx += nth) {
    int i = idx / 12288, rem = idx % 12288, n = rem / 192, k = rem % 192;
    int h = n >> 4, s = n & 15;
    const float* kvp = Kv + (i * 16 + s) * 192 + h * 48;
    const float* wqp = rwq + i * 36864 + k * 192 + h * 48;
    float acc = 0.f;
    for (int d = 0; d < 48; ++d) acc += wqp[d] * kvp[d];
    WKf[idx] = scale * acc;
  }
  // WK1 bf16 single chunk [64 n][192 k] (per-64k-block 8-granule swizzle)
  for (int idx = tid; idx < 12288; idx += nth) {
    int n = idx / 192, rem = idx % 192, kb = rem >> 6, kin = rem & 63;
    int k = kb * 64 + 8 * ((kin >> 3) ^ (n & 7)) + (kin & 7);
    int h = n >> 4, s = n & 15;
    const float* kvp = Kv + s * 192 + h * 48;
    const float* wqp = rwq + k * 192 + h * 48;
    float acc = 0.f;
    for (int d = 0; d < 48; ++d) acc += wqp[d] * kvp[d];
    ws[OFF_WK + idx] = f2bu_prep(scale * acc);
  }
  // Vpp[i][s1][dcol] = V_i[s1] @ wo_i
  for (int idx = tid; idx < 36864; idx += nth) {
    int i = idx / 12288, rem = idx % 12288, n = rem / 192, dcol = rem % 192;
    int h = n >> 4, s = n & 15;
    const float* vvp = Vv + (i * 16 + s) * 192 + h * 48;
    const float* wop = rwo + i * 36864 + (h * 48) * 192 + dcol;
    float acc = 0.f;
    for (int d = 0; d < 48; ++d) acc += vvp[d] * wop[d * 192];
    Vpp[idx] = acc;
  }
  // bSf[i][n] = scale * bq_h . K_h[s]
  for (int idx = tid; idx < 192; idx += nth) {
    int i = idx >> 6, n = idx & 63, h = n >> 4, s = n & 15;
    const float* kvp = Kv + (i * 16 + s) * 192 + h * 48;
    const float* bqp = rbq + i * 192 + h * 48;
    float acc = 0.f;
    for (int d = 0; d < 48; ++d) acc += bqp[d] * kvp[d];
    bSf[idx] = scale * acc;
  }
}

// ------- prep 3: slot-space folds M2, M3, MG (bf16 blob) + battn + bG -----
__global__ void prep_kv3(const float* __restrict__ rbo, const float* __restrict__ gr,
                         float* __restrict__ wsf, ushort_t* __restrict__ ws) {
  int tid = blockIdx.x * blockDim.x + threadIdx.x;
  int nth = gridDim.x * blockDim.x;
  const float* Vpp = wsf + F_VPP;
  const float* WKf = wsf + F_WKF;
  const float* bSf = wsf + F_BSF;
  // M_{l+1}[s1][s2] = Vpp[l][s1] . WKf[l+1][s2]; chunk [n=s2][k=s1] swizzled
  for (int idx = tid; idx < 8192; idx += nth) {
    int l = idx >> 12, rem = idx & 4095, n = rem >> 6, kin = rem & 63;
    int k = 8 * ((kin >> 3) ^ (n & 7)) + (kin & 7);
    const float* vp = Vpp + l * 12288 + k * 192;
    const float* wp = WKf + (l + 1) * 12288 + n * 192;
    float acc = 0.f;
    for (int t = 0; t < 192; ++t) acc += vp[t] * wp[t];
    ws[OFF_M + l * 4096 + n * 64 + kin] = f2bu_prep(acc);
  }
  // MG[s1][g] = Vpp[2][s1] . grid[g]; chunk [n=g][k=s1]
  for (int idx = tid; idx < 4096; idx += nth) {
    int n = idx >> 6, kin = idx & 63;
    int k = 8 * ((kin >> 3) ^ (n & 7)) + (kin & 7);
    const float* vp = Vpp + 2 * 12288 + k * 192;
    const float* gp = gr + n * 192;
    float acc = 0.f;
    for (int t = 0; t < 192; ++t) acc += vp[t] * gp[t];
    ws[OFF_M + 8192 + n * 64 + kin] = f2bu_prep(acc);
  }
  // battn[0]=bSf0; battn[l]=bSf[l]+bo_{l-1}@WKf[l]
  for (int idx = tid; idx < 192; idx += nth) {
    int l = idx >> 6, n = idx & 63;
    float acc = bSf[l * 64 + n];
    if (l > 0) {
      const float* wp = WKf + l * 12288 + n * 192;
      const float* bo = rbo + (l - 1) * 192;
      for (int t = 0; t < 192; ++t) acc += bo[t] * wp[t];
    }
    wsf[F_BATTN + idx] = acc;
  }
  // bG[g] = bo2 . grid[g] - 0.5*||grid[g]||^2
  for (int g = tid; g < 64; g += nth) {
    const float* gp = gr + g * 192;
    const float* bo = rbo + 2 * 192;
    float a = 0.f, s = 0.f;
    for (int t = 0; t < 192; ++t) { a += bo[t] * gp[t]; s += gp[t] * gp[t]; }
    wsf[F_BG + g] = a - 0.5f * s;
  }
}

// ---------------- main-kernel helpers (4-wave block, 24-seg chunks) -------
__device__ __forceinline__ void stage_to(ushort_t* dst, const ushort_t* src, int wave, int lane) {
#pragma unroll
  for (int j = 0; j < 6; ++j) {
    int s = wave + j * 4;
    gload16(src + (s << 9) + lane * 8, dst + (s << 9));
  }
}

// consumption-order phase table (18 phases); all chunks are 24 segs
__device__ __forceinline__ const ushort_t* chunk_ptr(const ushort_t* wsu, int g, int* nseg) {
  *nseg = 24;
  if (g < 1)            return wsu + OFF_VIB;
  g -= 1;  if (g < 3)   return wsu + OFF_FUS + g * 12288;
  g -= 3;  if (g < 4)   return wsu + OFF_ACO + g * 12288;
  g -= 4;  if (g < 3)   return wsu + OFF_FUS + 36864 + g * 12288;
  g -= 3;  if (g < 2)   return wsu + OFF_TMP + g * 12288;
  g -= 2;  if (g < 3)   return wsu + OFF_FUS + 73728 + g * 12288;
  g -= 3;  if (g < 1)   return wsu + OFF_WK;    // phase 16
  g -= 1;  if (g < 1)   return wsu + OFF_M;     // phase 17 (blob; staged during 16)
  *nseg = 0; return wsu;
}

__device__ __forceinline__ void phase_begin(const ushort_t* wsu, ushort_t (*Wb)[12288],
                                            int gph, int wave, int lane) {
  __syncthreads();
  int nseg; const ushort_t* ns = chunk_ptr(wsu, gph + 1, &nseg);
  if (nseg) stage_to(&Wb[(gph + 1) & 1][0], ns, wave, lane);
}

__device__ __forceinline__ short8 cvt8(float4 a, float4 b) {
  short8 v;
  v[0] = (short)f2bu(a.x); v[1] = (short)f2bu(a.y); v[2] = (short)f2bu(a.z); v[3] = (short)f2bu(a.w);
  v[4] = (short)f2bu(b.x); v[5] = (short)f2bu(b.y); v[6] = (short)f2bu(b.z); v[7] = (short)f2bu(b.w);
  return v;
}

// preload first 64 k of an encoder's x (issued early to hide latency under
// the previous section's epilogue + fusion phases)
__device__ __forceinline__ void enc_preload(const float* __restrict__ x, int row0, int KF,
    float4* c0, float4* c1, float4* c2, float4* c3, int gq) {
  const float* p0 = x + (size_t)row0 * KF + gq * 8;
  *c0 = *(const float4*)(p0);
  *c1 = *(const float4*)(p0 + 4);
  *c2 = *(const float4*)(p0 + 32);
  *c3 = *(const float4*)(p0 + 36);
}

// encoder GEMM, ROW-SPLIT: wave owns 16 rows x all 192 out-cols.
// First 64 k arrive preloaded; rolling 2-step (64k) prefetch thereafter.
template<int NPH>
__device__ __forceinline__ void enc_gemm(const float* __restrict__ x, int row0,
    const ushort_t* wsu, ushort_t (*Wb)[12288], int* gph, f32x4* accE,
    float4 ca0, float4 ca1, float4 cb0, float4 cb1,
    int m, int gq, int wave, int lane) {
  const int KF = NPH * 64;
  const float* p0 = x + (size_t)row0 * KF + gq * 8;
#pragma unroll
  for (int ph = 0; ph < NPH; ++ph) {
    phase_begin(wsu, Wb, *gph, wave, lane);
    const ushort_t* Wc = &Wb[*gph & 1][0];
#pragma unroll
    for (int ks = 0; ks < 2; ++ks) {
      int sl = ks * 4 + gq;
      short8 a = cvt8(ca0, ca1);
      int nk = (ph * 2 + ks + 2) * 32;
      float4 n0 = ca0, n1 = ca1;
      if (nk < KF) {
        n0 = *(const float4*)(p0 + nk);
        n1 = *(const float4*)(p0 + nk + 4);
      }
      __builtin_amdgcn_s_setprio(1);
#pragma unroll
      for (int t = 0; t < 12; ++t) {
        int n = t * 16 + m;
        short8 b = *(const short8*)(Wc + n * 64 + ((sl ^ (n & 7)) << 3));
        accE[t] = MFMA16(b, a, accE[t]);
      }
      __builtin_amdgcn_s_setprio(0);
      ca0 = cb0; ca1 = cb1; cb0 = n0; cb1 = n1;
    }
    ++*gph;
  }
}

// GEMM from activation panel, COL-SPLIT: wave owns all 64 rows x 48 cols.
__device__ __forceinline__ void lds_gemm(const ushort_t* Ab, const ushort_t* wsu,
    ushort_t (*Wb)[12288], int* gph, f32x4* acc, int wc0, int m, int gq,
    int wave, int lane) {
#pragma unroll
  for (int ph = 0; ph < 3; ++ph) {
    phase_begin(wsu, Wb, *gph, wave, lane);
    const ushort_t* Wc = &Wb[*gph & 1][0];
    __builtin_amdgcn_s_setprio(1);
#pragma unroll
    for (int ks = 0; ks < 2; ++ks) {
      int sl = ks * 4 + gq;
      short8 b0, b1, b2;
      {
        int n0 = wc0 + m, n1 = wc0 + 16 + m, n2 = wc0 + 32 + m;
        b0 = *(const short8*)(Wc + n0 * 64 + ((sl ^ (n0 & 7)) << 3));
        b1 = *(const short8*)(Wc + n1 * 64 + ((sl ^ (n1 & 7)) << 3));
        b2 = *(const short8*)(Wc + n2 * 64 + ((sl ^ (n2 & 7)) << 3));
      }
#pragma unroll
      for (int mt = 0; mt < 4; ++mt) {
        int r = mt * 16 + m;
        short8 a = *(const short8*)(Ab + r * 192 + ((ph * 8 + (sl ^ (r & 7))) << 3));
        acc[mt * 3 + 0] = MFMA16(b0, a, acc[mt * 3 + 0]);
        acc[mt * 3 + 1] = MFMA16(b1, a, acc[mt * 3 + 1]);
        acc[mt * 3 + 2] = MFMA16(b2, a, acc[mt * 3 + 2]);
      }
    }
    __builtin_amdgcn_s_setprio(0);
    ++*gph;
  }
}

// encoder LN+GELU: fully wave-local (row-split).
__device__ __forceinline__ void ln_gelu_enc(f32x4* acc, const float* __restrict__ bias,
    const float* __restrict__ gam, const float* __restrict__ bet,
    ushort_t* __restrict__ Ab, int rloc, int gq) {
  float s = 0.f, q = 0.f;
#pragma unroll
  for (int t = 0; t < 12; ++t) {
    float4 bv = *(const float4*)(bias + t * 16 + gq * 4);
#pragma unroll
    for (int j = 0; j < 4; ++j) {
      float v = acc[t][j] + ((const float*)&bv)[j];
      acc[t][j] = v; s += v; q += v * v;
    }
  }
  s += __shfl_xor(s, 16, 64); q += __shfl_xor(q, 16, 64);
  s += __shfl_xor(s, 32, 64); q += __shfl_xor(q, 32, 64);
  float mean = s * (1.0f / 192.0f);
  float var = q * (1.0f / 192.0f) - mean * mean;
  float rstd = rsqrtf(var + 1e-5f);
#pragma unroll
  for (int t = 0; t < 12; ++t) {
    int colb = t * 16 + gq * 4;
    float4 ga = *(const float4*)(gam + colb);
    float4 be = *(const float4*)(bet + colb);
    ushort_t o[4];
#pragma unroll
    for (int j = 0; j < 4; ++j) {
      float y = (acc[t][j] - mean) * rstd * ((const float*)&ga)[j] + ((const float*)&be)[j];
      o[j] = f2bu(gelu_fast(y));
    }
    int off = rloc * 192 + (((colb >> 3) ^ (rloc & 7)) << 3) + (colb & 7);
    *(uint2*)(Ab + off) = *(uint2*)o;
  }
}

// fusion LN+GELU: col-split (4-way) with cross-wave stats scratch
__device__ __forceinline__ void ln_gelu_fus(f32x4* acc, const float* __restrict__ bias,
    const float* __restrict__ gam, const float* __restrict__ bet,
    ushort_t* __restrict__ Ab, float2 (*scr)[4], int wave, int wc0, int m, int gq) {
  float4 bv[3];
#pragma unroll
  for (int t = 0; t < 3; ++t) bv[t] = *(const float4*)(bias + wc0 + t * 16 + gq * 4);
#pragma unroll
  for (int mt = 0; mt < 4; ++mt) {
    float s = 0.f, q = 0.f;
#pragma unroll
    for (int t = 0; t < 3; ++t)
#pragma unroll
      for (int j = 0; j < 4; ++j) {
        float v = acc[mt * 3 + t][j] + ((const float*)&bv[t])[j];
        acc[mt * 3 + t][j] = v; s += v; q += v * v;
      }
    s += __shfl_xor(s, 16, 64); q += __shfl_xor(q, 16, 64);
    s += __shfl_xor(s, 32, 64); q += __shfl_xor(q, 32, 64);
    if (gq == 0) scr[mt * 16 + m][wave] = (float2){s, q};
  }
  __syncthreads();
#pragma unroll
  for (int mt = 0; mt < 4; ++mt) {
    int row = mt * 16 + m;
    float s = 0.f, q = 0.f;
#pragma unroll
    for (int w = 0; w < 4; ++w) { float2 p = scr[row][w]; s += p.x; q += p.y; }
    float mean = s * (1.0f / 192.0f);
    float var = q * (1.0f / 192.0f) - mean * mean;
    float rstd = rsqrtf(var + 1e-5f);
#pragma unroll
    for (int t = 0; t < 3; ++t) {
      int colb = wc0 + t * 16 + gq * 4;
      float4 ga = *(const float4*)(gam + colb);
      float4 be = *(const float4*)(bet + colb);
      ushort_t o[4];
#pragma unroll
      for (int j = 0; j < 4; ++j) {
        float y = (acc[mt * 3 + t][j] - mean) * rstd * ((const float*)&ga)[j] + ((const float*)&be)[j];
        o[j] = f2bu(gelu_fast(y));
      }
      int off = row * 192 + (((colb >> 3) ^ (row & 7)) << 3) + (colb & 7);
      *(uint2*)(Ab + off) = *(uint2*)o;
    }
  }
}

// softmax over this wave's 16 slots (head = wave) -> write P panel (swizzled)
__device__ __forceinline__ void softmax_to_P(f32x4* accS, const float* __restrict__ bptr,
    ushort_t* __restrict__ Pb, int w16, int m, int gq) {
  float4 b4 = *(const float4*)(bptr + w16 + gq * 4);
  const int gnum = (w16 + gq * 4) >> 3;
#pragma unroll
  for (int mt = 0; mt < 4; ++mt) {
    float e[4]; float mx = -3.0e38f;
#pragma unroll
    for (int j = 0; j < 4; ++j) { e[j] = accS[mt][j] + ((const float*)&b4)[j]; mx = fmaxf(mx, e[j]); }
    mx = fmaxf(mx, __shfl_xor(mx, 16, 64));
    mx = fmaxf(mx, __shfl_xor(mx, 32, 64));
    float sm = 0.f;
#pragma unroll
    for (int j = 0; j < 4; ++j) { e[j] = exp2f((e[j] - mx) * 1.44269504f); sm += e[j]; }
    sm += __shfl_xor(sm, 16, 64);
    sm += __shfl_xor(sm, 32, 64);
    float inv = fastrcp(sm);
    ushort_t p4[4];
#pragma unroll
    for (int j = 0; j < 4; ++j) p4[j] = f2bu(e[j] * inv);
    int r = mt * 16 + m;
    *(uint2*)(Pb + r * 64 + ((gnum ^ (r & 7)) << 3) + (gq & 1) * 4) = *(uint2*)p4;
  }
}

// ---------------- main fused kernel ----------------
// R17 = R16 + cross-section x preloads: the first 64k of encoder p+1 is
// loaded BEFORE encoder p's epilogue, hiding the ~500cy global-load chain
// under the epilogue + 3 fusion phases. setprio on remaining MFMA clusters.
__global__ __launch_bounds__(256) __attribute__((amdgpu_waves_per_eu(2))) void arn_main(
    const float* __restrict__ xv, const float* __restrict__ xa, const float* __restrict__ xt,
    const ushort_t* __restrict__ wsu, const float* __restrict__ battn,
    const float* __restrict__ bG, unsigned* __restrict__ counts,
    const float* __restrict__ ebv, const float* __restrict__ egv, const float* __restrict__ ebbv,
    const float* __restrict__ eba, const float* __restrict__ ega, const float* __restrict__ ebba,
    const float* __restrict__ ebt, const float* __restrict__ egt, const float* __restrict__ ebbt,
    const float* __restrict__ fb, const float* __restrict__ fg, const float* __restrict__ fbb) {
  __shared__ __align__(16) ushort_t Abuf[64 * 192 + 64];  // swizzled activations + zero pad
  __shared__ __align__(16) ushort_t Wbuf[2][12288];       // double-buffered chunks
  __shared__ float2 lnscr[64][4];
  __shared__ unsigned hist[64];

  const int tid = threadIdx.x, lane = tid & 63, wave = tid >> 6;
  const int m = lane & 15, gq = lane >> 4;
  const int wc0 = wave * 48;             // col-split GEMM col base
  const int w16 = wave * 16;             // head base / row-split base
  const int growbase = blockIdx.x * 64;

  if (tid < 64) { hist[tid] = 0u; Abuf[12288 + tid] = 0; }

  int gph = 0;
  { int nseg; const ushort_t* s0 = chunk_ptr(wsu, 0, &nseg); stage_to(&Wbuf[0][0], s0, wave, lane); }

  const int row0 = growbase + w16 + m;   // this lane's global row (row-split)
  const int rloc = w16 + m;              // local row in Abuf
  f32x4 accF[12];
#pragma unroll
  for (int t = 0; t < 12; ++t) accF[t] = (f32x4){0.f, 0.f, 0.f, 0.f};

  float4 c0, c1, c2, c3;
  enc_preload(xv, row0, 64, &c0, &c1, &c2, &c3, gq);

  // ===== vib encoder + fus part 0 =====
  {
    f32x4 accE[12];
#pragma unroll
    for (int t = 0; t < 12; ++t) accE[t] = (f32x4){0.f, 0.f, 0.f, 0.f};
    enc_gemm<1>(xv, row0, wsu, Wbuf, &gph, accE, c0, c1, c2, c3, m, gq, wave, lane);
    enc_preload(xa, row0, 256, &c0, &c1, &c2, &c3, gq);  // hide under epilogue+fus
    ln_gelu_enc(accE, ebv, egv, ebbv, Abuf, rloc, gq);
  }
  lds_gemm(Abuf, wsu, Wbuf, &gph, accF, wc0, m, gq, wave, lane);

  // ===== aco encoder + fus part 1 =====
  {
    f32x4 accE[12];
#pragma unroll
    for (int t = 0; t < 12; ++t) accE[t] = (f32x4){0.f, 0.f, 0.f, 0.f};
    enc_gemm<4>(xa, row0, wsu, Wbuf, &gph, accE, c0, c1, c2, c3, m, gq, wave, lane);
    enc_preload(xt, row0, 128, &c0, &c1, &c2, &c3, gq);  // hide under epilogue+fus
    ln_gelu_enc(accE, eba, ega, ebba, Abuf, rloc, gq);
  }
  lds_gemm(Abuf, wsu, Wbuf, &gph, accF, wc0, m, gq, wave, lane);

  // ===== tmp encoder + fus part 2 + fusion LN =====
  {
    f32x4 accE[12];
#pragma unroll
    for (int t = 0; t < 12; ++t) accE[t] = (f32x4){0.f, 0.f, 0.f, 0.f};
    enc_gemm<2>(xt, row0, wsu, Wbuf, &gph, accE, c0, c1, c2, c3, m, gq, wave, lane);
    ln_gelu_enc(accE, ebt, egt, ebbt, Abuf, rloc, gq);
  }
  lds_gemm(Abuf, wsu, Wbuf, &gph, accF, wc0, m, gq, wave, lane);
  ln_gelu_fus(accF, fb, fg, fbb, Abuf, lnscr, wave, wc0, m, gq);

  // ===== folded resonance chain (1 heavy phase + 4 light barriers) =====
  {
    f32x4 accS[4];
#pragma unroll
    for (int t = 0; t < 4; ++t) accS[t] = (f32x4){0.f, 0.f, 0.f, 0.f};
    // --- GEMM1: S1 = fused @ WK1 (phase 16; prefetches M-blob into buf1)
    phase_begin(wsu, Wbuf, gph, wave, lane);   // gph == 16, WK1 in buf0
    {
      const ushort_t* Wc = &Wbuf[0][0];
      int n = w16 + m;
      __builtin_amdgcn_s_setprio(1);
#pragma unroll
      for (int ks = 0; ks < 6; ++ks) {
        int kb = ks >> 1, sl = (ks & 1) * 4 + gq;
        short8 b = *(const short8*)(Wc + n * 192 + ((kb * 8 + (sl ^ (n & 7))) << 3));
#pragma unroll
        for (int mt = 0; mt < 4; ++mt) {
          int r = mt * 16 + m;
          short8 a = *(const short8*)(Abuf + r * 192 + ((kb * 8 + (sl ^ (r & 7))) << 3));
          accS[mt] = MFMA16(b, a, accS[mt]);
        }
      }
      __builtin_amdgcn_s_setprio(0);
      ++gph;
    }
    __syncthreads();  // all WK1 reads done; M-blob loads drained (vmcnt on barrier)
    softmax_to_P(accS, battn, &Wbuf[0][0], w16, m, gq);  // P1 -> buf0 @0
    __syncthreads();

    // --- layers 2,3: S = P_prev @ M + b (barrier-only; M from buf1 blob)
#pragma unroll
    for (int l = 1; l <= 2; ++l) {
      const ushort_t* Mc = &Wbuf[1][(l - 1) * 4096];
      const ushort_t* Pp = &Wbuf[0][(l - 1) * 4096];
#pragma unroll
      for (int t = 0; t < 4; ++t) accS[t] = (f32x4){0.f, 0.f, 0.f, 0.f};
      int n = w16 + m;
      __builtin_amdgcn_s_setprio(1);
#pragma unroll
      for (int ks = 0; ks < 2; ++ks) {
        int sl = ks * 4 + gq;
        short8 b = *(const short8*)(Mc + n * 64 + ((sl ^ (n & 7)) << 3));
#pragma unroll
        for (int mt = 0; mt < 4; ++mt) {
          int r = mt * 16 + m;
          short8 a = *(const short8*)(Pp + r * 64 + ((sl ^ (r & 7)) << 3));
          accS[mt] = MFMA16(b, a, accS[mt]);
        }
      }
      __builtin_amdgcn_s_setprio(0);
      softmax_to_P(accS, battn + l * 64, &Wbuf[0][l * 4096], w16, m, gq);  // disjoint region
      __syncthreads();
    }

    // --- SOFM: scores = P3 @ MG + bG (row-split) -> argmax histogram
    {
      const ushort_t* Mc = &Wbuf[1][8192];
      const ushort_t* P3 = &Wbuf[0][8192];
      f32x4 accG[4];
#pragma unroll
      for (int t = 0; t < 4; ++t) accG[t] = (f32x4){0.f, 0.f, 0.f, 0.f};
      int r = w16 + m;
      __builtin_amdgcn_s_setprio(1);
#pragma unroll
      for (int ks = 0; ks < 2; ++ks) {
        int sl = ks * 4 + gq;
        short8 a = *(const short8*)(P3 + r * 64 + ((sl ^ (r & 7)) << 3));
#pragma unroll
        for (int nt = 0; nt < 4; ++nt) {
          int n = nt * 16 + m;
          short8 b = *(const short8*)(Mc + n * 64 + ((sl ^ (n & 7)) << 3));
          accG[nt] = MFMA16(b, a, accG[nt]);  // accG[nt][j] = score[row][g=nt*16+gq*4+j]
        }
      }
      __builtin_amdgcn_s_setprio(0);
      float bv = -3.0e38f; int bi = 64;
#pragma unroll
      for (int nt = 0; nt < 4; ++nt) {
        int gb = nt * 16 + gq * 4;
        float4 g4 = *(const float4*)(bG + gb);
#pragma unroll
        for (int j = 0; j < 4; ++j) {
          float v = accG[nt][j] + ((const float*)&g4)[j];
          int g = gb + j;
          bool take = (v > bv);  // ascending g within lane: strict > keeps lowest
          bv = take ? v : bv; bi = take ? g : bi;
        }
      }
#pragma unroll
      for (int off = 16; off < 64; off <<= 1) {
        float ov = __shfl_xor(bv, off, 64);
        int oi = __shfl_xor(bi, off, 64);
        bool take = (ov > bv) || (ov == bv && oi < bi);
        bv = take ? ov : bv; bi = take ? oi : bi;
      }
      if (gq == 0) atomicAdd(&hist[bi], 1u);  // one count per row (owner m-lane)
    }
  }
  __syncthreads();
  if (tid < 64 && hist[tid]) atomicAdd(&counts[tid], hist[tid]);
}

// ---------------- finisher ----------------
__global__ void arn_finish(const unsigned* __restrict__ counts, const float* __restrict__ gr,
                           const float* __restrict__ ow, const float* __restrict__ ob,
                           float* __restrict__ out) {
  __shared__ float pooled[192];
  __shared__ float cf[64];
  int t = threadIdx.x;
  if (t < 64) cf[t] = (float)counts[t];
  __syncthreads();
  float s = 0.f;
  for (int g = 0; g < 64; ++g) s += cf[g] * gr[g * 192 + t];
  pooled[t] = s * (1.0f / (float)B_TOTAL);
  __syncthreads();
  if (t < 6) {
    float o = ob[t];
    for (int j = 0; j < 192; ++j) o += pooled[j] * ow[j * 6 + t];
    out[t] = (t == 1) ? fmaxf(o, 0.f) : 1.f / (1.f + expf(-o));
  }
}

// ---------------- launch ----------------
extern "C" void kernel_launch(void* const* d_in, const int* in_sizes, int n_in,
                              void* d_out, int out_size, void* d_ws, size_t ws_size,
                              hipStream_t stream) {
  (void)in_sizes; (void)n_in; (void)out_size; (void)ws_size;
  const float* xv   = (const float*)d_in[0];
  const float* xa   = (const float*)d_in[1];
  const float* xt   = (const float*)d_in[2];
  const float* ewv  = (const float*)d_in[3];
  const float* ebv  = (const float*)d_in[4];
  const float* egv  = (const float*)d_in[5];
  const float* ebbv = (const float*)d_in[6];
  const float* ewa  = (const float*)d_in[7];
  const float* eba  = (const float*)d_in[8];
  const float* ega  = (const float*)d_in[9];
  const float* ebba = (const float*)d_in[10];
  const float* ewt  = (const float*)d_in[11];
  const float* ebt  = (const float*)d_in[12];
  const float* egt  = (const float*)d_in[13];
  const float* ebbt = (const float*)d_in[14];
  const float* fw   = (const float*)d_in[15];
  const float* fb   = (const float*)d_in[16];
  const float* fg   = (const float*)d_in[17];
  const float* fbb  = (const float*)d_in[18];
  const float* rwq  = (const float*)d_in[19];
  const float* rwk  = (const float*)d_in[20];
  const float* rwv  = (const float*)d_in[21];
  const float* rwo  = (const float*)d_in[22];
  const float* rbq  = (const float*)d_in[23];
  const float* rbk  = (const float*)d_in[24];
  const float* rbv  = (const float*)d_in[25];
  const float* rbo  = (const float*)d_in[26];
  const float* rmem = (const float*)d_in[27];
  const float* grid = (const float*)d_in[28];
  const float* ow   = (const float*)d_in[29];
  const float* ob   = (const float*)d_in[30];

  ushort_t* wsu = (ushort_t*)d_ws;
  float* wsf = (float*)((char*)d_ws + F32_BYTE_OFF);
  float* battn = wsf + F_BATTN;
  float* bG    = wsf + F_BG;
  unsigned* cnt = (unsigned*)(wsf + F_CNT);

  prep_weights<<<dim3(256), dim3(256), 0, stream>>>(ewv, ewa, ewt, fw, wsu);
  prep_kv1<<<dim3(80), dim3(256), 0, stream>>>(rwk, rwv, rbk, rbv, rmem, wsf, cnt);
  prep_kv2<<<dim3(120), dim3(256), 0, stream>>>(rwq, rbq, rwo, wsf, wsu);
  prep_kv3<<<dim3(64), dim3(256), 0, stream>>>(rbo, grid, wsf, wsu);
  arn_main<<<dim3(2048), dim3(256), 0, stream>>>(xv, xa, xt, wsu, battn, bG, cnt,
      ebv, egv, ebbv, eba, ega, ebba, ebt, egt, ebbt, fb, fg, fbb);
  arn_finish<<<dim3(1), dim3(192), 0, stream>>>(cnt, grid, ow, ob, (float*)d_out);
}